// Round 1
// baseline (493.115 us; speedup 1.0000x reference)
//
#include <hip/hip_runtime.h>
#include <hip/hip_bf16.h>

#define B_SZ 4
#define L_SEQ 1024
#define D_MODEL 1024
#define DF_FF 4096
#define E_PER_B 32768
#define R_REL 64
#define M_ROWS (B_SZ * L_SEQ)   // 4096

typedef __attribute__((ext_vector_type(8))) short bf16x8;
typedef __attribute__((ext_vector_type(4))) float f32x4;

__device__ inline float b2f(unsigned short u) {
    union { unsigned int i; float f; } x; x.i = ((unsigned int)u) << 16; return x.f;
}
__device__ inline unsigned short f2b(float f) {
    union { float f; unsigned int u; } x; x.f = f;
    unsigned int r = x.u + 0x7FFFu + ((x.u >> 16) & 1u);
    return (unsigned short)(r >> 16);
}

#define GLOBAL_CAST(p) ((const __attribute__((address_space(1))) void*)(p))
#define LDS_CAST(p)    ((__attribute__((address_space(3))) void*)(p))

// ---------------- transpose + f32->bf16: W[K,N] -> Wt[N,K] ----------------
__global__ void transpose_f32_to_bf16(const float* __restrict__ W,
                                      unsigned short* __restrict__ Wt,
                                      int K, int N) {
    __shared__ float tile[32][33];
    int n0 = blockIdx.x * 32, k0 = blockIdx.y * 32;
    int tx = threadIdx.x & 31, ty = threadIdx.x >> 5;   // 32 x 8
#pragma unroll
    for (int r = 0; r < 32; r += 8)
        tile[ty + r][tx] = W[(size_t)(k0 + ty + r) * N + (n0 + tx)];
    __syncthreads();
#pragma unroll
    for (int r = 0; r < 32; r += 8)
        Wt[(size_t)(n0 + ty + r) * K + (k0 + tx)] = f2b(tile[tx][ty + r]);
}

__global__ void f32_to_bf16_kernel(const float* __restrict__ in,
                                   unsigned short* __restrict__ out, int n) {
    int i = blockIdx.x * 256 + threadIdx.x;
    if (i < n) out[i] = f2b(in[i]);
}

__global__ void build_bqkv(const float* __restrict__ bq, float* __restrict__ bqkv) {
    int i = blockIdx.x * 256 + threadIdx.x;   // grid covers 3072
    bqkv[i] = (i < 1024) ? bq[i] : 0.0f;
}

__global__ void zero_ints(int* __restrict__ p, int n) {
    int i = blockIdx.x * 256 + threadIdx.x;
    if (i < n) p[i] = 0;
}

// ---------------- GEMM: C[M,N] = A[M,K](bf16) * Bt[N,K](bf16)^T + bias ----------------
template<bool OUT_BF16, bool RELU>
__global__ __launch_bounds__(256, 2)
void gemm_bf16(const unsigned short* __restrict__ A,
               const unsigned short* __restrict__ Bt,
               const float* __restrict__ bias,
               float* __restrict__ Cf,
               unsigned short* __restrict__ Cb,
               int N, int K) {
    __shared__ unsigned short lA[128 * 32];
    __shared__ unsigned short lB[128 * 32];
    const int tile_m = blockIdx.y * 128;
    const int tile_n = blockIdx.x * 128;
    const int t = threadIdx.x;
    const int wave = t >> 6, lane = t & 63;
    const int wm = (wave >> 1) * 64, wn = (wave & 1) * 64;
    const int quad = lane >> 4, l16 = lane & 15;

    // staging: wave w, round r covers rows [r*64 + w*16, +16), lane i -> row i/4, col (i%4)*8
    const int srow = wave * 16 + (lane >> 2);
    const int scol = (lane & 3) * 8;
    const unsigned short* gA = A + (size_t)(tile_m + srow) * K + scol;
    const unsigned short* gB = Bt + (size_t)(tile_n + srow) * K + scol;

    f32x4 acc[4][4];
#pragma unroll
    for (int i = 0; i < 4; i++)
#pragma unroll
        for (int j = 0; j < 4; j++) acc[i][j] = (f32x4)0.0f;

    for (int k0 = 0; k0 < K; k0 += 32) {
        __syncthreads();
#pragma unroll
        for (int r = 0; r < 2; ++r) {
            __builtin_amdgcn_global_load_lds(GLOBAL_CAST(gA + (size_t)r * 64 * K),
                                             LDS_CAST(&lA[(r * 64 + wave * 16) * 32]), 16, 0, 0);
            __builtin_amdgcn_global_load_lds(GLOBAL_CAST(gB + (size_t)r * 64 * K),
                                             LDS_CAST(&lB[(r * 64 + wave * 16) * 32]), 16, 0, 0);
        }
        gA += 32; gB += 32;
        __builtin_amdgcn_s_waitcnt(0);
        __syncthreads();

        bf16x8 af[4], bf[4];
#pragma unroll
        for (int i = 0; i < 4; i++) {
            af[i] = *(const bf16x8*)&lA[(wm + i * 16 + l16) * 32 + quad * 8];
            bf[i] = *(const bf16x8*)&lB[(wn + i * 16 + l16) * 32 + quad * 8];
        }
#pragma unroll
        for (int mi = 0; mi < 4; mi++)
#pragma unroll
            for (int ni = 0; ni < 4; ni++)
                acc[mi][ni] = __builtin_amdgcn_mfma_f32_16x16x32_bf16(af[mi], bf[ni], acc[mi][ni], 0, 0, 0);
    }

#pragma unroll
    for (int mi = 0; mi < 4; mi++) {
#pragma unroll
        for (int ni = 0; ni < 4; ni++) {
            const int col = tile_n + wn + ni * 16 + l16;
            const float bv = bias[col];
#pragma unroll
            for (int r = 0; r < 4; r++) {
                const int row = tile_m + wm + mi * 16 + quad * 4 + r;
                float v = acc[mi][ni][r] + bv;
                if (RELU) v = fmaxf(v, 0.0f);
                if (OUT_BF16) Cb[(size_t)row * N + col] = f2b(v);
                else          Cf[(size_t)row * N + col] = v;
            }
        }
    }
}

// ---------------- LayerNorm family ----------------
// MODE 0: y = LN(X)            -> of32 + ob16
// MODE 1: y = LN(X + Res)      -> of32 + ob16
// MODE 2: y = LN(X + Res); fout = hidden + elu(y)
template<int MODE>
__global__ void ln_kernel(const float* __restrict__ X, const float* __restrict__ Res,
                          const float* __restrict__ g, const float* __restrict__ be,
                          float* __restrict__ of32, unsigned short* __restrict__ ob16,
                          const float* __restrict__ hidden, float* __restrict__ fout) {
    __shared__ float sb1[4], sb2[4];
    const int row = blockIdx.x, t = threadIdx.x;
    const size_t base = (size_t)row * 1024 + t * 4;

    float4 xv = *(const float4*)(X + base);
    float x0 = xv.x, x1 = xv.y, x2 = xv.z, x3 = xv.w;
    if (MODE >= 1) {
        float4 rv = *(const float4*)(Res + base);
        x0 += rv.x; x1 += rv.y; x2 += rv.z; x3 += rv.w;
    }
    float s = x0 + x1 + x2 + x3;
#pragma unroll
    for (int o = 32; o > 0; o >>= 1) s += __shfl_down(s, o);
    if ((t & 63) == 0) sb1[t >> 6] = s;
    __syncthreads();
    const float mu = (sb1[0] + sb1[1] + sb1[2] + sb1[3]) * (1.0f / 1024.0f);

    const float d0 = x0 - mu, d1 = x1 - mu, d2 = x2 - mu, d3 = x3 - mu;
    float s2 = d0 * d0 + d1 * d1 + d2 * d2 + d3 * d3;
#pragma unroll
    for (int o = 32; o > 0; o >>= 1) s2 += __shfl_down(s2, o);
    if ((t & 63) == 0) sb2[t >> 6] = s2;
    __syncthreads();
    const float var = (sb2[0] + sb2[1] + sb2[2] + sb2[3]) * (1.0f / 1024.0f);
    const float rstd = rsqrtf(var + 1e-6f);

    const float4 gv = *(const float4*)(g + t * 4);
    const float4 bv = *(const float4*)(be + t * 4);
    const float y0 = d0 * rstd * gv.x + bv.x;
    const float y1 = d1 * rstd * gv.y + bv.y;
    const float y2 = d2 * rstd * gv.z + bv.z;
    const float y3 = d3 * rstd * gv.w + bv.w;

    if (MODE <= 1) {
        float4 o; o.x = y0; o.y = y1; o.z = y2; o.w = y3;
        *(float4*)(of32 + base) = o;
        ushort4 ob; ob.x = f2b(y0); ob.y = f2b(y1); ob.z = f2b(y2); ob.w = f2b(y3);
        *(ushort4*)(ob16 + base) = ob;
    } else {
        const float4 hv = *(const float4*)(hidden + base);
        const float e0 = y0 > 0.0f ? y0 : expm1f(y0);
        const float e1 = y1 > 0.0f ? y1 : expm1f(y1);
        const float e2 = y2 > 0.0f ? y2 : expm1f(y2);
        const float e3 = y3 > 0.0f ? y3 : expm1f(y3);
        float4 o; o.x = hv.x + e0; o.y = hv.y + e1; o.z = hv.z + e2; o.w = hv.w + e3;
        *(float4*)(fout + base) = o;
    }
}

// ---------------- edge pipeline ----------------
__global__ void count_kernel(const int* __restrict__ dst, int* __restrict__ counts) {
    int g = blockIdx.x * 256 + threadIdx.x;   // exactly B*E
    int b = g >> 15;
    atomicAdd(&counts[(b << 10) + dst[g]], 1);
}

__global__ void scan_kernel(const int* __restrict__ counts, int* __restrict__ offs,
                            int* __restrict__ cursor) {
    __shared__ int buf[1024];
    const int b = blockIdx.x, t = threadIdx.x;
    const int c = counts[b * 1024 + t];
    buf[t] = c;
    __syncthreads();
    for (int o = 1; o < 1024; o <<= 1) {
        int v = (t >= o) ? buf[t - o] : 0;
        __syncthreads();
        buf[t] += v;
        __syncthreads();
    }
    const int ex = buf[t] - c;
    offs[b * 1024 + t] = ex;
    cursor[b * 1024 + t] = ex;
}

__global__ void scatter_kernel(const int* __restrict__ dst, int* __restrict__ cursor,
                               int* __restrict__ perm) {
    int g = blockIdx.x * 256 + threadIdx.x;
    int b = g >> 15;
    int pos = atomicAdd(&cursor[(b << 10) + dst[g]], 1);
    perm[((size_t)b << 15) + pos] = g & (E_PER_B - 1);
}

// one wave per edge: score = exp(clip(dot(k[src]+e, q[dst]) / 32, +-10))
__global__ void edge_score(const unsigned short* __restrict__ QKV,   // [M,3072] q|k|v
                           const unsigned short* __restrict__ relb,  // [R,1024]
                           const int* __restrict__ src, const int* __restrict__ dstA,
                           const int* __restrict__ rel,
                           float* __restrict__ scores) {
    const int gw = (blockIdx.x * 256 + threadIdx.x) >> 6;
    const int lane = threadIdx.x & 63;
    const int b = gw >> 15;
    const int s = src[gw], d = dstA[gw], r = rel[gw];
    const unsigned short* kr = QKV + ((size_t)((b << 10) + s)) * 3072 + 1024;
    const unsigned short* qr = QKV + ((size_t)((b << 10) + d)) * 3072;
    const unsigned short* er = relb + (size_t)r * 1024;
    float acc = 0.0f;
#pragma unroll
    for (int j = 0; j < 4; j++) {
        const int off = j * 256 + lane * 4;
        const ushort4 kv = *(const ushort4*)(kr + off);
        const ushort4 qv = *(const ushort4*)(qr + off);
        const ushort4 ev = *(const ushort4*)(er + off);
        acc += (b2f(kv.x) + b2f(ev.x)) * b2f(qv.x);
        acc += (b2f(kv.y) + b2f(ev.y)) * b2f(qv.y);
        acc += (b2f(kv.z) + b2f(ev.z)) * b2f(qv.z);
        acc += (b2f(kv.w) + b2f(ev.w)) * b2f(qv.w);
    }
#pragma unroll
    for (int o = 32; o > 0; o >>= 1) acc += __shfl_down(acc, o);
    if (lane == 0) {
        float sc = acc * (1.0f / 32.0f);
        sc = fminf(fmaxf(sc, -10.0f), 10.0f);
        scores[gw] = expf(sc);
    }
}

// one block per (b,node): o[node] = sum_e (v[src]+e)*score / sum_e score
__global__ void edge_agg(const unsigned short* __restrict__ QKV,
                         const unsigned short* __restrict__ relb,
                         const float* __restrict__ scores,
                         const int* __restrict__ src, const int* __restrict__ rel,
                         const int* __restrict__ perm, const int* __restrict__ offs,
                         const int* __restrict__ counts,
                         unsigned short* __restrict__ O) {
    const int node = blockIdx.x;          // b*1024 + l
    const int b = node >> 10;
    const int t = threadIdx.x;
    const int start = offs[node], cnt = counts[node];
    const int base = b << 15;
    float a0 = 0, a1 = 0, a2 = 0, a3 = 0, z = 0;
    for (int j = 0; j < cnt; j++) {
        const int ei = perm[(size_t)base + start + j];
        const float sc = scores[base + ei];
        const int s = src[base + ei], r = rel[base + ei];
        const ushort4 vv = *(const ushort4*)(QKV + ((size_t)((b << 10) + s)) * 3072 + 2048 + t * 4);
        const ushort4 ev = *(const ushort4*)(relb + (size_t)r * 1024 + t * 4);
        a0 += (b2f(vv.x) + b2f(ev.x)) * sc;
        a1 += (b2f(vv.y) + b2f(ev.y)) * sc;
        a2 += (b2f(vv.z) + b2f(ev.z)) * sc;
        a3 += (b2f(vv.w) + b2f(ev.w)) * sc;
        z += sc;
    }
    const float inv = 1.0f / z;
    const size_t ob = (size_t)node * 1024 + t * 4;
    ushort4 o4;
    o4.x = f2b(a0 * inv); o4.y = f2b(a1 * inv); o4.z = f2b(a2 * inv); o4.w = f2b(a3 * inv);
    *(ushort4*)(O + ob) = o4;
}

// ---------------- launch ----------------
extern "C" void kernel_launch(void* const* d_in, const int* in_sizes, int n_in,
                              void* d_out, int out_size, void* d_ws, size_t ws_size,
                              hipStream_t stream) {
    const float* hidden  = (const float*)d_in[0];
    const float* rel_tbl = (const float*)d_in[1];
    const float* Wq = (const float*)d_in[2];
    const float* bq = (const float*)d_in[3];
    const float* Wk = (const float*)d_in[4];
    const float* Wv = (const float*)d_in[5];
    const float* Wo = (const float*)d_in[6];
    const float* bo = (const float*)d_in[7];
    const float* ln0_g = (const float*)d_in[8];
    const float* ln0_b = (const float*)d_in[9];
    const float* ln1_g = (const float*)d_in[10];
    const float* ln1_b = (const float*)d_in[11];
    const float* W1 = (const float*)d_in[12];
    const float* b1 = (const float*)d_in[13];
    const float* W2 = (const float*)d_in[14];
    const float* b2 = (const float*)d_in[15];
    const float* ln2_g = (const float*)d_in[16];
    const float* ln2_b = (const float*)d_in[17];
    const int* esrc = (const int*)d_in[18];
    const int* edst = (const int*)d_in[19];
    const int* erel = (const int*)d_in[20];
    float* out = (float*)d_out;

    char* ws = (char*)d_ws;
    const size_t MB = 1024 * 1024;
    float*          Xn_f32  = (float*)(ws + 0);                    // 16MB
    unsigned short* Xn_b16  = (unsigned short*)(ws + 16 * MB);     // 8MB
    unsigned short* Wqkv_t  = (unsigned short*)(ws + 24 * MB);     // [3072,1024] 6MB
    unsigned short* Wo_t    = (unsigned short*)(ws + 30 * MB);     // 2MB
    unsigned short* W1_t    = (unsigned short*)(ws + 32 * MB);     // [4096,1024] 8MB
    unsigned short* W2_t    = (unsigned short*)(ws + 40 * MB);     // [1024,4096] 8MB
    unsigned short* relb    = (unsigned short*)(ws + 48 * MB);     // 128KB
    float*          bqkv    = (float*)(ws + 48 * MB + 256 * 1024); // 12KB
    unsigned short* QKV     = (unsigned short*)(ws + 49 * MB);     // [4096,3072] 24MB
    float*          scores  = (float*)(ws + 73 * MB);              // 512KB
    int*            perm    = (int*)(ws + 73 * MB + 512 * 1024);   // 512KB
    int*            counts  = (int*)(ws + 74 * MB);                // 16KB
    int*            offs    = (int*)(ws + 74 * MB + 16 * 1024);    // 16KB
    int*            cursor  = (int*)(ws + 74 * MB + 32 * 1024);    // 16KB
    unsigned short* Obf     = (unsigned short*)(ws + 75 * MB);     // 8MB
    float*          C1      = (float*)(ws + 83 * MB);              // 16MB (also H2)
    float*          Out_f32 = (float*)(ws + 99 * MB);              // 16MB
    unsigned short* Out_b16 = (unsigned short*)(ws + 115 * MB);    // 8MB
    unsigned short* H1      = (unsigned short*)(ws + 49 * MB);     // 32MB overlay (QKV dead)

    const dim3 blk(256);

    // weight prep
    transpose_f32_to_bf16<<<dim3(32, 32), blk, 0, stream>>>(Wq, Wqkv_t, 1024, 1024);
    transpose_f32_to_bf16<<<dim3(32, 32), blk, 0, stream>>>(Wk, Wqkv_t + 1024 * 1024, 1024, 1024);
    transpose_f32_to_bf16<<<dim3(32, 32), blk, 0, stream>>>(Wv, Wqkv_t + 2 * 1024 * 1024, 1024, 1024);
    transpose_f32_to_bf16<<<dim3(32, 32), blk, 0, stream>>>(Wo, Wo_t, 1024, 1024);
    transpose_f32_to_bf16<<<dim3(128, 32), blk, 0, stream>>>(W1, W1_t, 1024, 4096);
    transpose_f32_to_bf16<<<dim3(32, 128), blk, 0, stream>>>(W2, W2_t, 4096, 1024);
    f32_to_bf16_kernel<<<256, blk, 0, stream>>>(rel_tbl, relb, R_REL * 1024);
    build_bqkv<<<12, blk, 0, stream>>>(bq, bqkv);

    // LN0
    ln_kernel<0><<<M_ROWS, blk, 0, stream>>>(hidden, nullptr, ln0_g, ln0_b,
                                             Xn_f32, Xn_b16, nullptr, nullptr);
    // QKV fused GEMM: [4096,1024] x [1024,3072]
    gemm_bf16<true, false><<<dim3(24, 32), blk, 0, stream>>>(Xn_b16, Wqkv_t, bqkv,
                                                             nullptr, QKV, 3072, 1024);
    // CSR build
    zero_ints<<<16, blk, 0, stream>>>(counts, 4096);
    count_kernel<<<512, blk, 0, stream>>>(edst, counts);
    scan_kernel<<<4, 1024, 0, stream>>>(counts, offs, cursor);
    scatter_kernel<<<512, blk, 0, stream>>>(edst, cursor, perm);
    // scores + aggregation
    edge_score<<<32768, blk, 0, stream>>>(QKV, relb, esrc, edst, erel, scores);
    edge_agg<<<M_ROWS, blk, 0, stream>>>(QKV, relb, scores, esrc, erel, perm, offs, counts, Obf);
    // o @ Wo + bo
    gemm_bf16<false, false><<<dim3(8, 32), blk, 0, stream>>>(Obf, Wo_t, bo,
                                                             C1, nullptr, 1024, 1024);
    // LN1(x + .)
    ln_kernel<1><<<M_ROWS, blk, 0, stream>>>(Xn_f32, C1, ln1_g, ln1_b,
                                             Out_f32, Out_b16, nullptr, nullptr);
    // FFN
    gemm_bf16<true, true><<<dim3(32, 32), blk, 0, stream>>>(Out_b16, W1_t, b1,
                                                            nullptr, H1, 4096, 1024);
    gemm_bf16<false, false><<<dim3(8, 32), blk, 0, stream>>>(H1, W2_t, b2,
                                                             C1, nullptr, 1024, 4096);
    // LN2 + elu + residual
    ln_kernel<2><<<M_ROWS, blk, 0, stream>>>(Out_f32, C1, ln2_g, ln2_b,
                                             nullptr, nullptr, hidden, out);
    (void)in_sizes; (void)n_in; (void)out_size; (void)ws_size;
}

// Round 2
// 470.632 us; speedup vs baseline: 1.0478x; 1.0478x over previous
//
#include <hip/hip_runtime.h>
#include <hip/hip_bf16.h>

#define B_SZ 4
#define L_SEQ 1024
#define D_MODEL 1024
#define DF_FF 4096
#define E_PER_B 32768
#define R_REL 64
#define M_ROWS (B_SZ * L_SEQ)   // 4096

typedef __attribute__((ext_vector_type(8))) short bf16x8;
typedef __attribute__((ext_vector_type(4))) float f32x4;

__device__ inline float b2f(unsigned short u) {
    union { unsigned int i; float f; } x; x.i = ((unsigned int)u) << 16; return x.f;
}
__device__ inline unsigned short f2b(float f) {
    union { float f; unsigned int u; } x; x.f = f;
    unsigned int r = x.u + 0x7FFFu + ((x.u >> 16) & 1u);
    return (unsigned short)(r >> 16);
}

#define GLOBAL_CAST(p) ((const __attribute__((address_space(1))) void*)(p))
#define LDS_CAST(p)    ((__attribute__((address_space(3))) void*)(p))

// ---------------- transpose + f32->bf16: W[K,N] -> Wt[N,K] ----------------
__global__ void transpose_f32_to_bf16(const float* __restrict__ W,
                                      unsigned short* __restrict__ Wt,
                                      int K, int N) {
    __shared__ float tile[32][33];
    int n0 = blockIdx.x * 32, k0 = blockIdx.y * 32;
    int tx = threadIdx.x & 31, ty = threadIdx.x >> 5;   // 32 x 8
#pragma unroll
    for (int r = 0; r < 32; r += 8)
        tile[ty + r][tx] = W[(size_t)(k0 + ty + r) * N + (n0 + tx)];
    __syncthreads();
#pragma unroll
    for (int r = 0; r < 32; r += 8)
        Wt[(size_t)(n0 + ty + r) * K + (k0 + tx)] = f2b(tile[tx][ty + r]);
}

__global__ void f32_to_bf16_kernel(const float* __restrict__ in,
                                   unsigned short* __restrict__ out, int n) {
    int i = blockIdx.x * 256 + threadIdx.x;
    if (i < n) out[i] = f2b(in[i]);
}

__global__ void build_bqkv(const float* __restrict__ bq, float* __restrict__ bqkv) {
    int i = blockIdx.x * 256 + threadIdx.x;   // grid covers 3072
    bqkv[i] = (i < 1024) ? bq[i] : 0.0f;
}

__global__ void zero_ints(int* __restrict__ p, int n) {
    int i = blockIdx.x * 256 + threadIdx.x;
    if (i < n) p[i] = 0;
}

// XOR-swizzled LDS layout: LDS slot s of row r holds global chunk s ^ ((r>>1)&3)
// (chunks of 8 shorts = 16B). Kills the 8-way bank conflicts of the 64B row stride;
// residual 2-way aliasing is free (m136).

// ---------------- GEMM: C[M,N] = A[M,K](bf16) * Bt[N,K](bf16)^T + bias ----------------
template<bool OUT_BF16, bool RELU>
__global__ __launch_bounds__(256, 2)
void gemm_bf16(const unsigned short* __restrict__ A,
               const unsigned short* __restrict__ Bt,
               const float* __restrict__ bias,
               float* __restrict__ Cf,
               unsigned short* __restrict__ Cb,
               int N, int K) {
    __shared__ unsigned short lA[128 * 32];
    __shared__ unsigned short lB[128 * 32];
    const int tile_m = blockIdx.y * 128;
    const int tile_n = blockIdx.x * 128;
    const int t = threadIdx.x;
    const int wave = t >> 6, lane = t & 63;
    const int wm = (wave >> 1) * 64, wn = (wave & 1) * 64;
    const int quad = lane >> 4, l16 = lane & 15;

    // staging: lane i -> row i/4, swizzled chunk (i%4)^((i>>3)&3)
    const int srow = wave * 16 + (lane >> 2);
    const int scol = ((lane & 3) ^ ((lane >> 3) & 3)) * 8;
    const unsigned short* gA = A + (size_t)(tile_m + srow) * K + scol;
    const unsigned short* gB = Bt + (size_t)(tile_n + srow) * K + scol;

    const int rcha = (quad ^ ((l16 >> 1) & 3)) * 8;   // read-side swizzled chunk

    f32x4 acc[4][4];
#pragma unroll
    for (int i = 0; i < 4; i++)
#pragma unroll
        for (int j = 0; j < 4; j++) acc[i][j] = (f32x4)0.0f;

    for (int k0 = 0; k0 < K; k0 += 32) {
        __syncthreads();
#pragma unroll
        for (int r = 0; r < 2; ++r) {
            __builtin_amdgcn_global_load_lds(GLOBAL_CAST(gA + (size_t)r * 64 * K),
                                             LDS_CAST(&lA[(r * 64 + wave * 16) * 32]), 16, 0, 0);
            __builtin_amdgcn_global_load_lds(GLOBAL_CAST(gB + (size_t)r * 64 * K),
                                             LDS_CAST(&lB[(r * 64 + wave * 16) * 32]), 16, 0, 0);
        }
        gA += 32; gB += 32;
        __builtin_amdgcn_s_waitcnt(0);
        __syncthreads();

        bf16x8 af[4], bf[4];
#pragma unroll
        for (int i = 0; i < 4; i++) {
            af[i] = *(const bf16x8*)&lA[(wm + i * 16 + l16) * 32 + rcha];
            bf[i] = *(const bf16x8*)&lB[(wn + i * 16 + l16) * 32 + rcha];
        }
#pragma unroll
        for (int mi = 0; mi < 4; mi++)
#pragma unroll
            for (int ni = 0; ni < 4; ni++)
                acc[mi][ni] = __builtin_amdgcn_mfma_f32_16x16x32_bf16(af[mi], bf[ni], acc[mi][ni], 0, 0, 0);
    }

#pragma unroll
    for (int mi = 0; mi < 4; mi++) {
#pragma unroll
        for (int ni = 0; ni < 4; ni++) {
            const int col = tile_n + wn + ni * 16 + l16;
            const float bv = bias[col];
#pragma unroll
            for (int r = 0; r < 4; r++) {
                const int row = tile_m + wm + mi * 16 + quad * 4 + r;
                float v = acc[mi][ni][r] + bv;
                if (RELU) v = fmaxf(v, 0.0f);
                if (OUT_BF16) Cb[(size_t)row * N + col] = f2b(v);
                else          Cf[(size_t)row * N + col] = v;
            }
        }
    }
}

// split-K variant: grid.z in {0,1}; chunk z covers K-range [z*Kc, (z+1)*Kc).
// writes f32 partial to P0/P1; bias folded into chunk 0.
__global__ __launch_bounds__(256, 2)
void gemm_bf16_splitk(const unsigned short* __restrict__ A,
                      const unsigned short* __restrict__ Bt,
                      const float* __restrict__ bias,
                      float* __restrict__ P0, float* __restrict__ P1,
                      int N, int K, int Kc) {
    __shared__ unsigned short lA[128 * 32];
    __shared__ unsigned short lB[128 * 32];
    const int tile_m = blockIdx.y * 128;
    const int tile_n = blockIdx.x * 128;
    const int z = blockIdx.z;
    const int t = threadIdx.x;
    const int wave = t >> 6, lane = t & 63;
    const int wm = (wave >> 1) * 64, wn = (wave & 1) * 64;
    const int quad = lane >> 4, l16 = lane & 15;

    const int srow = wave * 16 + (lane >> 2);
    const int scol = ((lane & 3) ^ ((lane >> 3) & 3)) * 8;
    const unsigned short* gA = A + (size_t)(tile_m + srow) * K + z * Kc + scol;
    const unsigned short* gB = Bt + (size_t)(tile_n + srow) * K + z * Kc + scol;

    const int rcha = (quad ^ ((l16 >> 1) & 3)) * 8;

    f32x4 acc[4][4];
#pragma unroll
    for (int i = 0; i < 4; i++)
#pragma unroll
        for (int j = 0; j < 4; j++) acc[i][j] = (f32x4)0.0f;

    for (int k0 = 0; k0 < Kc; k0 += 32) {
        __syncthreads();
#pragma unroll
        for (int r = 0; r < 2; ++r) {
            __builtin_amdgcn_global_load_lds(GLOBAL_CAST(gA + (size_t)r * 64 * K),
                                             LDS_CAST(&lA[(r * 64 + wave * 16) * 32]), 16, 0, 0);
            __builtin_amdgcn_global_load_lds(GLOBAL_CAST(gB + (size_t)r * 64 * K),
                                             LDS_CAST(&lB[(r * 64 + wave * 16) * 32]), 16, 0, 0);
        }
        gA += 32; gB += 32;
        __builtin_amdgcn_s_waitcnt(0);
        __syncthreads();

        bf16x8 af[4], bf[4];
#pragma unroll
        for (int i = 0; i < 4; i++) {
            af[i] = *(const bf16x8*)&lA[(wm + i * 16 + l16) * 32 + rcha];
            bf[i] = *(const bf16x8*)&lB[(wn + i * 16 + l16) * 32 + rcha];
        }
#pragma unroll
        for (int mi = 0; mi < 4; mi++)
#pragma unroll
            for (int ni = 0; ni < 4; ni++)
                acc[mi][ni] = __builtin_amdgcn_mfma_f32_16x16x32_bf16(af[mi], bf[ni], acc[mi][ni], 0, 0, 0);
    }

    float* P = (z == 0) ? P0 : P1;
#pragma unroll
    for (int mi = 0; mi < 4; mi++) {
#pragma unroll
        for (int ni = 0; ni < 4; ni++) {
            const int col = tile_n + wn + ni * 16 + l16;
            const float bv = (z == 0) ? bias[col] : 0.0f;
#pragma unroll
            for (int r = 0; r < 4; r++) {
                const int row = tile_m + wm + mi * 16 + quad * 4 + r;
                P[(size_t)row * N + col] = acc[mi][ni][r] + bv;
            }
        }
    }
}

// ---------------- LayerNorm family ----------------
// MODE 0: y = LN(X)                  -> of32 + ob16
// MODE 1: y = LN(X + R0 + R1)        -> of32 + ob16
// MODE 2: y = LN(X + R0 + R1); fout = hidden + elu(y)
template<int MODE>
__global__ void ln_kernel(const float* __restrict__ X,
                          const float* __restrict__ R0, const float* __restrict__ R1,
                          const float* __restrict__ g, const float* __restrict__ be,
                          float* __restrict__ of32, unsigned short* __restrict__ ob16,
                          const float* __restrict__ hidden, float* __restrict__ fout) {
    __shared__ float sb1[4], sb2[4];
    const int row = blockIdx.x, t = threadIdx.x;
    const size_t base = (size_t)row * 1024 + t * 4;

    float4 xv = *(const float4*)(X + base);
    float x0 = xv.x, x1 = xv.y, x2 = xv.z, x3 = xv.w;
    if (MODE >= 1) {
        float4 r0 = *(const float4*)(R0 + base);
        float4 r1 = *(const float4*)(R1 + base);
        x0 += r0.x + r1.x; x1 += r0.y + r1.y; x2 += r0.z + r1.z; x3 += r0.w + r1.w;
    }
    float s = x0 + x1 + x2 + x3;
#pragma unroll
    for (int o = 32; o > 0; o >>= 1) s += __shfl_down(s, o);
    if ((t & 63) == 0) sb1[t >> 6] = s;
    __syncthreads();
    const float mu = (sb1[0] + sb1[1] + sb1[2] + sb1[3]) * (1.0f / 1024.0f);

    const float d0 = x0 - mu, d1 = x1 - mu, d2 = x2 - mu, d3 = x3 - mu;
    float s2 = d0 * d0 + d1 * d1 + d2 * d2 + d3 * d3;
#pragma unroll
    for (int o = 32; o > 0; o >>= 1) s2 += __shfl_down(s2, o);
    if ((t & 63) == 0) sb2[t >> 6] = s2;
    __syncthreads();
    const float var = (sb2[0] + sb2[1] + sb2[2] + sb2[3]) * (1.0f / 1024.0f);
    const float rstd = rsqrtf(var + 1e-6f);

    const float4 gv = *(const float4*)(g + t * 4);
    const float4 bv = *(const float4*)(be + t * 4);
    const float y0 = d0 * rstd * gv.x + bv.x;
    const float y1 = d1 * rstd * gv.y + bv.y;
    const float y2 = d2 * rstd * gv.z + bv.z;
    const float y3 = d3 * rstd * gv.w + bv.w;

    if (MODE <= 1) {
        float4 o; o.x = y0; o.y = y1; o.z = y2; o.w = y3;
        *(float4*)(of32 + base) = o;
        ushort4 ob; ob.x = f2b(y0); ob.y = f2b(y1); ob.z = f2b(y2); ob.w = f2b(y3);
        *(ushort4*)(ob16 + base) = ob;
    } else {
        const float4 hv = *(const float4*)(hidden + base);
        const float e0 = y0 > 0.0f ? y0 : expm1f(y0);
        const float e1 = y1 > 0.0f ? y1 : expm1f(y1);
        const float e2 = y2 > 0.0f ? y2 : expm1f(y2);
        const float e3 = y3 > 0.0f ? y3 : expm1f(y3);
        float4 o; o.x = hv.x + e0; o.y = hv.y + e1; o.z = hv.z + e2; o.w = hv.w + e3;
        *(float4*)(fout + base) = o;
    }
}

// ---------------- edge pipeline ----------------
__global__ void count_kernel(const int* __restrict__ dst, int* __restrict__ counts) {
    int g = blockIdx.x * 256 + threadIdx.x;   // exactly B*E
    int b = g >> 15;
    atomicAdd(&counts[(b << 10) + dst[g]], 1);
}

__global__ void scan_kernel(const int* __restrict__ counts, int* __restrict__ offs,
                            int* __restrict__ cursor) {
    __shared__ int buf[1024];
    const int b = blockIdx.x, t = threadIdx.x;
    const int c = counts[b * 1024 + t];
    buf[t] = c;
    __syncthreads();
    for (int o = 1; o < 1024; o <<= 1) {
        int v = (t >= o) ? buf[t - o] : 0;
        __syncthreads();
        buf[t] += v;
        __syncthreads();
    }
    const int ex = buf[t] - c;
    offs[b * 1024 + t] = ex;
    cursor[b * 1024 + t] = ex;
}

__global__ void scatter_kernel(const int* __restrict__ dst, int* __restrict__ cursor,
                               int* __restrict__ perm) {
    int g = blockIdx.x * 256 + threadIdx.x;
    int b = g >> 15;
    int pos = atomicAdd(&cursor[(b << 10) + dst[g]], 1);
    perm[((size_t)b << 15) + pos] = g & (E_PER_B - 1);
}

// one wave per edge: score = exp(clip(dot(k[src]+e, q[dst]) / 32, +-10))
__global__ void edge_score(const unsigned short* __restrict__ QKV,   // [M,3072] q|k|v
                           const unsigned short* __restrict__ relb,  // [R,1024]
                           const int* __restrict__ src, const int* __restrict__ dstA,
                           const int* __restrict__ rel,
                           float* __restrict__ scores) {
    const int gw = (blockIdx.x * 256 + threadIdx.x) >> 6;
    const int lane = threadIdx.x & 63;
    const int b = gw >> 15;
    const int s = src[gw], d = dstA[gw], r = rel[gw];
    const unsigned short* kr = QKV + ((size_t)((b << 10) + s)) * 3072 + 1024;
    const unsigned short* qr = QKV + ((size_t)((b << 10) + d)) * 3072;
    const unsigned short* er = relb + (size_t)r * 1024;
    float acc = 0.0f;
#pragma unroll
    for (int j = 0; j < 4; j++) {
        const int off = j * 256 + lane * 4;
        const ushort4 kv = *(const ushort4*)(kr + off);
        const ushort4 qv = *(const ushort4*)(qr + off);
        const ushort4 ev = *(const ushort4*)(er + off);
        acc += (b2f(kv.x) + b2f(ev.x)) * b2f(qv.x);
        acc += (b2f(kv.y) + b2f(ev.y)) * b2f(qv.y);
        acc += (b2f(kv.z) + b2f(ev.z)) * b2f(qv.z);
        acc += (b2f(kv.w) + b2f(ev.w)) * b2f(qv.w);
    }
#pragma unroll
    for (int o = 32; o > 0; o >>= 1) acc += __shfl_down(acc, o);
    if (lane == 0) {
        float sc = acc * (1.0f / 32.0f);
        sc = fminf(fmaxf(sc, -10.0f), 10.0f);
        scores[gw] = expf(sc);
    }
}

// one block per (b,node): o[node] = sum_e (v[src]+e)*score / sum_e score
__global__ void edge_agg(const unsigned short* __restrict__ QKV,
                         const unsigned short* __restrict__ relb,
                         const float* __restrict__ scores,
                         const int* __restrict__ src, const int* __restrict__ rel,
                         const int* __restrict__ perm, const int* __restrict__ offs,
                         const int* __restrict__ counts,
                         unsigned short* __restrict__ O) {
    const int node = blockIdx.x;          // b*1024 + l
    const int b = node >> 10;
    const int t = threadIdx.x;
    const int start = offs[node], cnt = counts[node];
    const int base = b << 15;
    float a0 = 0, a1 = 0, a2 = 0, a3 = 0, z = 0;
    for (int j = 0; j < cnt; j++) {
        const int ei = perm[(size_t)base + start + j];
        const float sc = scores[base + ei];
        const int s = src[base + ei], r = rel[base + ei];
        const ushort4 vv = *(const ushort4*)(QKV + ((size_t)((b << 10) + s)) * 3072 + 2048 + t * 4);
        const ushort4 ev = *(const ushort4*)(relb + (size_t)r * 1024 + t * 4);
        a0 += (b2f(vv.x) + b2f(ev.x)) * sc;
        a1 += (b2f(vv.y) + b2f(ev.y)) * sc;
        a2 += (b2f(vv.z) + b2f(ev.z)) * sc;
        a3 += (b2f(vv.w) + b2f(ev.w)) * sc;
        z += sc;
    }
    const float inv = 1.0f / z;
    const size_t ob = (size_t)node * 1024 + t * 4;
    ushort4 o4;
    o4.x = f2b(a0 * inv); o4.y = f2b(a1 * inv); o4.z = f2b(a2 * inv); o4.w = f2b(a3 * inv);
    *(ushort4*)(O + ob) = o4;
}

// ---------------- launch ----------------
extern "C" void kernel_launch(void* const* d_in, const int* in_sizes, int n_in,
                              void* d_out, int out_size, void* d_ws, size_t ws_size,
                              hipStream_t stream) {
    const float* hidden  = (const float*)d_in[0];
    const float* rel_tbl = (const float*)d_in[1];
    const float* Wq = (const float*)d_in[2];
    const float* bq = (const float*)d_in[3];
    const float* Wk = (const float*)d_in[4];
    const float* Wv = (const float*)d_in[5];
    const float* Wo = (const float*)d_in[6];
    const float* bo = (const float*)d_in[7];
    const float* ln0_g = (const float*)d_in[8];
    const float* ln0_b = (const float*)d_in[9];
    const float* ln1_g = (const float*)d_in[10];
    const float* ln1_b = (const float*)d_in[11];
    const float* W1 = (const float*)d_in[12];
    const float* b1 = (const float*)d_in[13];
    const float* W2 = (const float*)d_in[14];
    const float* b2 = (const float*)d_in[15];
    const float* ln2_g = (const float*)d_in[16];
    const float* ln2_b = (const float*)d_in[17];
    const int* esrc = (const int*)d_in[18];
    const int* edst = (const int*)d_in[19];
    const int* erel = (const int*)d_in[20];
    float* out = (float*)d_out;

    // ws timeline overlay (<=123MB, all offsets verified against kernel order):
    //  0-16  Xn_f32 (LN0->LN1)           then H1 low half (FFN1->W2)
    // 16-24  Xn_b16 (LN0->QKV)           then H1 high... H1 = 0-32 total
    // 24-30  Wqkv_t (->QKV)   30-32 Wo_t (->Wo)
    // 32-40  W1_t (->FFN1)    40-48 W2_t (->W2)
    // 48-49  relb + bqkv
    // 49-65  P1 (Wo/W2 split-K partial z=1)   [QKV 49-73 dead by Wo time]
    // 49-73  QKV (QKV gemm -> edge_agg)
    // 73-74  scores/counts/offs/cursor   74-74.5 perm
    // 75-83  Obf (edge_agg -> Wo)
    // 83-99  P0 (split-K partial z=0)
    // 99-115 Out_f32 (LN1->LN2)   115-123 Out_b16 (LN1->FFN1)
    char* ws = (char*)d_ws;
    const size_t MB = 1024 * 1024;
    float*          Xn_f32  = (float*)(ws + 0);                    // 16MB
    unsigned short* Xn_b16  = (unsigned short*)(ws + 16 * MB);     // 8MB
    unsigned short* H1      = (unsigned short*)(ws + 0);           // 32MB overlay
    unsigned short* Wqkv_t  = (unsigned short*)(ws + 24 * MB);     // 6MB
    unsigned short* Wo_t    = (unsigned short*)(ws + 30 * MB);     // 2MB
    unsigned short* W1_t    = (unsigned short*)(ws + 32 * MB);     // 8MB
    unsigned short* W2_t    = (unsigned short*)(ws + 40 * MB);     // 8MB
    unsigned short* relb    = (unsigned short*)(ws + 48 * MB);     // 128KB
    float*          bqkv    = (float*)(ws + 48 * MB + 256 * 1024); // 12KB
    unsigned short* QKV     = (unsigned short*)(ws + 49 * MB);     // 24MB
    float*          P1      = (float*)(ws + 49 * MB);              // 16MB overlay
    float*          scores  = (float*)(ws + 73 * MB);              // 512KB
    int*            counts  = (int*)(ws + 73 * MB + 512 * 1024);   // 16KB
    int*            offs    = (int*)(ws + 73 * MB + 528 * 1024);   // 16KB
    int*            cursor  = (int*)(ws + 73 * MB + 544 * 1024);   // 16KB
    int*            perm    = (int*)(ws + 74 * MB);                // 512KB
    unsigned short* Obf     = (unsigned short*)(ws + 75 * MB);     // 8MB
    float*          P0      = (float*)(ws + 83 * MB);              // 16MB
    float*          Out_f32 = (float*)(ws + 99 * MB);              // 16MB
    unsigned short* Out_b16 = (unsigned short*)(ws + 115 * MB);    // 8MB

    const dim3 blk(256);

    // weight prep
    transpose_f32_to_bf16<<<dim3(32, 32), blk, 0, stream>>>(Wq, Wqkv_t, 1024, 1024);
    transpose_f32_to_bf16<<<dim3(32, 32), blk, 0, stream>>>(Wk, Wqkv_t + 1024 * 1024, 1024, 1024);
    transpose_f32_to_bf16<<<dim3(32, 32), blk, 0, stream>>>(Wv, Wqkv_t + 2 * 1024 * 1024, 1024, 1024);
    transpose_f32_to_bf16<<<dim3(32, 32), blk, 0, stream>>>(Wo, Wo_t, 1024, 1024);
    transpose_f32_to_bf16<<<dim3(128, 32), blk, 0, stream>>>(W1, W1_t, 1024, 4096);
    transpose_f32_to_bf16<<<dim3(32, 128), blk, 0, stream>>>(W2, W2_t, 4096, 1024);
    f32_to_bf16_kernel<<<256, blk, 0, stream>>>(rel_tbl, relb, R_REL * 1024);
    build_bqkv<<<12, blk, 0, stream>>>(bq, bqkv);

    // LN0
    ln_kernel<0><<<M_ROWS, blk, 0, stream>>>(hidden, nullptr, nullptr, ln0_g, ln0_b,
                                             Xn_f32, Xn_b16, nullptr, nullptr);
    // QKV fused GEMM: [4096,1024] x [1024,3072]
    gemm_bf16<true, false><<<dim3(24, 32), blk, 0, stream>>>(Xn_b16, Wqkv_t, bqkv,
                                                             nullptr, QKV, 3072, 1024);
    // CSR build
    zero_ints<<<16, blk, 0, stream>>>(counts, 4096);
    count_kernel<<<512, blk, 0, stream>>>(edst, counts);
    scan_kernel<<<4, 1024, 0, stream>>>(counts, offs, cursor);
    scatter_kernel<<<512, blk, 0, stream>>>(edst, cursor, perm);
    // scores + aggregation
    edge_score<<<32768, blk, 0, stream>>>(QKV, relb, esrc, edst, erel, scores);
    edge_agg<<<M_ROWS, blk, 0, stream>>>(QKV, relb, scores, esrc, erel, perm, offs, counts, Obf);
    // o @ Wo + bo  (split-K=2 -> P0,P1)
    gemm_bf16_splitk<<<dim3(8, 32, 2), blk, 0, stream>>>(Obf, Wo_t, bo, P0, P1, 1024, 1024, 512);
    // LN1(x + P0 + P1)
    ln_kernel<1><<<M_ROWS, blk, 0, stream>>>(Xn_f32, P0, P1, ln1_g, ln1_b,
                                             Out_f32, Out_b16, nullptr, nullptr);
    // FFN
    gemm_bf16<true, true><<<dim3(32, 32), blk, 0, stream>>>(Out_b16, W1_t, b1,
                                                            nullptr, H1, 4096, 1024);
    gemm_bf16_splitk<<<dim3(8, 32, 2), blk, 0, stream>>>(H1, W2_t, b2, P0, P1, 1024, 4096, 2048);
    // LN2 + elu + residual
    ln_kernel<2><<<M_ROWS, blk, 0, stream>>>(Out_f32, P0, P1, ln2_g, ln2_b,
                                             nullptr, nullptr, hidden, out);
    (void)in_sizes; (void)n_in; (void)out_size; (void)ws_size;
}

// Round 3
// 463.214 us; speedup vs baseline: 1.0646x; 1.0160x over previous
//
#include <hip/hip_runtime.h>
#include <hip/hip_bf16.h>

#define B_SZ 4
#define L_SEQ 1024
#define D_MODEL 1024
#define DF_FF 4096
#define E_PER_B 32768
#define R_REL 64
#define M_ROWS (B_SZ * L_SEQ)   // 4096

typedef __attribute__((ext_vector_type(8))) short bf16x8;
typedef __attribute__((ext_vector_type(4))) float f32x4;

__device__ inline float b2f(unsigned short u) {
    union { unsigned int i; float f; } x; x.i = ((unsigned int)u) << 16; return x.f;
}
__device__ inline unsigned short f2b(float f) {
    union { float f; unsigned int u; } x; x.f = f;
    unsigned int r = x.u + 0x7FFFu + ((x.u >> 16) & 1u);
    return (unsigned short)(r >> 16);
}

#define GLOBAL_CAST(p) ((const __attribute__((address_space(1))) void*)(p))
#define LDS_CAST(p)    ((__attribute__((address_space(3))) void*)(p))

// ---------------- transpose + f32->bf16: W[K,N] -> Wt[N,K] ----------------
__global__ void transpose_f32_to_bf16(const float* __restrict__ W,
                                      unsigned short* __restrict__ Wt,
                                      int K, int N) {
    __shared__ float tile[32][33];
    int n0 = blockIdx.x * 32, k0 = blockIdx.y * 32;
    int tx = threadIdx.x & 31, ty = threadIdx.x >> 5;   // 32 x 8
#pragma unroll
    for (int r = 0; r < 32; r += 8)
        tile[ty + r][tx] = W[(size_t)(k0 + ty + r) * N + (n0 + tx)];
    __syncthreads();
#pragma unroll
    for (int r = 0; r < 32; r += 8)
        Wt[(size_t)(n0 + ty + r) * K + (k0 + tx)] = f2b(tile[tx][ty + r]);
}

__global__ void f32_to_bf16_kernel(const float* __restrict__ in,
                                   unsigned short* __restrict__ out, int n) {
    int i = blockIdx.x * 256 + threadIdx.x;
    if (i < n) out[i] = f2b(in[i]);
}

__global__ void build_bqkv(const float* __restrict__ bq, float* __restrict__ bqkv) {
    int i = blockIdx.x * 256 + threadIdx.x;   // grid covers 3072
    bqkv[i] = (i < 1024) ? bq[i] : 0.0f;
}

__global__ void zero_ints(int* __restrict__ p, int n) {
    int i = blockIdx.x * 256 + threadIdx.x;
    if (i < n) p[i] = 0;
}

// XCD-aware tile swizzle: XCD = linear_id % 8 (round-robin heuristic). Group all
// tile_n of a given tile_m onto ONE XCD so its L2 caches the A-tile once.
// Requires ntm % 8 == 0 (all our GEMMs have ntm=32).
__device__ inline void tile_swizzle(int id, int ntn, int& tm, int& tn) {
    tm = ((id & 7) + ((id >> 3) / ntn) * 8) * 128;
    tn = ((id >> 3) % ntn) * 128;
}

// ---------------- GEMM: C[M,N] = A[M,K](bf16) * Bt[N,K](bf16)^T + bias ----------------
// LDS: XOR-swizzled 16B chunks (slot s of row r holds chunk s ^ ((r>>1)&3)) -> 0 bank conflicts.
template<bool OUT_BF16, bool RELU>
__global__ __launch_bounds__(256, 2)
void gemm_bf16(const unsigned short* __restrict__ A,
               const unsigned short* __restrict__ Bt,
               const float* __restrict__ bias,
               float* __restrict__ Cf,
               unsigned short* __restrict__ Cb,
               int N, int K, int ntn) {
    __shared__ unsigned short lA[128 * 32];
    __shared__ unsigned short lB[128 * 32];
    int tile_m, tile_n;
    tile_swizzle(blockIdx.x, ntn, tile_m, tile_n);
    const int t = threadIdx.x;
    const int wave = t >> 6, lane = t & 63;
    const int wm = (wave >> 1) * 64, wn = (wave & 1) * 64;
    const int quad = lane >> 4, l16 = lane & 15;

    const int srow = wave * 16 + (lane >> 2);
    const int scol = ((lane & 3) ^ ((lane >> 3) & 3)) * 8;
    const unsigned short* gA = A + (size_t)(tile_m + srow) * K + scol;
    const unsigned short* gB = Bt + (size_t)(tile_n + srow) * K + scol;

    const int rcha = (quad ^ ((l16 >> 1) & 3)) * 8;   // read-side swizzled chunk

    f32x4 acc[4][4];
#pragma unroll
    for (int i = 0; i < 4; i++)
#pragma unroll
        for (int j = 0; j < 4; j++) acc[i][j] = (f32x4)0.0f;

    for (int k0 = 0; k0 < K; k0 += 32) {
        __syncthreads();
#pragma unroll
        for (int r = 0; r < 2; ++r) {
            __builtin_amdgcn_global_load_lds(GLOBAL_CAST(gA + (size_t)r * 64 * K),
                                             LDS_CAST(&lA[(r * 64 + wave * 16) * 32]), 16, 0, 0);
            __builtin_amdgcn_global_load_lds(GLOBAL_CAST(gB + (size_t)r * 64 * K),
                                             LDS_CAST(&lB[(r * 64 + wave * 16) * 32]), 16, 0, 0);
        }
        gA += 32; gB += 32;
        __builtin_amdgcn_s_waitcnt(0);
        __syncthreads();

        bf16x8 af[4], bf[4];
#pragma unroll
        for (int i = 0; i < 4; i++) {
            af[i] = *(const bf16x8*)&lA[(wm + i * 16 + l16) * 32 + rcha];
            bf[i] = *(const bf16x8*)&lB[(wn + i * 16 + l16) * 32 + rcha];
        }
#pragma unroll
        for (int mi = 0; mi < 4; mi++)
#pragma unroll
            for (int ni = 0; ni < 4; ni++)
                acc[mi][ni] = __builtin_amdgcn_mfma_f32_16x16x32_bf16(af[mi], bf[ni], acc[mi][ni], 0, 0, 0);
    }

#pragma unroll
    for (int mi = 0; mi < 4; mi++) {
#pragma unroll
        for (int ni = 0; ni < 4; ni++) {
            const int col = tile_n + wn + ni * 16 + l16;
            const float bv = bias[col];
#pragma unroll
            for (int r = 0; r < 4; r++) {
                const int row = tile_m + wm + mi * 16 + quad * 4 + r;
                float v = acc[mi][ni][r] + bv;
                if (RELU) v = fmaxf(v, 0.0f);
                if (OUT_BF16) Cb[(size_t)row * N + col] = f2b(v);
                else          Cf[(size_t)row * N + col] = v;
            }
        }
    }
}

// split-K variant: blockIdx.z = z chunk over K-range [z*Kc,(z+1)*Kc);
// writes f32 partial to Pbase + z*pstride; bias folded into chunk 0.
__global__ __launch_bounds__(256, 2)
void gemm_bf16_splitk(const unsigned short* __restrict__ A,
                      const unsigned short* __restrict__ Bt,
                      const float* __restrict__ bias,
                      float* __restrict__ Pbase, size_t pstride,
                      int N, int K, int Kc, int ntn) {
    __shared__ unsigned short lA[128 * 32];
    __shared__ unsigned short lB[128 * 32];
    int tile_m, tile_n;
    tile_swizzle(blockIdx.x, ntn, tile_m, tile_n);
    const int z = blockIdx.z;
    const int t = threadIdx.x;
    const int wave = t >> 6, lane = t & 63;
    const int wm = (wave >> 1) * 64, wn = (wave & 1) * 64;
    const int quad = lane >> 4, l16 = lane & 15;

    const int srow = wave * 16 + (lane >> 2);
    const int scol = ((lane & 3) ^ ((lane >> 3) & 3)) * 8;
    const unsigned short* gA = A + (size_t)(tile_m + srow) * K + z * Kc + scol;
    const unsigned short* gB = Bt + (size_t)(tile_n + srow) * K + z * Kc + scol;

    const int rcha = (quad ^ ((l16 >> 1) & 3)) * 8;

    f32x4 acc[4][4];
#pragma unroll
    for (int i = 0; i < 4; i++)
#pragma unroll
        for (int j = 0; j < 4; j++) acc[i][j] = (f32x4)0.0f;

    for (int k0 = 0; k0 < Kc; k0 += 32) {
        __syncthreads();
#pragma unroll
        for (int r = 0; r < 2; ++r) {
            __builtin_amdgcn_global_load_lds(GLOBAL_CAST(gA + (size_t)r * 64 * K),
                                             LDS_CAST(&lA[(r * 64 + wave * 16) * 32]), 16, 0, 0);
            __builtin_amdgcn_global_load_lds(GLOBAL_CAST(gB + (size_t)r * 64 * K),
                                             LDS_CAST(&lB[(r * 64 + wave * 16) * 32]), 16, 0, 0);
        }
        gA += 32; gB += 32;
        __builtin_amdgcn_s_waitcnt(0);
        __syncthreads();

        bf16x8 af[4], bf[4];
#pragma unroll
        for (int i = 0; i < 4; i++) {
            af[i] = *(const bf16x8*)&lA[(wm + i * 16 + l16) * 32 + rcha];
            bf[i] = *(const bf16x8*)&lB[(wn + i * 16 + l16) * 32 + rcha];
        }
#pragma unroll
        for (int mi = 0; mi < 4; mi++)
#pragma unroll
            for (int ni = 0; ni < 4; ni++)
                acc[mi][ni] = __builtin_amdgcn_mfma_f32_16x16x32_bf16(af[mi], bf[ni], acc[mi][ni], 0, 0, 0);
    }

    float* P = Pbase + (size_t)z * pstride;
#pragma unroll
    for (int mi = 0; mi < 4; mi++) {
#pragma unroll
        for (int ni = 0; ni < 4; ni++) {
            const int col = tile_n + wn + ni * 16 + l16;
            const float bv = (z == 0) ? bias[col] : 0.0f;
#pragma unroll
            for (int r = 0; r < 4; r++) {
                const int row = tile_m + wm + mi * 16 + quad * 4 + r;
                P[(size_t)row * N + col] = acc[mi][ni][r] + bv;
            }
        }
    }
}

// ---------------- LayerNorm family ----------------
// MODE 0 (NR=0): y = LN(X_f32)                          -> of32 + ob16
// MODE 1 (NR=2): y = LN(X_f32 + sum partials)           -> ob16 only
// MODE 2 (NR=4): y = LN(X_bf16 + sum partials); fout = hidden + elu(y)
template<int MODE, int NR>
__global__ void ln_kernel(const float* __restrict__ X, const unsigned short* __restrict__ Xb,
                          const float* __restrict__ Rbase, size_t rstride,
                          const float* __restrict__ g, const float* __restrict__ be,
                          float* __restrict__ of32, unsigned short* __restrict__ ob16,
                          const float* __restrict__ hidden, float* __restrict__ fout) {
    __shared__ float sb1[4], sb2[4];
    const int row = blockIdx.x, t = threadIdx.x;
    const size_t base = (size_t)row * 1024 + t * 4;

    float x0, x1, x2, x3;
    if (MODE == 2) {
        ushort4 xv = *(const ushort4*)(Xb + base);
        x0 = b2f(xv.x); x1 = b2f(xv.y); x2 = b2f(xv.z); x3 = b2f(xv.w);
    } else {
        float4 xv = *(const float4*)(X + base);
        x0 = xv.x; x1 = xv.y; x2 = xv.z; x3 = xv.w;
    }
#pragma unroll
    for (int r = 0; r < NR; r++) {
        float4 rv = *(const float4*)(Rbase + r * rstride + base);
        x0 += rv.x; x1 += rv.y; x2 += rv.z; x3 += rv.w;
    }
    float s = x0 + x1 + x2 + x3;
#pragma unroll
    for (int o = 32; o > 0; o >>= 1) s += __shfl_down(s, o);
    if ((t & 63) == 0) sb1[t >> 6] = s;
    __syncthreads();
    const float mu = (sb1[0] + sb1[1] + sb1[2] + sb1[3]) * (1.0f / 1024.0f);

    const float d0 = x0 - mu, d1 = x1 - mu, d2 = x2 - mu, d3 = x3 - mu;
    float s2 = d0 * d0 + d1 * d1 + d2 * d2 + d3 * d3;
#pragma unroll
    for (int o = 32; o > 0; o >>= 1) s2 += __shfl_down(s2, o);
    if ((t & 63) == 0) sb2[t >> 6] = s2;
    __syncthreads();
    const float var = (sb2[0] + sb2[1] + sb2[2] + sb2[3]) * (1.0f / 1024.0f);
    const float rstd = rsqrtf(var + 1e-6f);

    const float4 gv = *(const float4*)(g + t * 4);
    const float4 bv = *(const float4*)(be + t * 4);
    const float y0 = d0 * rstd * gv.x + bv.x;
    const float y1 = d1 * rstd * gv.y + bv.y;
    const float y2 = d2 * rstd * gv.z + bv.z;
    const float y3 = d3 * rstd * gv.w + bv.w;

    if (MODE == 0) {
        float4 o; o.x = y0; o.y = y1; o.z = y2; o.w = y3;
        *(float4*)(of32 + base) = o;
    }
    if (MODE <= 1) {
        ushort4 ob; ob.x = f2b(y0); ob.y = f2b(y1); ob.z = f2b(y2); ob.w = f2b(y3);
        *(ushort4*)(ob16 + base) = ob;
    } else {
        const float4 hv = *(const float4*)(hidden + base);
        const float e0 = y0 > 0.0f ? y0 : expm1f(y0);
        const float e1 = y1 > 0.0f ? y1 : expm1f(y1);
        const float e2 = y2 > 0.0f ? y2 : expm1f(y2);
        const float e3 = y3 > 0.0f ? y3 : expm1f(y3);
        float4 o; o.x = hv.x + e0; o.y = hv.y + e1; o.z = hv.z + e2; o.w = hv.w + e3;
        *(float4*)(fout + base) = o;
    }
}

// ---------------- edge pipeline ----------------
__global__ void count_kernel(const int* __restrict__ dst, int* __restrict__ counts) {
    int g = blockIdx.x * 256 + threadIdx.x;   // exactly B*E
    int b = g >> 15;
    atomicAdd(&counts[(b << 10) + dst[g]], 1);
}

__global__ void scan_kernel(const int* __restrict__ counts, int* __restrict__ offs,
                            int* __restrict__ cursor) {
    __shared__ int buf[1024];
    const int b = blockIdx.x, t = threadIdx.x;
    const int c = counts[b * 1024 + t];
    buf[t] = c;
    __syncthreads();
    for (int o = 1; o < 1024; o <<= 1) {
        int v = (t >= o) ? buf[t - o] : 0;
        __syncthreads();
        buf[t] += v;
        __syncthreads();
    }
    const int ex = buf[t] - c;
    offs[b * 1024 + t] = ex;
    cursor[b * 1024 + t] = ex;
}

__global__ void scatter_kernel(const int* __restrict__ dst, int* __restrict__ cursor,
                               int* __restrict__ perm) {
    int g = blockIdx.x * 256 + threadIdx.x;
    int b = g >> 15;
    int pos = atomicAdd(&cursor[(b << 10) + dst[g]], 1);
    perm[((size_t)b << 15) + pos] = g & (E_PER_B - 1);
}

// one wave per edge: score = exp(clip(dot(k[src]+e, q[dst]) / 32, +-10))
__global__ void edge_score(const unsigned short* __restrict__ QKV,   // [M,3072] q|k|v
                           const unsigned short* __restrict__ relb,  // [R,1024]
                           const int* __restrict__ src, const int* __restrict__ dstA,
                           const int* __restrict__ rel,
                           float* __restrict__ scores) {
    const int gw = (blockIdx.x * 256 + threadIdx.x) >> 6;
    const int lane = threadIdx.x & 63;
    const int b = gw >> 15;
    const int s = src[gw], d = dstA[gw], r = rel[gw];
    const unsigned short* kr = QKV + ((size_t)((b << 10) + s)) * 3072 + 1024;
    const unsigned short* qr = QKV + ((size_t)((b << 10) + d)) * 3072;
    const unsigned short* er = relb + (size_t)r * 1024;
    float acc = 0.0f;
#pragma unroll
    for (int j = 0; j < 4; j++) {
        const int off = j * 256 + lane * 4;
        const ushort4 kv = *(const ushort4*)(kr + off);
        const ushort4 qv = *(const ushort4*)(qr + off);
        const ushort4 ev = *(const ushort4*)(er + off);
        acc += (b2f(kv.x) + b2f(ev.x)) * b2f(qv.x);
        acc += (b2f(kv.y) + b2f(ev.y)) * b2f(qv.y);
        acc += (b2f(kv.z) + b2f(ev.z)) * b2f(qv.z);
        acc += (b2f(kv.w) + b2f(ev.w)) * b2f(qv.w);
    }
#pragma unroll
    for (int o = 32; o > 0; o >>= 1) acc += __shfl_down(acc, o);
    if (lane == 0) {
        float sc = acc * (1.0f / 32.0f);
        sc = fminf(fmaxf(sc, -10.0f), 10.0f);
        scores[gw] = expf(sc);
    }
}

// one block per (b,node): o[node] = sum_e (v[src]+e)*score / sum_e score
__global__ void edge_agg(const unsigned short* __restrict__ QKV,
                         const unsigned short* __restrict__ relb,
                         const float* __restrict__ scores,
                         const int* __restrict__ src, const int* __restrict__ rel,
                         const int* __restrict__ perm, const int* __restrict__ offs,
                         const int* __restrict__ counts,
                         unsigned short* __restrict__ O) {
    const int node = blockIdx.x;          // b*1024 + l
    const int b = node >> 10;
    const int t = threadIdx.x;
    const int start = offs[node], cnt = counts[node];
    const int base = b << 15;
    float a0 = 0, a1 = 0, a2 = 0, a3 = 0, z = 0;
    for (int j = 0; j < cnt; j++) {
        const int ei = perm[(size_t)base + start + j];
        const float sc = scores[base + ei];
        const int s = src[base + ei], r = rel[base + ei];
        const ushort4 vv = *(const ushort4*)(QKV + ((size_t)((b << 10) + s)) * 3072 + 2048 + t * 4);
        const ushort4 ev = *(const ushort4*)(relb + (size_t)r * 1024 + t * 4);
        a0 += (b2f(vv.x) + b2f(ev.x)) * sc;
        a1 += (b2f(vv.y) + b2f(ev.y)) * sc;
        a2 += (b2f(vv.z) + b2f(ev.z)) * sc;
        a3 += (b2f(vv.w) + b2f(ev.w)) * sc;
        z += sc;
    }
    const float inv = 1.0f / z;
    const size_t ob = (size_t)node * 1024 + t * 4;
    ushort4 o4;
    o4.x = f2b(a0 * inv); o4.y = f2b(a1 * inv); o4.z = f2b(a2 * inv); o4.w = f2b(a3 * inv);
    *(ushort4*)(O + ob) = o4;
}

// ---------------- launch ----------------
extern "C" void kernel_launch(void* const* d_in, const int* in_sizes, int n_in,
                              void* d_out, int out_size, void* d_ws, size_t ws_size,
                              hipStream_t stream) {
    const float* hidden  = (const float*)d_in[0];
    const float* rel_tbl = (const float*)d_in[1];
    const float* Wq = (const float*)d_in[2];
    const float* bq = (const float*)d_in[3];
    const float* Wk = (const float*)d_in[4];
    const float* Wv = (const float*)d_in[5];
    const float* Wo = (const float*)d_in[6];
    const float* bo = (const float*)d_in[7];
    const float* ln0_g = (const float*)d_in[8];
    const float* ln0_b = (const float*)d_in[9];
    const float* ln1_g = (const float*)d_in[10];
    const float* ln1_b = (const float*)d_in[11];
    const float* W1 = (const float*)d_in[12];
    const float* b1 = (const float*)d_in[13];
    const float* W2 = (const float*)d_in[14];
    const float* b2 = (const float*)d_in[15];
    const float* ln2_g = (const float*)d_in[16];
    const float* ln2_b = (const float*)d_in[17];
    const int* esrc = (const int*)d_in[18];
    const int* edst = (const int*)d_in[19];
    const int* erel = (const int*)d_in[20];
    float* out = (float*)d_out;

    // ws lifetime overlay (max 121MB):
    //  0-16  Xn_f32 (LN0->LN1)        0-32 H1 (FFN1->W2, overlays Xn after LN1)
    // 16-24  Xn_b16 (LN0->QKV)
    // 24-30  Wqkv_t   30-32 Wo_t   32-40 W1_t   40-48 W2_t
    // 48-49  relb + bqkv (->edge_agg)
    // 49-73  QKV (QKVgemm->edge_agg);  49-57 Out_b16 (LN1->FFN1,LN2) overlays
    // 57-121 Qw2: 4 x 16MB W2 split-K partials (W2->LN2), overlays QKV tail/scores/perm/Obf/Pwo
    // 73-74  scores+counts/offs/cursor   74-74.5 perm (CSR->edge_agg)
    // 75-83  Obf (edge_agg->Wo)
    // 83-115 Pwo: 2 x 16MB Wo split-K partials (Wo->LN1)
    char* ws = (char*)d_ws;
    const size_t MB = 1024 * 1024;
    float*          Xn_f32  = (float*)(ws + 0);
    unsigned short* Xn_b16  = (unsigned short*)(ws + 16 * MB);
    unsigned short* H1      = (unsigned short*)(ws + 0);
    unsigned short* Wqkv_t  = (unsigned short*)(ws + 24 * MB);
    unsigned short* Wo_t    = (unsigned short*)(ws + 30 * MB);
    unsigned short* W1_t    = (unsigned short*)(ws + 32 * MB);
    unsigned short* W2_t    = (unsigned short*)(ws + 40 * MB);
    unsigned short* relb    = (unsigned short*)(ws + 48 * MB);
    float*          bqkv    = (float*)(ws + 48 * MB + 256 * 1024);
    unsigned short* QKV     = (unsigned short*)(ws + 49 * MB);
    unsigned short* Out_b16 = (unsigned short*)(ws + 49 * MB);
    float*          Qw2     = (float*)(ws + 57 * MB);
    float*          scores  = (float*)(ws + 73 * MB);
    int*            counts  = (int*)(ws + 73 * MB + 512 * 1024);
    int*            offs    = (int*)(ws + 73 * MB + 528 * 1024);
    int*            cursor  = (int*)(ws + 73 * MB + 544 * 1024);
    int*            perm    = (int*)(ws + 74 * MB);
    unsigned short* Obf     = (unsigned short*)(ws + 75 * MB);
    float*          Pwo     = (float*)(ws + 83 * MB);

    const size_t PSTRIDE = 4u * 1024 * 1024;   // 16MB / sizeof(float)
    const dim3 blk(256);

    // weight prep
    transpose_f32_to_bf16<<<dim3(32, 32), blk, 0, stream>>>(Wq, Wqkv_t, 1024, 1024);
    transpose_f32_to_bf16<<<dim3(32, 32), blk, 0, stream>>>(Wk, Wqkv_t + 1024 * 1024, 1024, 1024);
    transpose_f32_to_bf16<<<dim3(32, 32), blk, 0, stream>>>(Wv, Wqkv_t + 2 * 1024 * 1024, 1024, 1024);
    transpose_f32_to_bf16<<<dim3(32, 32), blk, 0, stream>>>(Wo, Wo_t, 1024, 1024);
    transpose_f32_to_bf16<<<dim3(128, 32), blk, 0, stream>>>(W1, W1_t, 1024, 4096);
    transpose_f32_to_bf16<<<dim3(32, 128), blk, 0, stream>>>(W2, W2_t, 4096, 1024);
    f32_to_bf16_kernel<<<256, blk, 0, stream>>>(rel_tbl, relb, R_REL * 1024);
    build_bqkv<<<12, blk, 0, stream>>>(bq, bqkv);

    // LN0 -> Xn_f32 + Xn_b16
    ln_kernel<0, 0><<<M_ROWS, blk, 0, stream>>>(hidden, nullptr, nullptr, 0, ln0_g, ln0_b,
                                                Xn_f32, Xn_b16, nullptr, nullptr);
    // QKV fused GEMM: [4096,1024] x [1024,3072]
    gemm_bf16<true, false><<<dim3(24 * 32), blk, 0, stream>>>(Xn_b16, Wqkv_t, bqkv,
                                                              nullptr, QKV, 3072, 1024, 24);
    // CSR build
    zero_ints<<<16, blk, 0, stream>>>(counts, 4096);
    count_kernel<<<512, blk, 0, stream>>>(edst, counts);
    scan_kernel<<<4, 1024, 0, stream>>>(counts, offs, cursor);
    scatter_kernel<<<512, blk, 0, stream>>>(edst, cursor, perm);
    // scores + aggregation
    edge_score<<<32768, blk, 0, stream>>>(QKV, relb, esrc, edst, erel, scores);
    edge_agg<<<M_ROWS, blk, 0, stream>>>(QKV, relb, scores, esrc, erel, perm, offs, counts, Obf);
    // o @ Wo + bo  (split-K=2 -> Pwo[0..1])
    gemm_bf16_splitk<<<dim3(8 * 32, 1, 2), blk, 0, stream>>>(Obf, Wo_t, bo, Pwo, PSTRIDE,
                                                             1024, 1024, 512, 8);
    // LN1(x + P0 + P1) -> Out_b16
    ln_kernel<1, 2><<<M_ROWS, blk, 0, stream>>>(Xn_f32, nullptr, Pwo, PSTRIDE, ln1_g, ln1_b,
                                                nullptr, Out_b16, nullptr, nullptr);
    // FFN1: relu(out @ W1 + b1) -> H1
    gemm_bf16<true, true><<<dim3(32 * 32), blk, 0, stream>>>(Out_b16, W1_t, b1,
                                                             nullptr, H1, 4096, 1024, 32);
    // W2: H1 @ W2 + b2 (split-K=4 -> Qw2[0..3])
    gemm_bf16_splitk<<<dim3(8 * 32, 1, 4), blk, 0, stream>>>(H1, W2_t, b2, Qw2, PSTRIDE,
                                                             1024, 4096, 1024, 8);
    // LN2(out + sum Qw2) + elu + residual
    ln_kernel<2, 4><<<M_ROWS, blk, 0, stream>>>(nullptr, Out_b16, Qw2, PSTRIDE, ln2_g, ln2_b,
                                                nullptr, nullptr, hidden, out);
    (void)in_sizes; (void)n_in; (void)out_size; (void)ws_size;
}

// Round 4
// 444.702 us; speedup vs baseline: 1.1089x; 1.0416x over previous
//
#include <hip/hip_runtime.h>
#include <hip/hip_bf16.h>

#define B_SZ 4
#define L_SEQ 1024
#define D_MODEL 1024
#define DF_FF 4096
#define E_PER_B 32768
#define R_REL 64
#define M_ROWS (B_SZ * L_SEQ)   // 4096

typedef __attribute__((ext_vector_type(8))) short bf16x8;
typedef __attribute__((ext_vector_type(4))) float f32x4;

__device__ inline float b2f(unsigned short u) {
    union { unsigned int i; float f; } x; x.i = ((unsigned int)u) << 16; return x.f;
}
__device__ inline unsigned short f2b(float f) {
    union { float f; unsigned int u; } x; x.f = f;
    unsigned int r = x.u + 0x7FFFu + ((x.u >> 16) & 1u);
    return (unsigned short)(r >> 16);
}

#define GLOBAL_CAST(p) ((const __attribute__((address_space(1))) void*)(p))
#define LDS_CAST(p)    ((__attribute__((address_space(3))) void*)(p))

// ---------------- transpose + f32->bf16: W[K,N] -> Wt[N,K] ----------------
__global__ void transpose_f32_to_bf16(const float* __restrict__ W,
                                      unsigned short* __restrict__ Wt,
                                      int K, int N) {
    __shared__ float tile[32][33];
    int n0 = blockIdx.x * 32, k0 = blockIdx.y * 32;
    int tx = threadIdx.x & 31, ty = threadIdx.x >> 5;   // 32 x 8
#pragma unroll
    for (int r = 0; r < 32; r += 8)
        tile[ty + r][tx] = W[(size_t)(k0 + ty + r) * N + (n0 + tx)];
    __syncthreads();
#pragma unroll
    for (int r = 0; r < 32; r += 8)
        Wt[(size_t)(n0 + ty + r) * K + (k0 + tx)] = f2b(tile[tx][ty + r]);
}

// V^T per batch: Vt[b][d, s] = QKV[(b<<10)+s, 2048+d]  (bf16)
__global__ void transpose_v_bf16(const unsigned short* __restrict__ QKV,
                                 unsigned short* __restrict__ Vt) {
    __shared__ unsigned short tile[32][33];
    const int b = blockIdx.z;
    const int d0 = blockIdx.x * 32, s0 = blockIdx.y * 32;
    const int tx = threadIdx.x & 31, ty = threadIdx.x >> 5;  // 32 x 8
#pragma unroll
    for (int r = 0; r < 32; r += 8)
        tile[ty + r][tx] = QKV[(size_t)((b << 10) + s0 + ty + r) * 3072 + 2048 + d0 + tx];
    __syncthreads();
#pragma unroll
    for (int r = 0; r < 32; r += 8)
        Vt[(size_t)b * 1048576 + (size_t)(d0 + ty + r) * 1024 + s0 + tx] = tile[tx][ty + r];
}

__global__ void build_bqkv(const float* __restrict__ bq, float* __restrict__ bqkv) {
    int i = blockIdx.x * 256 + threadIdx.x;   // grid covers 3072
    bqkv[i] = (i < 1024) ? bq[i] : 0.0f;
}

// relbPad bf16 [128,1024]: rows 0..63 = rel_table, 64..127 = 0
__global__ void build_relbpad(const float* __restrict__ rel, unsigned short* __restrict__ out) {
    int i = blockIdx.x * 256 + threadIdx.x;  // 131072
    out[i] = (i < 65536) ? f2b(rel[i]) : (unsigned short)0;
}

// relbT bf16 [1024,64]: relbT[d*64+r] = rel[r*1024+d]
__global__ void build_relbT(const float* __restrict__ rel, unsigned short* __restrict__ out) {
    int i = blockIdx.x * 256 + threadIdx.x;  // 65536
    int d = i >> 6, r = i & 63;
    out[i] = f2b(rel[r * 1024 + d]);
}

// XCD-aware tile swizzle: XCD = linear_id % 8. Group all tile_n of a tile_m on one XCD.
__device__ inline void tile_swizzle(int id, int ntn, int& tm, int& tn) {
    tm = ((id & 7) + ((id >> 3) / ntn) * 8) * 128;
    tn = ((id >> 3) % ntn) * 128;
}

// ---------------- GEMM: C[M,N] = A[M,K](bf16, lda) * Bt[N,K](bf16, ldb)^T + bias ----------------
// Bt optionally batched by tile_m>>10 (bt_batch element stride). LDS XOR-swizzled (0 conflicts).
// ACC: C += accin (f32). OUT_BF16 selects Cb vs Cf.
template<bool OUT_BF16, bool RELU, bool ACC>
__global__ __launch_bounds__(256, 2)
void gemm_bf16(const unsigned short* __restrict__ A, int lda,
               const unsigned short* __restrict__ Bt, int ldb, size_t bt_batch,
               const float* __restrict__ bias,
               float* __restrict__ Cf, unsigned short* __restrict__ Cb,
               const float* __restrict__ accin,
               int N, int K, int ntn) {
    __shared__ unsigned short lA[128 * 32];
    __shared__ unsigned short lB[128 * 32];
    int tile_m, tile_n;
    tile_swizzle(blockIdx.x, ntn, tile_m, tile_n);
    const int t = threadIdx.x;
    const int wave = t >> 6, lane = t & 63;
    const int wm = (wave >> 1) * 64, wn = (wave & 1) * 64;
    const int quad = lane >> 4, l16 = lane & 15;

    const int srow = wave * 16 + (lane >> 2);
    const int scol = ((lane & 3) ^ ((lane >> 3) & 3)) * 8;
    const unsigned short* gA = A + (size_t)(tile_m + srow) * lda + scol;
    const unsigned short* gB = Bt + (size_t)(tile_m >> 10) * bt_batch
                                  + (size_t)(tile_n + srow) * ldb + scol;

    const int rcha = (quad ^ ((l16 >> 1) & 3)) * 8;

    f32x4 acc[4][4];
#pragma unroll
    for (int i = 0; i < 4; i++)
#pragma unroll
        for (int j = 0; j < 4; j++) acc[i][j] = (f32x4)0.0f;

    for (int k0 = 0; k0 < K; k0 += 32) {
        __syncthreads();
#pragma unroll
        for (int r = 0; r < 2; ++r) {
            __builtin_amdgcn_global_load_lds(GLOBAL_CAST(gA + (size_t)r * 64 * lda),
                                             LDS_CAST(&lA[(r * 64 + wave * 16) * 32]), 16, 0, 0);
            __builtin_amdgcn_global_load_lds(GLOBAL_CAST(gB + (size_t)r * 64 * ldb),
                                             LDS_CAST(&lB[(r * 64 + wave * 16) * 32]), 16, 0, 0);
        }
        gA += 32; gB += 32;
        __builtin_amdgcn_s_waitcnt(0);
        __syncthreads();

        bf16x8 af[4], bf[4];
#pragma unroll
        for (int i = 0; i < 4; i++) {
            af[i] = *(const bf16x8*)&lA[(wm + i * 16 + l16) * 32 + rcha];
            bf[i] = *(const bf16x8*)&lB[(wn + i * 16 + l16) * 32 + rcha];
        }
#pragma unroll
        for (int mi = 0; mi < 4; mi++)
#pragma unroll
            for (int ni = 0; ni < 4; ni++)
                acc[mi][ni] = __builtin_amdgcn_mfma_f32_16x16x32_bf16(af[mi], bf[ni], acc[mi][ni], 0, 0, 0);
    }

#pragma unroll
    for (int mi = 0; mi < 4; mi++) {
#pragma unroll
        for (int ni = 0; ni < 4; ni++) {
            const int col = tile_n + wn + ni * 16 + l16;
            const float bv = bias[col];
#pragma unroll
            for (int r = 0; r < 4; r++) {
                const int row = tile_m + wm + mi * 16 + quad * 4 + r;
                float v = acc[mi][ni][r] + bv;
                if (ACC) v += accin[(size_t)row * N + col];
                if (RELU) v = fmaxf(v, 0.0f);
                if (OUT_BF16) Cb[(size_t)row * N + col] = f2b(v);
                else          Cf[(size_t)row * N + col] = v;
            }
        }
    }
}

// split-K: blockIdx.z = z over K-range [z*Kc,(z+1)*Kc); f32 partial at Pbase + z*pstride.
__global__ __launch_bounds__(256, 2)
void gemm_bf16_splitk(const unsigned short* __restrict__ A, int lda,
                      const unsigned short* __restrict__ Bt, int ldb, size_t bt_batch,
                      const float* __restrict__ bias,
                      float* __restrict__ Pbase, size_t pstride,
                      int N, int Kc, int ntn) {
    __shared__ unsigned short lA[128 * 32];
    __shared__ unsigned short lB[128 * 32];
    int tile_m, tile_n;
    tile_swizzle(blockIdx.x, ntn, tile_m, tile_n);
    const int z = blockIdx.z;
    const int kofs = z * Kc;
    const int t = threadIdx.x;
    const int wave = t >> 6, lane = t & 63;
    const int wm = (wave >> 1) * 64, wn = (wave & 1) * 64;
    const int quad = lane >> 4, l16 = lane & 15;

    const int srow = wave * 16 + (lane >> 2);
    const int scol = ((lane & 3) ^ ((lane >> 3) & 3)) * 8;
    const unsigned short* gA = A + (size_t)(tile_m + srow) * lda + kofs + scol;
    const unsigned short* gB = Bt + (size_t)(tile_m >> 10) * bt_batch
                                  + (size_t)(tile_n + srow) * ldb + kofs + scol;

    const int rcha = (quad ^ ((l16 >> 1) & 3)) * 8;

    f32x4 acc[4][4];
#pragma unroll
    for (int i = 0; i < 4; i++)
#pragma unroll
        for (int j = 0; j < 4; j++) acc[i][j] = (f32x4)0.0f;

    for (int k0 = 0; k0 < Kc; k0 += 32) {
        __syncthreads();
#pragma unroll
        for (int r = 0; r < 2; ++r) {
            __builtin_amdgcn_global_load_lds(GLOBAL_CAST(gA + (size_t)r * 64 * lda),
                                             LDS_CAST(&lA[(r * 64 + wave * 16) * 32]), 16, 0, 0);
            __builtin_amdgcn_global_load_lds(GLOBAL_CAST(gB + (size_t)r * 64 * ldb),
                                             LDS_CAST(&lB[(r * 64 + wave * 16) * 32]), 16, 0, 0);
        }
        gA += 32; gB += 32;
        __builtin_amdgcn_s_waitcnt(0);
        __syncthreads();

        bf16x8 af[4], bf[4];
#pragma unroll
        for (int i = 0; i < 4; i++) {
            af[i] = *(const bf16x8*)&lA[(wm + i * 16 + l16) * 32 + rcha];
            bf[i] = *(const bf16x8*)&lB[(wn + i * 16 + l16) * 32 + rcha];
        }
#pragma unroll
        for (int mi = 0; mi < 4; mi++)
#pragma unroll
            for (int ni = 0; ni < 4; ni++)
                acc[mi][ni] = __builtin_amdgcn_mfma_f32_16x16x32_bf16(af[mi], bf[ni], acc[mi][ni], 0, 0, 0);
    }

    float* P = Pbase + (size_t)z * pstride;
#pragma unroll
    for (int mi = 0; mi < 4; mi++) {
#pragma unroll
        for (int ni = 0; ni < 4; ni++) {
            const int col = tile_n + wn + ni * 16 + l16;
            const float bv = (z == 0) ? bias[col] : 0.0f;
#pragma unroll
            for (int r = 0; r < 4; r++) {
                const int row = tile_m + wm + mi * 16 + quad * 4 + r;
                P[(size_t)row * N + col] = acc[mi][ni][r] + bv;
            }
        }
    }
}

// ---------------- LayerNorm family ----------------
// MODE 0 (NR=0): y = LN(X_f32)                      -> of32 + ob16
// MODE 1 (NR=2): y = LN(X_f32 + sum NR partials)    -> ob16
// MODE 2 (NR=4): y = LN(X_bf16 + sum NR partials); fout = hidden + elu(y)
template<int MODE, int NR>
__global__ void ln_kernel(const float* __restrict__ X, const unsigned short* __restrict__ Xb,
                          const float* __restrict__ Rbase, size_t rstride,
                          const float* __restrict__ g, const float* __restrict__ be,
                          float* __restrict__ of32, unsigned short* __restrict__ ob16,
                          const float* __restrict__ hidden, float* __restrict__ fout) {
    __shared__ float sb1[4], sb2[4];
    const int row = blockIdx.x, t = threadIdx.x;
    const size_t base = (size_t)row * 1024 + t * 4;

    float x0, x1, x2, x3;
    if (MODE == 2) {
        ushort4 xv = *(const ushort4*)(Xb + base);
        x0 = b2f(xv.x); x1 = b2f(xv.y); x2 = b2f(xv.z); x3 = b2f(xv.w);
    } else {
        float4 xv = *(const float4*)(X + base);
        x0 = xv.x; x1 = xv.y; x2 = xv.z; x3 = xv.w;
    }
#pragma unroll
    for (int r = 0; r < NR; r++) {
        float4 rv = *(const float4*)(Rbase + r * rstride + base);
        x0 += rv.x; x1 += rv.y; x2 += rv.z; x3 += rv.w;
    }
    float s = x0 + x1 + x2 + x3;
#pragma unroll
    for (int o = 32; o > 0; o >>= 1) s += __shfl_down(s, o);
    if ((t & 63) == 0) sb1[t >> 6] = s;
    __syncthreads();
    const float mu = (sb1[0] + sb1[1] + sb1[2] + sb1[3]) * (1.0f / 1024.0f);

    const float d0 = x0 - mu, d1 = x1 - mu, d2 = x2 - mu, d3 = x3 - mu;
    float s2 = d0 * d0 + d1 * d1 + d2 * d2 + d3 * d3;
#pragma unroll
    for (int o = 32; o > 0; o >>= 1) s2 += __shfl_down(s2, o);
    if ((t & 63) == 0) sb2[t >> 6] = s2;
    __syncthreads();
    const float var = (sb2[0] + sb2[1] + sb2[2] + sb2[3]) * (1.0f / 1024.0f);
    const float rstd = rsqrtf(var + 1e-6f);

    const float4 gv = *(const float4*)(g + t * 4);
    const float4 bv = *(const float4*)(be + t * 4);
    const float y0 = d0 * rstd * gv.x + bv.x;
    const float y1 = d1 * rstd * gv.y + bv.y;
    const float y2 = d2 * rstd * gv.z + bv.z;
    const float y3 = d3 * rstd * gv.w + bv.w;

    if (MODE == 0) {
        float4 o; o.x = y0; o.y = y1; o.z = y2; o.w = y3;
        *(float4*)(of32 + base) = o;
    }
    if (MODE <= 1) {
        ushort4 ob; ob.x = f2b(y0); ob.y = f2b(y1); ob.z = f2b(y2); ob.w = f2b(y3);
        *(ushort4*)(ob16 + base) = ob;
    } else {
        const float4 hv = *(const float4*)(hidden + base);
        const float e0 = y0 > 0.0f ? y0 : expm1f(y0);
        const float e1 = y1 > 0.0f ? y1 : expm1f(y1);
        const float e2 = y2 > 0.0f ? y2 : expm1f(y2);
        const float e3 = y3 > 0.0f ? y3 : expm1f(y3);
        float4 o; o.x = hv.x + e0; o.y = hv.y + e1; o.z = hv.z + e2; o.w = hv.w + e3;
        *(float4*)(fout + base) = o;
    }
}

// ---------------- dense edge phase ----------------
// per edge: sc = exp(clip((S[src,dst] + T[dst,r])/32)); A[dst,src] += sc; G[dst,r] += sc
__global__ void edge_scatter(const float* __restrict__ S0, const float* __restrict__ S1,
                             const float* __restrict__ T,
                             const int* __restrict__ src, const int* __restrict__ dst,
                             const int* __restrict__ rel,
                             float* __restrict__ A, float* __restrict__ G) {
    const int gg = blockIdx.x * 256 + threadIdx.x;   // B*E = 131072
    const int b = gg >> 15;
    const int s = src[gg], d = dst[gg], r = rel[gg];
    const size_t srow = (size_t)((b << 10) + s) * 1024 + d;
    const float sval = S0[srow] + S1[srow];
    const float tval = T[(size_t)((b << 10) + d) * 128 + r];
    float sc = (sval + tval) * (1.0f / 32.0f);
    sc = expf(fminf(fmaxf(sc, -10.0f), 10.0f));
    atomicAdd(&A[((size_t)((b << 10) + d) << 10) + s], sc);
    atomicAdd(&G[((size_t)((b << 10) + d) << 6) + r], sc);
}

// per node: z = sum_r G[node,r]; rz[node] = 1/z; Gn[node,r] = bf16(G[node,r]/z)
__global__ void zrow_convG(const float* __restrict__ G, float* __restrict__ rz,
                           unsigned short* __restrict__ Gn) {
    const int node = blockIdx.x * 4 + (threadIdx.x >> 6);
    const int lane = threadIdx.x & 63;
    const float v = G[(size_t)node * 64 + lane];
    float s = v;
#pragma unroll
    for (int o = 1; o < 64; o <<= 1) s += __shfl_xor(s, o);
    const float inv = 1.0f / s;
    Gn[(size_t)node * 64 + lane] = f2b(v * inv);
    if (lane == 0) rz[node] = inv;
}

// An[row, :] = bf16(A[row, :] * rz[row])
__global__ void convA(const float* __restrict__ A, const float* __restrict__ rz,
                      unsigned short* __restrict__ An) {
    const int row = blockIdx.x, t = threadIdx.x;
    const float r = rz[row];
    const size_t base = (size_t)row * 1024 + t * 4;
    const float4 v = *(const float4*)(A + base);
    ushort4 o;
    o.x = f2b(v.x * r); o.y = f2b(v.y * r); o.z = f2b(v.z * r); o.w = f2b(v.w * r);
    *(ushort4*)(An + base) = o;
}

// ---------------- launch ----------------
extern "C" void kernel_launch(void* const* d_in, const int* in_sizes, int n_in,
                              void* d_out, int out_size, void* d_ws, size_t ws_size,
                              hipStream_t stream) {
    const float* hidden  = (const float*)d_in[0];
    const float* rel_tbl = (const float*)d_in[1];
    const float* Wq = (const float*)d_in[2];
    const float* bq = (const float*)d_in[3];
    const float* Wk = (const float*)d_in[4];
    const float* Wv = (const float*)d_in[5];
    const float* Wo = (const float*)d_in[6];
    const float* bo = (const float*)d_in[7];
    const float* ln0_g = (const float*)d_in[8];
    const float* ln0_b = (const float*)d_in[9];
    const float* ln1_g = (const float*)d_in[10];
    const float* ln1_b = (const float*)d_in[11];
    const float* W1 = (const float*)d_in[12];
    const float* b1 = (const float*)d_in[13];
    const float* W2 = (const float*)d_in[14];
    const float* b2 = (const float*)d_in[15];
    const float* ln2_g = (const float*)d_in[16];
    const float* ln2_b = (const float*)d_in[17];
    const int* esrc = (const int*)d_in[18];
    const int* edst = (const int*)d_in[19];
    const int* erel = (const int*)d_in[20];
    float* out = (float*)d_out;

    // ws lifetime map (peak 121MB), time-ordered overlay:
    //  0-16   Xn_f32 [LN0->LN1]                      ; 0-32 H1 [FFN1->W2]
    // 16-24   Xn_b16 [LN0->QKV] ; Vt [Vtrans->wvA]
    // 24-30   Wqkv_t ; 30-32 Wo_t
    // 32-40   W1_t ; 40-48 W2_t
    // 48-48.25 relbPad ; 48.25-48.375 relbT ; 48.5 bqkv (cols 1024+ = zeros bias)
    // 49-73   QKV [QKVg->S,T,Vtrans] ; 49-65 A,65-66 G,66 rz ; 49-81 Pwo [Wo->LN1] ; 49-113 Qw2 x4 [W2->LN2]
    // 73-89   S0 [S->scatter] ; tmp [wvG->wvA]
    // 89-105  S1 [S->scatter] ; 89-97 Obf [wvA->Wo] ; 97-105 An [convA->wvA]
    // 105-107 T [T->scatter] ; 105-105.5 Gn [zrowG->wvG]
    // 113-121 Out_b16 [LN1->FFN1,LN2]
    char* ws = (char*)d_ws;
    const size_t MB = 1024 * 1024;
    float*          Xn_f32  = (float*)(ws + 0);
    unsigned short* Xn_b16  = (unsigned short*)(ws + 16 * MB);
    unsigned short* Vt      = (unsigned short*)(ws + 16 * MB);
    unsigned short* H1      = (unsigned short*)(ws + 0);
    unsigned short* Wqkv_t  = (unsigned short*)(ws + 24 * MB);
    unsigned short* Wo_t    = (unsigned short*)(ws + 30 * MB);
    unsigned short* Out_b16 = (unsigned short*)(ws + 113 * MB);
    unsigned short* W1_t    = (unsigned short*)(ws + 32 * MB);
    unsigned short* W2_t    = (unsigned short*)(ws + 40 * MB);
    unsigned short* relbPad = (unsigned short*)(ws + 48 * MB);
    unsigned short* relbT   = (unsigned short*)(ws + 48 * MB + 256 * 1024);
    float*          bqkv    = (float*)(ws + 48 * MB + 512 * 1024);
    const float*    zbias   = bqkv + 1024;  // 2048 zeros
    unsigned short* QKV     = (unsigned short*)(ws + 49 * MB);
    float*          Amat    = (float*)(ws + 49 * MB);
    float*          Gmat    = (float*)(ws + 65 * MB);
    float*          rz      = (float*)(ws + 66 * MB);
    float*          Pwo     = (float*)(ws + 49 * MB);
    float*          Qw2     = (float*)(ws + 49 * MB);
    float*          S0      = (float*)(ws + 73 * MB);
    float*          tmp     = (float*)(ws + 73 * MB);
    unsigned short* Obf     = (unsigned short*)(ws + 89 * MB);
    unsigned short* An      = (unsigned short*)(ws + 97 * MB);
    float*          Tmat    = (float*)(ws + 105 * MB);
    unsigned short* Gn      = (unsigned short*)(ws + 105 * MB);

    const size_t PSTRIDE = 4u * 1024 * 1024;     // 16MB in floats
    const size_t BT_QKV  = 1024u * 3072;         // per-batch Q stride
    const size_t BT_VT   = 1024u * 1024;         // per-batch Vt stride
    const dim3 blk(256);

    // ---- weight prep ----
    transpose_f32_to_bf16<<<dim3(32, 32), blk, 0, stream>>>(Wq, Wqkv_t, 1024, 1024);
    transpose_f32_to_bf16<<<dim3(32, 32), blk, 0, stream>>>(Wk, Wqkv_t + 1024 * 1024, 1024, 1024);
    transpose_f32_to_bf16<<<dim3(32, 32), blk, 0, stream>>>(Wv, Wqkv_t + 2 * 1024 * 1024, 1024, 1024);
    transpose_f32_to_bf16<<<dim3(32, 32), blk, 0, stream>>>(Wo, Wo_t, 1024, 1024);
    transpose_f32_to_bf16<<<dim3(128, 32), blk, 0, stream>>>(W1, W1_t, 1024, 4096);
    transpose_f32_to_bf16<<<dim3(32, 128), blk, 0, stream>>>(W2, W2_t, 4096, 1024);
    build_relbpad<<<512, blk, 0, stream>>>(rel_tbl, relbPad);
    build_relbT<<<256, blk, 0, stream>>>(rel_tbl, relbT);
    build_bqkv<<<12, blk, 0, stream>>>(bq, bqkv);

    // ---- LN0 ----
    ln_kernel<0, 0><<<M_ROWS, blk, 0, stream>>>(hidden, nullptr, nullptr, 0, ln0_g, ln0_b,
                                                Xn_f32, Xn_b16, nullptr, nullptr);
    // ---- QKV GEMM: [4096,1024] x [1024,3072] ----
    gemm_bf16<true, false, false><<<dim3(24 * 32), blk, 0, stream>>>(
        Xn_b16, 1024, Wqkv_t, 1024, 0, bqkv, nullptr, QKV, nullptr, 3072, 1024, 24);
    // ---- V^T ----
    transpose_v_bf16<<<dim3(32, 32, 4), blk, 0, stream>>>(QKV, Vt);
    // ---- S = K Q^T (batched, split-K=2) ----
    gemm_bf16_splitk<<<dim3(8 * 32, 1, 2), blk, 0, stream>>>(
        QKV + 1024, 3072, QKV, 3072, BT_QKV, zbias, S0, PSTRIDE, 1024, 512, 8);
    // ---- T = Q relPad^T ----
    gemm_bf16<false, false, false><<<dim3(1 * 32), blk, 0, stream>>>(
        QKV, 3072, relbPad, 1024, 0, zbias, Tmat, nullptr, nullptr, 128, 1024, 1);
    // ---- zero A,G,rz; scatter scores ----
    hipMemsetAsync(ws + 49 * MB, 0, 17 * MB + 16 * 1024, stream);
    edge_scatter<<<512, blk, 0, stream>>>(S0, S0 + PSTRIDE, Tmat, esrc, edst, erel, Amat, Gmat);
    // ---- normalize ----
    zrow_convG<<<1024, blk, 0, stream>>>(Gmat, rz, Gn);
    convA<<<M_ROWS, blk, 0, stream>>>(Amat, rz, An);
    // ---- wv = Gn @ relbT^T (f32 tmp), then An @ Vt^T + tmp -> Obf (bf16) ----
    gemm_bf16<false, false, false><<<dim3(8 * 32), blk, 0, stream>>>(
        Gn, 64, relbT, 64, 0, zbias, tmp, nullptr, nullptr, 1024, 64, 8);
    gemm_bf16<true, false, true><<<dim3(8 * 32), blk, 0, stream>>>(
        An, 1024, Vt, 1024, BT_VT, zbias, nullptr, Obf, tmp, 1024, 1024, 8);
    // ---- o @ Wo + bo (split-K=2) ----
    gemm_bf16_splitk<<<dim3(8 * 32, 1, 2), blk, 0, stream>>>(
        Obf, 1024, Wo_t, 1024, 0, bo, Pwo, PSTRIDE, 1024, 512, 8);
    // ---- LN1 ----
    ln_kernel<1, 2><<<M_ROWS, blk, 0, stream>>>(Xn_f32, nullptr, Pwo, PSTRIDE, ln1_g, ln1_b,
                                                nullptr, Out_b16, nullptr, nullptr);
    // ---- FFN1 ----
    gemm_bf16<true, true, false><<<dim3(32 * 32), blk, 0, stream>>>(
        Out_b16, 1024, W1_t, 1024, 0, b1, nullptr, H1, nullptr, 4096, 1024, 32);
    // ---- W2 (split-K=4) ----
    gemm_bf16_splitk<<<dim3(8 * 32, 1, 4), blk, 0, stream>>>(
        H1, 4096, W2_t, 4096, 0, b2, Qw2, PSTRIDE, 1024, 1024, 8);
    // ---- LN2 + elu + residual ----
    ln_kernel<2, 4><<<M_ROWS, blk, 0, stream>>>(nullptr, Out_b16, Qw2, PSTRIDE, ln2_g, ln2_b,
                                                nullptr, nullptr, hidden, out);
    (void)in_sizes; (void)n_in; (void)out_size; (void)ws_size;
}

// Round 5
// 427.339 us; speedup vs baseline: 1.1539x; 1.0406x over previous
//
#include <hip/hip_runtime.h>
#include <hip/hip_bf16.h>

#define B_SZ 4
#define L_SEQ 1024
#define D_MODEL 1024
#define DF_FF 4096
#define E_PER_B 32768
#define R_REL 64
#define M_ROWS (B_SZ * L_SEQ)   // 4096

typedef __attribute__((ext_vector_type(8))) short bf16x8;
typedef __attribute__((ext_vector_type(4))) float f32x4;

__device__ inline float b2f(unsigned short u) {
    union { unsigned int i; float f; } x; x.i = ((unsigned int)u) << 16; return x.f;
}
__device__ inline unsigned short f2b(float f) {
    union { float f; unsigned int u; } x; x.f = f;
    unsigned int r = x.u + 0x7FFFu + ((x.u >> 16) & 1u);
    return (unsigned short)(r >> 16);
}

#define GLOBAL_CAST(p) ((const __attribute__((address_space(1))) void*)(p))
#define LDS_CAST(p)    ((__attribute__((address_space(3))) void*)(p))

// ---------------- transpose + f32->bf16: W[K,N] -> Wt[N,K] ----------------
__global__ void transpose_f32_to_bf16(const float* __restrict__ W,
                                      unsigned short* __restrict__ Wt,
                                      int K, int N) {
    __shared__ float tile[32][33];
    int n0 = blockIdx.x * 32, k0 = blockIdx.y * 32;
    int tx = threadIdx.x & 31, ty = threadIdx.x >> 5;   // 32 x 8
#pragma unroll
    for (int r = 0; r < 32; r += 8)
        tile[ty + r][tx] = W[(size_t)(k0 + ty + r) * N + (n0 + tx)];
    __syncthreads();
#pragma unroll
    for (int r = 0; r < 32; r += 8)
        Wt[(size_t)(n0 + ty + r) * K + (k0 + tx)] = f2b(tile[tx][ty + r]);
}

// V^T per batch: Vt[b][d, s] = QKV[(b<<10)+s, 2048+d]  (bf16)
__global__ void transpose_v_bf16(const unsigned short* __restrict__ QKV,
                                 unsigned short* __restrict__ Vt) {
    __shared__ unsigned short tile[32][33];
    const int b = blockIdx.z;
    const int d0 = blockIdx.x * 32, s0 = blockIdx.y * 32;
    const int tx = threadIdx.x & 31, ty = threadIdx.x >> 5;  // 32 x 8
#pragma unroll
    for (int r = 0; r < 32; r += 8)
        tile[ty + r][tx] = QKV[(size_t)((b << 10) + s0 + ty + r) * 3072 + 2048 + d0 + tx];
    __syncthreads();
#pragma unroll
    for (int r = 0; r < 32; r += 8)
        Vt[(size_t)b * 1048576 + (size_t)(d0 + ty + r) * 1024 + s0 + tx] = tile[tx][ty + r];
}

__global__ void build_bqkv(const float* __restrict__ bq, float* __restrict__ bqkv) {
    int i = blockIdx.x * 256 + threadIdx.x;   // grid covers 3072
    bqkv[i] = (i < 1024) ? bq[i] : 0.0f;
}

// relbPad bf16 [128,1024]: rows 0..63 = rel_table, 64..127 = 0
__global__ void build_relbpad(const float* __restrict__ rel, unsigned short* __restrict__ out) {
    int i = blockIdx.x * 256 + threadIdx.x;  // 131072
    out[i] = (i < 65536) ? f2b(rel[i]) : (unsigned short)0;
}

// relbT bf16 [1024,64]: relbT[d*64+r] = rel[r*1024+d]
__global__ void build_relbT(const float* __restrict__ rel, unsigned short* __restrict__ out) {
    int i = blockIdx.x * 256 + threadIdx.x;  // 65536
    int d = i >> 6, r = i & 63;
    out[i] = f2b(rel[r * 1024 + d]);
}

// XCD-aware tile swizzle: XCD = linear_id % 8. Group all tile_n of a tile_m on one XCD.
__device__ inline void tile_swizzle(int id, int ntn, int& tm, int& tn) {
    tm = ((id & 7) + ((id >> 3) / ntn) * 8) * 128;
    tn = ((id >> 3) % ntn) * 128;
}

// ---------------- GEMM: C[M,N] = A[M,K](bf16, lda) * Bt[N,K](bf16, ldb)^T + bias ----------------
// BK=64 (32KB LDS): 32 MFMA per barrier-pair (halves the vmcnt(0)+s_barrier drains vs BK=32).
// LDS XOR swizzle: slot s of row r holds global 16B chunk s ^ (r&7) -> quarter-wave 2-way = free.
// Staging: wave w rows [w*32,w*32+32), 4 calls x 8 rows; lane i -> row i>>3, slot i&7.
template<bool OUT_BF16, bool RELU, bool ACC>
__global__ __launch_bounds__(256, 4)
void gemm_bf16(const unsigned short* __restrict__ A, int lda,
               const unsigned short* __restrict__ Bt, int ldb, size_t bt_batch,
               const float* __restrict__ bias,
               float* __restrict__ Cf, unsigned short* __restrict__ Cb,
               const float* __restrict__ accin,
               int N, int K, int ntn) {
    __shared__ unsigned short lA[128 * 64];
    __shared__ unsigned short lB[128 * 64];
    int tile_m, tile_n;
    tile_swizzle(blockIdx.x, ntn, tile_m, tile_n);
    const int t = threadIdx.x;
    const int wave = t >> 6, lane = t & 63;
    const int wm = (wave >> 1) * 64, wn = (wave & 1) * 64;
    const int quad = lane >> 4, l16 = lane & 15;

    const int srow = lane >> 3;                       // 0..7
    const int schunk = ((lane & 7) ^ srow) * 8;       // swizzled source chunk
    const unsigned short* gA = A + (size_t)(tile_m + wave * 32 + srow) * lda + schunk;
    const unsigned short* gB = Bt + (size_t)(tile_m >> 10) * bt_batch
                                  + (size_t)(tile_n + wave * 32 + srow) * ldb + schunk;

    f32x4 acc[4][4];
#pragma unroll
    for (int i = 0; i < 4; i++)
#pragma unroll
        for (int j = 0; j < 4; j++) acc[i][j] = (f32x4)0.0f;

    for (int k0 = 0; k0 < K; k0 += 64) {
        __syncthreads();
#pragma unroll
        for (int r = 0; r < 4; ++r) {
            __builtin_amdgcn_global_load_lds(GLOBAL_CAST(gA + (size_t)r * 8 * lda),
                                             LDS_CAST(&lA[(wave * 32 + r * 8) * 64]), 16, 0, 0);
            __builtin_amdgcn_global_load_lds(GLOBAL_CAST(gB + (size_t)r * 8 * ldb),
                                             LDS_CAST(&lB[(wave * 32 + r * 8) * 64]), 16, 0, 0);
        }
        gA += 64; gB += 64;
        __builtin_amdgcn_s_waitcnt(0);
        __syncthreads();

#pragma unroll
        for (int kk = 0; kk < 2; ++kk) {
            const int cb = kk * 4 + quad;
            bf16x8 af[4], bf[4];
#pragma unroll
            for (int i = 0; i < 4; i++) {
                const int ra = wm + i * 16 + l16;
                af[i] = *(const bf16x8*)&lA[ra * 64 + ((cb ^ (ra & 7)) * 8)];
                const int rb = wn + i * 16 + l16;
                bf[i] = *(const bf16x8*)&lB[rb * 64 + ((cb ^ (rb & 7)) * 8)];
            }
#pragma unroll
            for (int mi = 0; mi < 4; mi++)
#pragma unroll
                for (int ni = 0; ni < 4; ni++)
                    acc[mi][ni] = __builtin_amdgcn_mfma_f32_16x16x32_bf16(af[mi], bf[ni], acc[mi][ni], 0, 0, 0);
        }
    }

#pragma unroll
    for (int mi = 0; mi < 4; mi++) {
#pragma unroll
        for (int ni = 0; ni < 4; ni++) {
            const int col = tile_n + wn + ni * 16 + l16;
            const float bv = bias[col];
#pragma unroll
            for (int r = 0; r < 4; r++) {
                const int row = tile_m + wm + mi * 16 + quad * 4 + r;
                float v = acc[mi][ni][r] + bv;
                if (ACC) v += accin[(size_t)row * N + col];
                if (RELU) v = fmaxf(v, 0.0f);
                if (OUT_BF16) Cb[(size_t)row * N + col] = f2b(v);
                else          Cf[(size_t)row * N + col] = v;
            }
        }
    }
}

// split-K: blockIdx.z = z over K-range [z*Kc,(z+1)*Kc); f32 partial at Pbase + z*pstride.
__global__ __launch_bounds__(256, 4)
void gemm_bf16_splitk(const unsigned short* __restrict__ A, int lda,
                      const unsigned short* __restrict__ Bt, int ldb, size_t bt_batch,
                      const float* __restrict__ bias,
                      float* __restrict__ Pbase, size_t pstride,
                      int N, int Kc, int ntn) {
    __shared__ unsigned short lA[128 * 64];
    __shared__ unsigned short lB[128 * 64];
    int tile_m, tile_n;
    tile_swizzle(blockIdx.x, ntn, tile_m, tile_n);
    const int z = blockIdx.z;
    const int kofs = z * Kc;
    const int t = threadIdx.x;
    const int wave = t >> 6, lane = t & 63;
    const int wm = (wave >> 1) * 64, wn = (wave & 1) * 64;
    const int quad = lane >> 4, l16 = lane & 15;

    const int srow = lane >> 3;
    const int schunk = ((lane & 7) ^ srow) * 8;
    const unsigned short* gA = A + (size_t)(tile_m + wave * 32 + srow) * lda + kofs + schunk;
    const unsigned short* gB = Bt + (size_t)(tile_m >> 10) * bt_batch
                                  + (size_t)(tile_n + wave * 32 + srow) * ldb + kofs + schunk;

    f32x4 acc[4][4];
#pragma unroll
    for (int i = 0; i < 4; i++)
#pragma unroll
        for (int j = 0; j < 4; j++) acc[i][j] = (f32x4)0.0f;

    for (int k0 = 0; k0 < Kc; k0 += 64) {
        __syncthreads();
#pragma unroll
        for (int r = 0; r < 4; ++r) {
            __builtin_amdgcn_global_load_lds(GLOBAL_CAST(gA + (size_t)r * 8 * lda),
                                             LDS_CAST(&lA[(wave * 32 + r * 8) * 64]), 16, 0, 0);
            __builtin_amdgcn_global_load_lds(GLOBAL_CAST(gB + (size_t)r * 8 * ldb),
                                             LDS_CAST(&lB[(wave * 32 + r * 8) * 64]), 16, 0, 0);
        }
        gA += 64; gB += 64;
        __builtin_amdgcn_s_waitcnt(0);
        __syncthreads();

#pragma unroll
        for (int kk = 0; kk < 2; ++kk) {
            const int cb = kk * 4 + quad;
            bf16x8 af[4], bf[4];
#pragma unroll
            for (int i = 0; i < 4; i++) {
                const int ra = wm + i * 16 + l16;
                af[i] = *(const bf16x8*)&lA[ra * 64 + ((cb ^ (ra & 7)) * 8)];
                const int rb = wn + i * 16 + l16;
                bf[i] = *(const bf16x8*)&lB[rb * 64 + ((cb ^ (rb & 7)) * 8)];
            }
#pragma unroll
            for (int mi = 0; mi < 4; mi++)
#pragma unroll
                for (int ni = 0; ni < 4; ni++)
                    acc[mi][ni] = __builtin_amdgcn_mfma_f32_16x16x32_bf16(af[mi], bf[ni], acc[mi][ni], 0, 0, 0);
        }
    }

    float* P = Pbase + (size_t)z * pstride;
#pragma unroll
    for (int mi = 0; mi < 4; mi++) {
#pragma unroll
        for (int ni = 0; ni < 4; ni++) {
            const int col = tile_n + wn + ni * 16 + l16;
            const float bv = (z == 0) ? bias[col] : 0.0f;
#pragma unroll
            for (int r = 0; r < 4; r++) {
                const int row = tile_m + wm + mi * 16 + quad * 4 + r;
                P[(size_t)row * N + col] = acc[mi][ni][r] + bv;
            }
        }
    }
}

// ---------------- LayerNorm family ----------------
// MODE 0 (NR=0): y = LN(X_f32)                      -> of32 + ob16
// MODE 1 (NR=2): y = LN(X_f32 + sum NR partials)    -> ob16
// MODE 2 (NR=4): y = LN(X_bf16 + sum NR partials); fout = hidden + elu(y)
template<int MODE, int NR>
__global__ void ln_kernel(const float* __restrict__ X, const unsigned short* __restrict__ Xb,
                          const float* __restrict__ Rbase, size_t rstride,
                          const float* __restrict__ g, const float* __restrict__ be,
                          float* __restrict__ of32, unsigned short* __restrict__ ob16,
                          const float* __restrict__ hidden, float* __restrict__ fout) {
    __shared__ float sb1[4], sb2[4];
    const int row = blockIdx.x, t = threadIdx.x;
    const size_t base = (size_t)row * 1024 + t * 4;

    float x0, x1, x2, x3;
    if (MODE == 2) {
        ushort4 xv = *(const ushort4*)(Xb + base);
        x0 = b2f(xv.x); x1 = b2f(xv.y); x2 = b2f(xv.z); x3 = b2f(xv.w);
    } else {
        float4 xv = *(const float4*)(X + base);
        x0 = xv.x; x1 = xv.y; x2 = xv.z; x3 = xv.w;
    }
#pragma unroll
    for (int r = 0; r < NR; r++) {
        float4 rv = *(const float4*)(Rbase + r * rstride + base);
        x0 += rv.x; x1 += rv.y; x2 += rv.z; x3 += rv.w;
    }
    float s = x0 + x1 + x2 + x3;
#pragma unroll
    for (int o = 32; o > 0; o >>= 1) s += __shfl_down(s, o);
    if ((t & 63) == 0) sb1[t >> 6] = s;
    __syncthreads();
    const float mu = (sb1[0] + sb1[1] + sb1[2] + sb1[3]) * (1.0f / 1024.0f);

    const float d0 = x0 - mu, d1 = x1 - mu, d2 = x2 - mu, d3 = x3 - mu;
    float s2 = d0 * d0 + d1 * d1 + d2 * d2 + d3 * d3;
#pragma unroll
    for (int o = 32; o > 0; o >>= 1) s2 += __shfl_down(s2, o);
    if ((t & 63) == 0) sb2[t >> 6] = s2;
    __syncthreads();
    const float var = (sb2[0] + sb2[1] + sb2[2] + sb2[3]) * (1.0f / 1024.0f);
    const float rstd = rsqrtf(var + 1e-6f);

    const float4 gv = *(const float4*)(g + t * 4);
    const float4 bv = *(const float4*)(be + t * 4);
    const float y0 = d0 * rstd * gv.x + bv.x;
    const float y1 = d1 * rstd * gv.y + bv.y;
    const float y2 = d2 * rstd * gv.z + bv.z;
    const float y3 = d3 * rstd * gv.w + bv.w;

    if (MODE == 0) {
        float4 o; o.x = y0; o.y = y1; o.z = y2; o.w = y3;
        *(float4*)(of32 + base) = o;
    }
    if (MODE <= 1) {
        ushort4 ob; ob.x = f2b(y0); ob.y = f2b(y1); ob.z = f2b(y2); ob.w = f2b(y3);
        *(ushort4*)(ob16 + base) = ob;
    } else {
        const float4 hv = *(const float4*)(hidden + base);
        const float e0 = y0 > 0.0f ? y0 : expm1f(y0);
        const float e1 = y1 > 0.0f ? y1 : expm1f(y1);
        const float e2 = y2 > 0.0f ? y2 : expm1f(y2);
        const float e3 = y3 > 0.0f ? y3 : expm1f(y3);
        float4 o; o.x = hv.x + e0; o.y = hv.y + e1; o.z = hv.z + e2; o.w = hv.w + e3;
        *(float4*)(fout + base) = o;
    }
}

// ---------------- dense edge phase ----------------
// per edge: sc = exp(clip((S[src,dst] + T[dst,r])/32)); A[dst,src] += sc; G[dst,r] += sc
__global__ void edge_scatter(const float* __restrict__ S0, const float* __restrict__ S1,
                             const float* __restrict__ T,
                             const int* __restrict__ src, const int* __restrict__ dst,
                             const int* __restrict__ rel,
                             float* __restrict__ A, float* __restrict__ G) {
    const int gg = blockIdx.x * 256 + threadIdx.x;   // B*E = 131072
    const int b = gg >> 15;
    const int s = src[gg], d = dst[gg], r = rel[gg];
    const size_t srow = (size_t)((b << 10) + s) * 1024 + d;
    const float sval = S0[srow] + S1[srow];
    const float tval = T[(size_t)((b << 10) + d) * 128 + r];
    float sc = (sval + tval) * (1.0f / 32.0f);
    sc = expf(fminf(fmaxf(sc, -10.0f), 10.0f));
    atomicAdd(&A[((size_t)((b << 10) + d) << 10) + s], sc);
    atomicAdd(&G[((size_t)((b << 10) + d) << 6) + r], sc);
}

// per node: z = sum_r G[node,r]; rz[node] = 1/z; Gn[node,r] = bf16(G[node,r]/z)
__global__ void zrow_convG(const float* __restrict__ G, float* __restrict__ rz,
                           unsigned short* __restrict__ Gn) {
    const int node = blockIdx.x * 4 + (threadIdx.x >> 6);
    const int lane = threadIdx.x & 63;
    const float v = G[(size_t)node * 64 + lane];
    float s = v;
#pragma unroll
    for (int o = 1; o < 64; o <<= 1) s += __shfl_xor(s, o);
    const float inv = 1.0f / s;
    Gn[(size_t)node * 64 + lane] = f2b(v * inv);
    if (lane == 0) rz[node] = inv;
}

// An[row, :] = bf16(A[row, :] * rz[row])
__global__ void convA(const float* __restrict__ A, const float* __restrict__ rz,
                      unsigned short* __restrict__ An) {
    const int row = blockIdx.x, t = threadIdx.x;
    const float r = rz[row];
    const size_t base = (size_t)row * 1024 + t * 4;
    const float4 v = *(const float4*)(A + base);
    ushort4 o;
    o.x = f2b(v.x * r); o.y = f2b(v.y * r); o.z = f2b(v.z * r); o.w = f2b(v.w * r);
    *(ushort4*)(An + base) = o;
}

// ---------------- launch ----------------
extern "C" void kernel_launch(void* const* d_in, const int* in_sizes, int n_in,
                              void* d_out, int out_size, void* d_ws, size_t ws_size,
                              hipStream_t stream) {
    const float* hidden  = (const float*)d_in[0];
    const float* rel_tbl = (const float*)d_in[1];
    const float* Wq = (const float*)d_in[2];
    const float* bq = (const float*)d_in[3];
    const float* Wk = (const float*)d_in[4];
    const float* Wv = (const float*)d_in[5];
    const float* Wo = (const float*)d_in[6];
    const float* bo = (const float*)d_in[7];
    const float* ln0_g = (const float*)d_in[8];
    const float* ln0_b = (const float*)d_in[9];
    const float* ln1_g = (const float*)d_in[10];
    const float* ln1_b = (const float*)d_in[11];
    const float* W1 = (const float*)d_in[12];
    const float* b1 = (const float*)d_in[13];
    const float* W2 = (const float*)d_in[14];
    const float* b2 = (const float*)d_in[15];
    const float* ln2_g = (const float*)d_in[16];
    const float* ln2_b = (const float*)d_in[17];
    const int* esrc = (const int*)d_in[18];
    const int* edst = (const int*)d_in[19];
    const int* erel = (const int*)d_in[20];
    float* out = (float*)d_out;

    // ws lifetime map (peak 121MB) — unchanged from R4.
    char* ws = (char*)d_ws;
    const size_t MB = 1024 * 1024;
    float*          Xn_f32  = (float*)(ws + 0);
    unsigned short* Xn_b16  = (unsigned short*)(ws + 16 * MB);
    unsigned short* Vt      = (unsigned short*)(ws + 16 * MB);
    unsigned short* H1      = (unsigned short*)(ws + 0);
    unsigned short* Wqkv_t  = (unsigned short*)(ws + 24 * MB);
    unsigned short* Wo_t    = (unsigned short*)(ws + 30 * MB);
    unsigned short* Out_b16 = (unsigned short*)(ws + 113 * MB);
    unsigned short* W1_t    = (unsigned short*)(ws + 32 * MB);
    unsigned short* W2_t    = (unsigned short*)(ws + 40 * MB);
    unsigned short* relbPad = (unsigned short*)(ws + 48 * MB);
    unsigned short* relbT   = (unsigned short*)(ws + 48 * MB + 256 * 1024);
    float*          bqkv    = (float*)(ws + 48 * MB + 512 * 1024);
    const float*    zbias   = bqkv + 1024;  // 2048 zeros
    unsigned short* QKV     = (unsigned short*)(ws + 49 * MB);
    float*          Amat    = (float*)(ws + 49 * MB);
    float*          Gmat    = (float*)(ws + 65 * MB);
    float*          rz      = (float*)(ws + 66 * MB);
    float*          Pwo     = (float*)(ws + 49 * MB);
    float*          Qw2     = (float*)(ws + 49 * MB);
    float*          S0      = (float*)(ws + 73 * MB);
    float*          tmp     = (float*)(ws + 73 * MB);
    unsigned short* Obf     = (unsigned short*)(ws + 89 * MB);
    unsigned short* An      = (unsigned short*)(ws + 97 * MB);
    float*          Tmat    = (float*)(ws + 105 * MB);
    unsigned short* Gn      = (unsigned short*)(ws + 105 * MB);

    const size_t PSTRIDE = 4u * 1024 * 1024;     // 16MB in floats
    const size_t BT_QKV  = 1024u * 3072;         // per-batch Q stride
    const size_t BT_VT   = 1024u * 1024;         // per-batch Vt stride
    const dim3 blk(256);

    // ---- weight prep ----
    transpose_f32_to_bf16<<<dim3(32, 32), blk, 0, stream>>>(Wq, Wqkv_t, 1024, 1024);
    transpose_f32_to_bf16<<<dim3(32, 32), blk, 0, stream>>>(Wk, Wqkv_t + 1024 * 1024, 1024, 1024);
    transpose_f32_to_bf16<<<dim3(32, 32), blk, 0, stream>>>(Wv, Wqkv_t + 2 * 1024 * 1024, 1024, 1024);
    transpose_f32_to_bf16<<<dim3(32, 32), blk, 0, stream>>>(Wo, Wo_t, 1024, 1024);
    transpose_f32_to_bf16<<<dim3(128, 32), blk, 0, stream>>>(W1, W1_t, 1024, 4096);
    transpose_f32_to_bf16<<<dim3(32, 128), blk, 0, stream>>>(W2, W2_t, 4096, 1024);
    build_relbpad<<<512, blk, 0, stream>>>(rel_tbl, relbPad);
    build_relbT<<<256, blk, 0, stream>>>(rel_tbl, relbT);
    build_bqkv<<<12, blk, 0, stream>>>(bq, bqkv);

    // ---- LN0 ----
    ln_kernel<0, 0><<<M_ROWS, blk, 0, stream>>>(hidden, nullptr, nullptr, 0, ln0_g, ln0_b,
                                                Xn_f32, Xn_b16, nullptr, nullptr);
    // ---- QKV GEMM: [4096,1024] x [1024,3072] ----
    gemm_bf16<true, false, false><<<dim3(24 * 32), blk, 0, stream>>>(
        Xn_b16, 1024, Wqkv_t, 1024, 0, bqkv, nullptr, QKV, nullptr, 3072, 1024, 24);
    // ---- V^T ----
    transpose_v_bf16<<<dim3(32, 32, 4), blk, 0, stream>>>(QKV, Vt);
    // ---- S = K Q^T (batched, split-K=2) ----
    gemm_bf16_splitk<<<dim3(8 * 32, 1, 2), blk, 0, stream>>>(
        QKV + 1024, 3072, QKV, 3072, BT_QKV, zbias, S0, PSTRIDE, 1024, 512, 8);
    // ---- T = Q relPad^T ----
    gemm_bf16<false, false, false><<<dim3(1 * 32), blk, 0, stream>>>(
        QKV, 3072, relbPad, 1024, 0, zbias, Tmat, nullptr, nullptr, 128, 1024, 1);
    // ---- zero A,G,rz; scatter scores ----
    hipMemsetAsync(ws + 49 * MB, 0, 17 * MB + 16 * 1024, stream);
    edge_scatter<<<512, blk, 0, stream>>>(S0, S0 + PSTRIDE, Tmat, esrc, edst, erel, Amat, Gmat);
    // ---- normalize ----
    zrow_convG<<<1024, blk, 0, stream>>>(Gmat, rz, Gn);
    convA<<<M_ROWS, blk, 0, stream>>>(Amat, rz, An);
    // ---- wv = Gn @ relbT^T (f32 tmp), then An @ Vt^T + tmp -> Obf (bf16) ----
    gemm_bf16<false, false, false><<<dim3(8 * 32), blk, 0, stream>>>(
        Gn, 64, relbT, 64, 0, zbias, tmp, nullptr, nullptr, 1024, 64, 8);
    gemm_bf16<true, false, true><<<dim3(8 * 32), blk, 0, stream>>>(
        An, 1024, Vt, 1024, BT_VT, zbias, nullptr, Obf, tmp, 1024, 1024, 8);
    // ---- o @ Wo + bo (split-K=2) ----
    gemm_bf16_splitk<<<dim3(8 * 32, 1, 2), blk, 0, stream>>>(
        Obf, 1024, Wo_t, 1024, 0, bo, Pwo, PSTRIDE, 1024, 512, 8);
    // ---- LN1 ----
    ln_kernel<1, 2><<<M_ROWS, blk, 0, stream>>>(Xn_f32, nullptr, Pwo, PSTRIDE, ln1_g, ln1_b,
                                                nullptr, Out_b16, nullptr, nullptr);
    // ---- FFN1 ----
    gemm_bf16<true, true, false><<<dim3(32 * 32), blk, 0, stream>>>(
        Out_b16, 1024, W1_t, 1024, 0, b1, nullptr, H1, nullptr, 4096, 1024, 32);
    // ---- W2 (split-K=4) ----
    gemm_bf16_splitk<<<dim3(8 * 32, 1, 4), blk, 0, stream>>>(
        H1, 4096, W2_t, 4096, 0, b2, Qw2, PSTRIDE, 1024, 1024, 8);
    // ---- LN2 + elu + residual ----
    ln_kernel<2, 4><<<M_ROWS, blk, 0, stream>>>(nullptr, Out_b16, Qw2, PSTRIDE, ln2_g, ln2_b,
                                                nullptr, nullptr, hidden, out);
    (void)in_sizes; (void)n_in; (void)out_size; (void)ws_size;
}

// Round 6
// 401.986 us; speedup vs baseline: 1.2267x; 1.0631x over previous
//
#include <hip/hip_runtime.h>
#include <hip/hip_bf16.h>

#define B_SZ 4
#define L_SEQ 1024
#define D_MODEL 1024
#define DF_FF 4096
#define E_PER_B 32768
#define R_REL 64
#define M_ROWS (B_SZ * L_SEQ)   // 4096

typedef __attribute__((ext_vector_type(8))) short bf16x8;
typedef __attribute__((ext_vector_type(4))) float f32x4;

__device__ inline float b2f(unsigned short u) {
    union { unsigned int i; float f; } x; x.i = ((unsigned int)u) << 16; return x.f;
}
__device__ inline unsigned short f2b(float f) {
    union { float f; unsigned int u; } x; x.f = f;
    unsigned int r = x.u + 0x7FFFu + ((x.u >> 16) & 1u);
    return (unsigned short)(r >> 16);
}

#define GLOBAL_CAST(p) ((const __attribute__((address_space(1))) void*)(p))
#define LDS_CAST(p)    ((__attribute__((address_space(3))) void*)(p))

// ---------------- fused prep: all weight transposes + rel tables + bias ----------------
// flat grid 13068 blocks:
//   [0,4096)      4 x 1024 tiles: Wq,Wk,Wv -> Wqkv_t ; Wo -> Wo_t   (32x32 transpose tiles)
//   [4096,8192)   W1 [1024,4096] -> W1_t (x=t&127 n-tile, y=t>>7 k-tile)
//   [8192,12288)  W2 [4096,1024] -> W2_t (x=t&31, y=t>>5)
//   [12288,12800) relbPad bf16 [128,1024] (rows 64..127 zero)
//   [12800,13056) relbT bf16 [1024,64]
//   [13056,13068) bqkv f32 [3072] (cols 1024+ = 0 -> zbias)
__global__ void prep_all(const float* __restrict__ Wq, const float* __restrict__ Wk,
                         const float* __restrict__ Wv, const float* __restrict__ Wo,
                         const float* __restrict__ W1, const float* __restrict__ W2,
                         const float* __restrict__ rel, const float* __restrict__ bq,
                         unsigned short* __restrict__ Wqkv_t, unsigned short* __restrict__ Wo_t,
                         unsigned short* __restrict__ W1_t, unsigned short* __restrict__ W2_t,
                         unsigned short* __restrict__ relbPad, unsigned short* __restrict__ relbT,
                         float* __restrict__ bqkv) {
    __shared__ float tile[32][33];
    const int id = blockIdx.x, tid = threadIdx.x;
    if (id < 12288) {
        const float* src; unsigned short* dst; int K, N, x, y;
        if (id < 4096) {
            const int seg = id >> 10, t = id & 1023;
            K = 1024; N = 1024; x = t & 31; y = t >> 5;
            src = (seg == 0) ? Wq : (seg == 1) ? Wk : (seg == 2) ? Wv : Wo;
            dst = (seg == 3) ? Wo_t : (Wqkv_t + (size_t)seg * 1048576);
        } else if (id < 8192) {
            const int t = id - 4096; K = 1024; N = 4096; x = t & 127; y = t >> 7;
            src = W1; dst = W1_t;
        } else {
            const int t = id - 8192; K = 4096; N = 1024; x = t & 31; y = t >> 5;
            src = W2; dst = W2_t;
        }
        const int n0 = x * 32, k0 = y * 32, tx = tid & 31, ty = tid >> 5;
#pragma unroll
        for (int r = 0; r < 32; r += 8)
            tile[ty + r][tx] = src[(size_t)(k0 + ty + r) * N + (n0 + tx)];
        __syncthreads();
#pragma unroll
        for (int r = 0; r < 32; r += 8)
            dst[(size_t)(n0 + ty + r) * K + (k0 + tx)] = f2b(tile[tx][ty + r]);
    } else if (id < 12800) {
        const int i = (id - 12288) * 256 + tid;            // 131072
        relbPad[i] = (i < 65536) ? f2b(rel[i]) : (unsigned short)0;
    } else if (id < 13056) {
        const int i = (id - 12800) * 256 + tid;            // 65536: out[d*64+r]
        relbT[i] = f2b(rel[(i & 63) * 1024 + (i >> 6)]);
    } else {
        const int i = (id - 13056) * 256 + tid;            // 3072
        bqkv[i] = (i < 1024) ? bq[i] : 0.0f;
    }
}

// V^T per batch: Vt[b][d, s] = QKV[(b<<10)+s, 2048+d]  (bf16)
__global__ void transpose_v_bf16(const unsigned short* __restrict__ QKV,
                                 unsigned short* __restrict__ Vt) {
    __shared__ unsigned short tile[32][33];
    const int b = blockIdx.z;
    const int d0 = blockIdx.x * 32, s0 = blockIdx.y * 32;
    const int tx = threadIdx.x & 31, ty = threadIdx.x >> 5;  // 32 x 8
#pragma unroll
    for (int r = 0; r < 32; r += 8)
        tile[ty + r][tx] = QKV[(size_t)((b << 10) + s0 + ty + r) * 3072 + 2048 + d0 + tx];
    __syncthreads();
#pragma unroll
    for (int r = 0; r < 32; r += 8)
        Vt[(size_t)b * 1048576 + (size_t)(d0 + ty + r) * 1024 + s0 + tx] = tile[tx][ty + r];
}

// XCD-aware tile swizzle: XCD = linear_id % 8. Group all tile_n of a tile_m on one XCD.
__device__ inline void tile_swizzle(int id, int ntn, int& tm, int& tn) {
    tm = ((id & 7) + ((id >> 3) / ntn) * 8) * 128;
    tn = ((id >> 3) % ntn) * 128;
}

// ---------------- GEMM: C[M,N] = A[M,K](bf16, lda) * Bt[N,K](bf16, ldb)^T + bias ----------------
// BK=64 (32KB LDS): 32 MFMA per barrier-pair. XOR swizzle slot = chunk ^ (row&7) -> 0 conflicts.
template<bool OUT_BF16, bool RELU, bool ACC>
__global__ __launch_bounds__(256, 4)
void gemm_bf16(const unsigned short* __restrict__ A, int lda,
               const unsigned short* __restrict__ Bt, int ldb, size_t bt_batch,
               const float* __restrict__ bias,
               float* __restrict__ Cf, unsigned short* __restrict__ Cb,
               const float* __restrict__ accin,
               int N, int K, int ntn) {
    __shared__ unsigned short lA[128 * 64];
    __shared__ unsigned short lB[128 * 64];
    int tile_m, tile_n;
    tile_swizzle(blockIdx.x, ntn, tile_m, tile_n);
    const int t = threadIdx.x;
    const int wave = t >> 6, lane = t & 63;
    const int wm = (wave >> 1) * 64, wn = (wave & 1) * 64;
    const int quad = lane >> 4, l16 = lane & 15;

    const int srow = lane >> 3;
    const int schunk = ((lane & 7) ^ srow) * 8;
    const unsigned short* gA = A + (size_t)(tile_m + wave * 32 + srow) * lda + schunk;
    const unsigned short* gB = Bt + (size_t)(tile_m >> 10) * bt_batch
                                  + (size_t)(tile_n + wave * 32 + srow) * ldb + schunk;

    f32x4 acc[4][4];
#pragma unroll
    for (int i = 0; i < 4; i++)
#pragma unroll
        for (int j = 0; j < 4; j++) acc[i][j] = (f32x4)0.0f;

    for (int k0 = 0; k0 < K; k0 += 64) {
        __syncthreads();
#pragma unroll
        for (int r = 0; r < 4; ++r) {
            __builtin_amdgcn_global_load_lds(GLOBAL_CAST(gA + (size_t)r * 8 * lda),
                                             LDS_CAST(&lA[(wave * 32 + r * 8) * 64]), 16, 0, 0);
            __builtin_amdgcn_global_load_lds(GLOBAL_CAST(gB + (size_t)r * 8 * ldb),
                                             LDS_CAST(&lB[(wave * 32 + r * 8) * 64]), 16, 0, 0);
        }
        gA += 64; gB += 64;
        __builtin_amdgcn_s_waitcnt(0);
        __syncthreads();

#pragma unroll
        for (int kk = 0; kk < 2; ++kk) {
            const int cb = kk * 4 + quad;
            bf16x8 af[4], bf[4];
#pragma unroll
            for (int i = 0; i < 4; i++) {
                const int ra = wm + i * 16 + l16;
                af[i] = *(const bf16x8*)&lA[ra * 64 + ((cb ^ (ra & 7)) * 8)];
                const int rb = wn + i * 16 + l16;
                bf[i] = *(const bf16x8*)&lB[rb * 64 + ((cb ^ (rb & 7)) * 8)];
            }
#pragma unroll
            for (int mi = 0; mi < 4; mi++)
#pragma unroll
                for (int ni = 0; ni < 4; ni++)
                    acc[mi][ni] = __builtin_amdgcn_mfma_f32_16x16x32_bf16(af[mi], bf[ni], acc[mi][ni], 0, 0, 0);
        }
    }

#pragma unroll
    for (int mi = 0; mi < 4; mi++) {
#pragma unroll
        for (int ni = 0; ni < 4; ni++) {
            const int col = tile_n + wn + ni * 16 + l16;
            const float bv = bias[col];
#pragma unroll
            for (int r = 0; r < 4; r++) {
                const int row = tile_m + wm + mi * 16 + quad * 4 + r;
                float v = acc[mi][ni][r] + bv;
                if (ACC) v += accin[(size_t)row * N + col];
                if (RELU) v = fmaxf(v, 0.0f);
                if (OUT_BF16) Cb[(size_t)row * N + col] = f2b(v);
                else          Cf[(size_t)row * N + col] = v;
            }
        }
    }
}

// split-K: blockIdx.z = z over K-range [z*Kc,(z+1)*Kc); bf16 partial at Pbase + z*pstride.
__global__ __launch_bounds__(256, 4)
void gemm_bf16_splitk(const unsigned short* __restrict__ A, int lda,
                      const unsigned short* __restrict__ Bt, int ldb, size_t bt_batch,
                      const float* __restrict__ bias,
                      unsigned short* __restrict__ Pbase, size_t pstride,
                      int N, int Kc, int ntn) {
    __shared__ unsigned short lA[128 * 64];
    __shared__ unsigned short lB[128 * 64];
    int tile_m, tile_n;
    tile_swizzle(blockIdx.x, ntn, tile_m, tile_n);
    const int z = blockIdx.z;
    const int kofs = z * Kc;
    const int t = threadIdx.x;
    const int wave = t >> 6, lane = t & 63;
    const int wm = (wave >> 1) * 64, wn = (wave & 1) * 64;
    const int quad = lane >> 4, l16 = lane & 15;

    const int srow = lane >> 3;
    const int schunk = ((lane & 7) ^ srow) * 8;
    const unsigned short* gA = A + (size_t)(tile_m + wave * 32 + srow) * lda + kofs + schunk;
    const unsigned short* gB = Bt + (size_t)(tile_m >> 10) * bt_batch
                                  + (size_t)(tile_n + wave * 32 + srow) * ldb + kofs + schunk;

    f32x4 acc[4][4];
#pragma unroll
    for (int i = 0; i < 4; i++)
#pragma unroll
        for (int j = 0; j < 4; j++) acc[i][j] = (f32x4)0.0f;

    for (int k0 = 0; k0 < Kc; k0 += 64) {
        __syncthreads();
#pragma unroll
        for (int r = 0; r < 4; ++r) {
            __builtin_amdgcn_global_load_lds(GLOBAL_CAST(gA + (size_t)r * 8 * lda),
                                             LDS_CAST(&lA[(wave * 32 + r * 8) * 64]), 16, 0, 0);
            __builtin_amdgcn_global_load_lds(GLOBAL_CAST(gB + (size_t)r * 8 * ldb),
                                             LDS_CAST(&lB[(wave * 32 + r * 8) * 64]), 16, 0, 0);
        }
        gA += 64; gB += 64;
        __builtin_amdgcn_s_waitcnt(0);
        __syncthreads();

#pragma unroll
        for (int kk = 0; kk < 2; ++kk) {
            const int cb = kk * 4 + quad;
            bf16x8 af[4], bf[4];
#pragma unroll
            for (int i = 0; i < 4; i++) {
                const int ra = wm + i * 16 + l16;
                af[i] = *(const bf16x8*)&lA[ra * 64 + ((cb ^ (ra & 7)) * 8)];
                const int rb = wn + i * 16 + l16;
                bf[i] = *(const bf16x8*)&lB[rb * 64 + ((cb ^ (rb & 7)) * 8)];
            }
#pragma unroll
            for (int mi = 0; mi < 4; mi++)
#pragma unroll
                for (int ni = 0; ni < 4; ni++)
                    acc[mi][ni] = __builtin_amdgcn_mfma_f32_16x16x32_bf16(af[mi], bf[ni], acc[mi][ni], 0, 0, 0);
        }
    }

    unsigned short* P = Pbase + (size_t)z * pstride;
#pragma unroll
    for (int mi = 0; mi < 4; mi++) {
#pragma unroll
        for (int ni = 0; ni < 4; ni++) {
            const int col = tile_n + wn + ni * 16 + l16;
            const float bv = (z == 0) ? bias[col] : 0.0f;
#pragma unroll
            for (int r = 0; r < 4; r++) {
                const int row = tile_m + wm + mi * 16 + quad * 4 + r;
                P[(size_t)row * N + col] = f2b(acc[mi][ni][r] + bv);
            }
        }
    }
}

// ---------------- LayerNorm family ----------------
// partials are bf16 (split-K outputs). MODE 0: LN(X_f32) -> of32+ob16.
// MODE 1: LN(X_f32 + sum NR partials) -> ob16. MODE 2: LN(X_bf16 + sum NR partials);
// fout = hidden + elu(y).
template<int MODE, int NR>
__global__ void ln_kernel(const float* __restrict__ X, const unsigned short* __restrict__ Xb,
                          const unsigned short* __restrict__ Rbase, size_t rstride,
                          const float* __restrict__ g, const float* __restrict__ be,
                          float* __restrict__ of32, unsigned short* __restrict__ ob16,
                          const float* __restrict__ hidden, float* __restrict__ fout) {
    __shared__ float sb1[4], sb2[4];
    const int row = blockIdx.x, t = threadIdx.x;
    const size_t base = (size_t)row * 1024 + t * 4;

    float x0, x1, x2, x3;
    if (MODE == 2) {
        ushort4 xv = *(const ushort4*)(Xb + base);
        x0 = b2f(xv.x); x1 = b2f(xv.y); x2 = b2f(xv.z); x3 = b2f(xv.w);
    } else {
        float4 xv = *(const float4*)(X + base);
        x0 = xv.x; x1 = xv.y; x2 = xv.z; x3 = xv.w;
    }
#pragma unroll
    for (int r = 0; r < NR; r++) {
        ushort4 rv = *(const ushort4*)(Rbase + r * rstride + base);
        x0 += b2f(rv.x); x1 += b2f(rv.y); x2 += b2f(rv.z); x3 += b2f(rv.w);
    }
    float s = x0 + x1 + x2 + x3;
#pragma unroll
    for (int o = 32; o > 0; o >>= 1) s += __shfl_down(s, o);
    if ((t & 63) == 0) sb1[t >> 6] = s;
    __syncthreads();
    const float mu = (sb1[0] + sb1[1] + sb1[2] + sb1[3]) * (1.0f / 1024.0f);

    const float d0 = x0 - mu, d1 = x1 - mu, d2 = x2 - mu, d3 = x3 - mu;
    float s2 = d0 * d0 + d1 * d1 + d2 * d2 + d3 * d3;
#pragma unroll
    for (int o = 32; o > 0; o >>= 1) s2 += __shfl_down(s2, o);
    if ((t & 63) == 0) sb2[t >> 6] = s2;
    __syncthreads();
    const float var = (sb2[0] + sb2[1] + sb2[2] + sb2[3]) * (1.0f / 1024.0f);
    const float rstd = rsqrtf(var + 1e-6f);

    const float4 gv = *(const float4*)(g + t * 4);
    const float4 bv = *(const float4*)(be + t * 4);
    const float y0 = d0 * rstd * gv.x + bv.x;
    const float y1 = d1 * rstd * gv.y + bv.y;
    const float y2 = d2 * rstd * gv.z + bv.z;
    const float y3 = d3 * rstd * gv.w + bv.w;

    if (MODE == 0) {
        float4 o; o.x = y0; o.y = y1; o.z = y2; o.w = y3;
        *(float4*)(of32 + base) = o;
    }
    if (MODE <= 1) {
        ushort4 ob; ob.x = f2b(y0); ob.y = f2b(y1); ob.z = f2b(y2); ob.w = f2b(y3);
        *(ushort4*)(ob16 + base) = ob;
    } else {
        const float4 hv = *(const float4*)(hidden + base);
        const float e0 = y0 > 0.0f ? y0 : expm1f(y0);
        const float e1 = y1 > 0.0f ? y1 : expm1f(y1);
        const float e2 = y2 > 0.0f ? y2 : expm1f(y2);
        const float e3 = y3 > 0.0f ? y3 : expm1f(y3);
        float4 o; o.x = hv.x + e0; o.y = hv.y + e1; o.z = hv.z + e2; o.w = hv.w + e3;
        *(float4*)(fout + base) = o;
    }
}

// ---------------- dense edge phase ----------------
// per edge: sc = exp(clip((S0[src,dst]+S1[src,dst] + T[dst,r])/32)); A[dst,src]+=sc; G[dst,r]+=sc
__global__ void edge_scatter(const unsigned short* __restrict__ S0h,
                             const unsigned short* __restrict__ S1h,
                             const float* __restrict__ T,
                             const int* __restrict__ src, const int* __restrict__ dst,
                             const int* __restrict__ rel,
                             float* __restrict__ A, float* __restrict__ G) {
    const int gg = blockIdx.x * 256 + threadIdx.x;   // B*E = 131072
    const int b = gg >> 15;
    const int s = src[gg], d = dst[gg], r = rel[gg];
    const size_t srow = (size_t)((b << 10) + s) * 1024 + d;
    const float sval = b2f(S0h[srow]) + b2f(S1h[srow]);
    const float tval = T[(size_t)((b << 10) + d) * 128 + r];
    float sc = (sval + tval) * (1.0f / 32.0f);
    sc = expf(fminf(fmaxf(sc, -10.0f), 10.0f));
    atomicAdd(&A[((size_t)((b << 10) + d) << 10) + s], sc);
    atomicAdd(&G[((size_t)((b << 10) + d) << 6) + r], sc);
}

// per node: inv = 1/sum_r G[row,r]; Gn = bf16(G*inv); An = bf16(A*inv)
__global__ void normalize(const float* __restrict__ A, const float* __restrict__ G,
                          unsigned short* __restrict__ An, unsigned short* __restrict__ Gn) {
    __shared__ float sInv;
    const int row = blockIdx.x, t = threadIdx.x;
    float v = 0.0f;
    if (t < 64) {
        v = G[(size_t)row * 64 + t];
        float s = v;
#pragma unroll
        for (int o = 1; o < 64; o <<= 1) s += __shfl_xor(s, o);
        if (t == 0) sInv = 1.0f / s;
    }
    __syncthreads();
    const float inv = sInv;
    if (t < 64) Gn[(size_t)row * 64 + t] = f2b(v * inv);
    const size_t base = (size_t)row * 1024 + t * 4;
    const float4 a = *(const float4*)(A + base);
    ushort4 o;
    o.x = f2b(a.x * inv); o.y = f2b(a.y * inv); o.z = f2b(a.z * inv); o.w = f2b(a.w * inv);
    *(ushort4*)(An + base) = o;
}

// ---------------- launch ----------------
extern "C" void kernel_launch(void* const* d_in, const int* in_sizes, int n_in,
                              void* d_out, int out_size, void* d_ws, size_t ws_size,
                              hipStream_t stream) {
    const float* hidden  = (const float*)d_in[0];
    const float* rel_tbl = (const float*)d_in[1];
    const float* Wq = (const float*)d_in[2];
    const float* bq = (const float*)d_in[3];
    const float* Wk = (const float*)d_in[4];
    const float* Wv = (const float*)d_in[5];
    const float* Wo = (const float*)d_in[6];
    const float* bo = (const float*)d_in[7];
    const float* ln0_g = (const float*)d_in[8];
    const float* ln0_b = (const float*)d_in[9];
    const float* ln1_g = (const float*)d_in[10];
    const float* ln1_b = (const float*)d_in[11];
    const float* W1 = (const float*)d_in[12];
    const float* b1 = (const float*)d_in[13];
    const float* W2 = (const float*)d_in[14];
    const float* b2 = (const float*)d_in[15];
    const float* ln2_g = (const float*)d_in[16];
    const float* ln2_b = (const float*)d_in[17];
    const int* esrc = (const int*)d_in[18];
    const int* edst = (const int*)d_in[19];
    const int* erel = (const int*)d_in[20];
    float* out = (float*)d_out;

    // ws lifetime map (peak 121MB), time-ordered overlay:
    //  0-16   Xn_f32 [LN0->LN1]            ; 0-32 H1 [FFN1->W2]
    // 16-24   Xn_b16 [LN0->QKV] ; Vt [Vtrans->wvA]
    // 24-30   Wqkv_t ; 30-32 Wo_t ; 32-40 W1_t ; 40-48 W2_t
    // 48-48.25 relbPad ; 48.25-48.375 relbT ; 48.5 bqkv(+zbias)
    // 49-73   QKV [QKVg->Vt,S,T] ; then 49-65 A + 65-66 G [scatter->normalize]
    //         then 49-65 PwoH x2 bf16 [Wo->LN1] ; then 49-81 Qw2H x4 bf16 [W2->LN2]
    // 73-89   S0h/S1h bf16 [S->scatter] ; then tmp f32 [wvG->wvA]
    // 89-97   Obf [wvA->Wo] ; 97-105 An [normalize->wvA]
    // 105-107 Tmat [T->scatter] ; then 105-105.5 Gn [normalize->wvG]
    // 113-121 Out_b16 [LN1->FFN1,LN2]
    char* ws = (char*)d_ws;
    const size_t MB = 1024 * 1024;
    float*          Xn_f32  = (float*)(ws + 0);
    unsigned short* Xn_b16  = (unsigned short*)(ws + 16 * MB);
    unsigned short* Vt      = (unsigned short*)(ws + 16 * MB);
    unsigned short* H1      = (unsigned short*)(ws + 0);
    unsigned short* Wqkv_t  = (unsigned short*)(ws + 24 * MB);
    unsigned short* Wo_t    = (unsigned short*)(ws + 30 * MB);
    unsigned short* W1_t    = (unsigned short*)(ws + 32 * MB);
    unsigned short* W2_t    = (unsigned short*)(ws + 40 * MB);
    unsigned short* relbPad = (unsigned short*)(ws + 48 * MB);
    unsigned short* relbT   = (unsigned short*)(ws + 48 * MB + 256 * 1024);
    float*          bqkv    = (float*)(ws + 48 * MB + 512 * 1024);
    const float*    zbias   = bqkv + 1024;  // 2048 zeros
    unsigned short* QKV     = (unsigned short*)(ws + 49 * MB);
    float*          Amat    = (float*)(ws + 49 * MB);
    float*          Gmat    = (float*)(ws + 65 * MB);
    unsigned short* PwoH    = (unsigned short*)(ws + 49 * MB);
    unsigned short* Qw2H    = (unsigned short*)(ws + 49 * MB);
    unsigned short* S0h     = (unsigned short*)(ws + 73 * MB);
    float*          tmp     = (float*)(ws + 73 * MB);
    unsigned short* Obf     = (unsigned short*)(ws + 89 * MB);
    unsigned short* An      = (unsigned short*)(ws + 97 * MB);
    float*          Tmat    = (float*)(ws + 105 * MB);
    unsigned short* Gn      = (unsigned short*)(ws + 105 * MB);
    unsigned short* Out_b16 = (unsigned short*)(ws + 113 * MB);

    const size_t PSTRIDE_H = 4u * 1024 * 1024;   // 8MB bf16 partial, in ushorts
    const size_t BT_QKV  = 1024u * 3072;         // per-batch Q stride
    const size_t BT_VT   = 1024u * 1024;         // per-batch Vt stride
    const dim3 blk(256);

    // ---- fused prep ----
    prep_all<<<13068, blk, 0, stream>>>(Wq, Wk, Wv, Wo, W1, W2, rel_tbl, bq,
                                        Wqkv_t, Wo_t, W1_t, W2_t, relbPad, relbT, bqkv);
    // ---- LN0 ----
    ln_kernel<0, 0><<<M_ROWS, blk, 0, stream>>>(hidden, nullptr, nullptr, 0, ln0_g, ln0_b,
                                                Xn_f32, Xn_b16, nullptr, nullptr);
    // ---- QKV GEMM ----
    gemm_bf16<true, false, false><<<dim3(24 * 32), blk, 0, stream>>>(
        Xn_b16, 1024, Wqkv_t, 1024, 0, bqkv, nullptr, QKV, nullptr, 3072, 1024, 24);
    // ---- V^T ----
    transpose_v_bf16<<<dim3(32, 32, 4), blk, 0, stream>>>(QKV, Vt);
    // ---- S = K Q^T (batched, split-K=2, bf16 partials) ----
    gemm_bf16_splitk<<<dim3(8 * 32, 1, 2), blk, 0, stream>>>(
        QKV + 1024, 3072, QKV, 3072, BT_QKV, zbias, S0h, PSTRIDE_H, 1024, 512, 8);
    // ---- T = Q relPad^T ----
    gemm_bf16<false, false, false><<<dim3(1 * 32), blk, 0, stream>>>(
        QKV, 3072, relbPad, 1024, 0, zbias, Tmat, nullptr, nullptr, 128, 1024, 1);
    // ---- zero A,G; scatter scores ----
    hipMemsetAsync(ws + 49 * MB, 0, 17 * MB, stream);
    edge_scatter<<<512, blk, 0, stream>>>(S0h, S0h + PSTRIDE_H, Tmat, esrc, edst, erel, Amat, Gmat);
    // ---- normalize (rz inline) ----
    normalize<<<M_ROWS, blk, 0, stream>>>(Amat, Gmat, An, Gn);
    // ---- wv = Gn @ relbT^T (f32 tmp), then An @ Vt^T + tmp -> Obf ----
    gemm_bf16<false, false, false><<<dim3(8 * 32), blk, 0, stream>>>(
        Gn, 64, relbT, 64, 0, zbias, tmp, nullptr, nullptr, 1024, 64, 8);
    gemm_bf16<true, false, true><<<dim3(8 * 32), blk, 0, stream>>>(
        An, 1024, Vt, 1024, BT_VT, zbias, nullptr, Obf, tmp, 1024, 1024, 8);
    // ---- o @ Wo + bo (split-K=2, bf16 partials) ----
    gemm_bf16_splitk<<<dim3(8 * 32, 1, 2), blk, 0, stream>>>(
        Obf, 1024, Wo_t, 1024, 0, bo, PwoH, PSTRIDE_H, 1024, 512, 8);
    // ---- LN1 ----
    ln_kernel<1, 2><<<M_ROWS, blk, 0, stream>>>(Xn_f32, nullptr, PwoH, PSTRIDE_H, ln1_g, ln1_b,
                                                nullptr, Out_b16, nullptr, nullptr);
    // ---- FFN1 ----
    gemm_bf16<true, true, false><<<dim3(32 * 32), blk, 0, stream>>>(
        Out_b16, 1024, W1_t, 1024, 0, b1, nullptr, H1, nullptr, 4096, 1024, 32);
    // ---- W2 (split-K=4, bf16 partials) ----
    gemm_bf16_splitk<<<dim3(8 * 32, 1, 4), blk, 0, stream>>>(
        H1, 4096, W2_t, 4096, 0, b2, Qw2H, PSTRIDE_H, 1024, 1024, 8);
    // ---- LN2 + elu + residual ----
    ln_kernel<2, 4><<<M_ROWS, blk, 0, stream>>>(nullptr, Out_b16, Qw2H, PSTRIDE_H, ln2_g, ln2_b,
                                                nullptr, nullptr, hidden, out);
    (void)in_sizes; (void)n_in; (void)out_size; (void)ws_size;
}

// Round 7
// 376.523 us; speedup vs baseline: 1.3097x; 1.0676x over previous
//
#include <hip/hip_runtime.h>
#include <hip/hip_bf16.h>

#define B_SZ 4
#define L_SEQ 1024
#define D_MODEL 1024
#define DF_FF 4096
#define E_PER_B 32768
#define R_REL 64
#define M_ROWS (B_SZ * L_SEQ)   // 4096

typedef __attribute__((ext_vector_type(8))) short bf16x8;
typedef __attribute__((ext_vector_type(4))) float f32x4;

__device__ inline float b2f(unsigned short u) {
    union { unsigned int i; float f; } x; x.i = ((unsigned int)u) << 16; return x.f;
}
__device__ inline unsigned short f2b(float f) {
    union { float f; unsigned int u; } x; x.f = f;
    unsigned int r = x.u + 0x7FFFu + ((x.u >> 16) & 1u);
    return (unsigned short)(r >> 16);
}

#define GLOBAL_CAST(p) ((const __attribute__((address_space(1))) void*)(p))
#define LDS_CAST(p)    ((__attribute__((address_space(3))) void*)(p))

#define LDB_WV 1088                      // [V | rel] combined K width (17*64)
#define BT_WV  (1024u * 1088u)           // per-batch Bwv stride (elements)
#define BT_QKV (1024u * 3072u)           // per-batch QKV stride
#define SEXT_M 1152                      // S_ext rows per batch: 1024 src + 128 relPad

// ---------------- fused prep ----------------
// flat grid 13836 blocks:
//   [0,4096)       Wq,Wk,Wv -> Wqkv_t ; Wo -> Wo_t (32x32 transpose tiles)
//   [4096,8192)    W1 -> W1_t
//   [8192,12288)   W2 -> W2_t
//   [12288,12800)  relbPad bf16 [128,1024] (rows 64..127 zero)
//   [12800,13824)  Bwv rel columns: Bwv[b][d][1024+r] = rel[r,d]  (4x1024x64)
//   [13824,13836)  bqkv f32 [3072] (cols 1024+ = 0 -> zbias)
__global__ void prep_all(const float* __restrict__ Wq, const float* __restrict__ Wk,
                         const float* __restrict__ Wv, const float* __restrict__ Wo,
                         const float* __restrict__ W1, const float* __restrict__ W2,
                         const float* __restrict__ rel, const float* __restrict__ bq,
                         unsigned short* __restrict__ Wqkv_t, unsigned short* __restrict__ Wo_t,
                         unsigned short* __restrict__ W1_t, unsigned short* __restrict__ W2_t,
                         unsigned short* __restrict__ relbPad, unsigned short* __restrict__ Bwv,
                         float* __restrict__ bqkv) {
    __shared__ float tile[32][33];
    const int id = blockIdx.x, tid = threadIdx.x;
    if (id < 12288) {
        const float* src; unsigned short* dst; int K, N, x, y;
        if (id < 4096) {
            const int seg = id >> 10, t = id & 1023;
            K = 1024; N = 1024; x = t & 31; y = t >> 5;
            src = (seg == 0) ? Wq : (seg == 1) ? Wk : (seg == 2) ? Wv : Wo;
            dst = (seg == 3) ? Wo_t : (Wqkv_t + (size_t)seg * 1048576);
        } else if (id < 8192) {
            const int t = id - 4096; K = 1024; N = 4096; x = t & 127; y = t >> 7;
            src = W1; dst = W1_t;
        } else {
            const int t = id - 8192; K = 4096; N = 1024; x = t & 31; y = t >> 5;
            src = W2; dst = W2_t;
        }
        const int n0 = x * 32, k0 = y * 32, tx = tid & 31, ty = tid >> 5;
#pragma unroll
        for (int r = 0; r < 32; r += 8)
            tile[ty + r][tx] = src[(size_t)(k0 + ty + r) * N + (n0 + tx)];
        __syncthreads();
#pragma unroll
        for (int r = 0; r < 32; r += 8)
            dst[(size_t)(n0 + ty + r) * K + (k0 + tx)] = f2b(tile[tx][ty + r]);
    } else if (id < 12800) {
        const int i = (id - 12288) * 256 + tid;            // 131072
        relbPad[i] = (i < 65536) ? f2b(rel[i]) : (unsigned short)0;
    } else if (id < 13824) {
        const int i = (id - 12800) * 256 + tid;            // 262144
        const int b = i >> 16, rem = i & 65535, d = rem >> 6, r = rem & 63;
        Bwv[(size_t)b * BT_WV + (size_t)d * LDB_WV + 1024 + r] = f2b(rel[r * 1024 + d]);
    } else {
        const int i = (id - 13824) * 256 + tid;            // 3072
        bqkv[i] = (i < 1024) ? bq[i] : 0.0f;
    }
}

// V^T per batch into Bwv cols 0..1023: Bwv[b][d][s] = QKV[(b<<10)+s, 2048+d]
__global__ void transpose_v_bf16(const unsigned short* __restrict__ QKV,
                                 unsigned short* __restrict__ Bwv) {
    __shared__ unsigned short tile[32][33];
    const int b = blockIdx.z;
    const int d0 = blockIdx.x * 32, s0 = blockIdx.y * 32;
    const int tx = threadIdx.x & 31, ty = threadIdx.x >> 5;  // 32 x 8
#pragma unroll
    for (int r = 0; r < 32; r += 8)
        tile[ty + r][tx] = QKV[(size_t)((b << 10) + s0 + ty + r) * 3072 + 2048 + d0 + tx];
    __syncthreads();
#pragma unroll
    for (int r = 0; r < 32; r += 8)
        Bwv[(size_t)b * BT_WV + (size_t)(d0 + ty + r) * LDB_WV + s0 + tx] = tile[tx][ty + r];
}

// XCD-aware tile swizzle: XCD = linear_id % 8. Group all tile_n of a tile_m on one XCD.
__device__ inline void tile_swizzle(int id, int ntn, int& tm, int& tn) {
    tm = ((id & 7) + ((id >> 3) / ntn) * 8) * 128;
    tn = ((id >> 3) % ntn) * 128;
}

// ---------------- GEMM: C[M,N] = A[M,K](bf16, lda) * Bt[N,K](bf16, ldb)^T + bias ----------------
// BK=64 (32KB LDS): 32 MFMA per barrier-pair. XOR swizzle slot = chunk ^ (row&7) -> 0 conflicts.
template<bool OUT_BF16, bool RELU>
__global__ __launch_bounds__(256, 4)
void gemm_bf16(const unsigned short* __restrict__ A, int lda,
               const unsigned short* __restrict__ Bt, int ldb, size_t bt_batch,
               const float* __restrict__ bias,
               float* __restrict__ Cf, unsigned short* __restrict__ Cb,
               int N, int K, int ntn) {
    __shared__ unsigned short lA[128 * 64];
    __shared__ unsigned short lB[128 * 64];
    int tile_m, tile_n;
    tile_swizzle(blockIdx.x, ntn, tile_m, tile_n);
    const int t = threadIdx.x;
    const int wave = t >> 6, lane = t & 63;
    const int wm = (wave >> 1) * 64, wn = (wave & 1) * 64;
    const int quad = lane >> 4, l16 = lane & 15;

    const int srow = lane >> 3;
    const int schunk = ((lane & 7) ^ srow) * 8;
    const unsigned short* gA = A + (size_t)(tile_m + wave * 32 + srow) * lda + schunk;
    const unsigned short* gB = Bt + (size_t)(tile_m >> 10) * bt_batch
                                  + (size_t)(tile_n + wave * 32 + srow) * ldb + schunk;

    f32x4 acc[4][4];
#pragma unroll
    for (int i = 0; i < 4; i++)
#pragma unroll
        for (int j = 0; j < 4; j++) acc[i][j] = (f32x4)0.0f;

    for (int k0 = 0; k0 < K; k0 += 64) {
        __syncthreads();
#pragma unroll
        for (int r = 0; r < 4; ++r) {
            __builtin_amdgcn_global_load_lds(GLOBAL_CAST(gA + (size_t)r * 8 * lda),
                                             LDS_CAST(&lA[(wave * 32 + r * 8) * 64]), 16, 0, 0);
            __builtin_amdgcn_global_load_lds(GLOBAL_CAST(gB + (size_t)r * 8 * ldb),
                                             LDS_CAST(&lB[(wave * 32 + r * 8) * 64]), 16, 0, 0);
        }
        gA += 64; gB += 64;
        __builtin_amdgcn_s_waitcnt(0);
        __syncthreads();

#pragma unroll
        for (int kk = 0; kk < 2; ++kk) {
            const int cb = kk * 4 + quad;
            bf16x8 af[4], bf[4];
#pragma unroll
            for (int i = 0; i < 4; i++) {
                const int ra = wm + i * 16 + l16;
                af[i] = *(const bf16x8*)&lA[ra * 64 + ((cb ^ (ra & 7)) * 8)];
                const int rb = wn + i * 16 + l16;
                bf[i] = *(const bf16x8*)&lB[rb * 64 + ((cb ^ (rb & 7)) * 8)];
            }
#pragma unroll
            for (int mi = 0; mi < 4; mi++)
#pragma unroll
                for (int ni = 0; ni < 4; ni++)
                    acc[mi][ni] = __builtin_amdgcn_mfma_f32_16x16x32_bf16(af[mi], bf[ni], acc[mi][ni], 0, 0, 0);
        }
    }

#pragma unroll
    for (int mi = 0; mi < 4; mi++) {
#pragma unroll
        for (int ni = 0; ni < 4; ni++) {
            const int col = tile_n + wn + ni * 16 + l16;
            const float bv = bias[col];
#pragma unroll
            for (int r = 0; r < 4; r++) {
                const int row = tile_m + wm + mi * 16 + quad * 4 + r;
                float v = acc[mi][ni][r] + bv;
                if (RELU) v = fmaxf(v, 0.0f);
                if (OUT_BF16) Cb[(size_t)row * N + col] = f2b(v);
                else          Cf[(size_t)row * N + col] = v;
            }
        }
    }
}

// split-K: blockIdx.z = z over K-range [z*Kc,(z+1)*Kc); bf16 partial at Pbase + z*pstride.
__global__ __launch_bounds__(256, 4)
void gemm_bf16_splitk(const unsigned short* __restrict__ A, int lda,
                      const unsigned short* __restrict__ Bt, int ldb, size_t bt_batch,
                      const float* __restrict__ bias,
                      unsigned short* __restrict__ Pbase, size_t pstride,
                      int N, int Kc, int ntn) {
    __shared__ unsigned short lA[128 * 64];
    __shared__ unsigned short lB[128 * 64];
    int tile_m, tile_n;
    tile_swizzle(blockIdx.x, ntn, tile_m, tile_n);
    const int z = blockIdx.z;
    const int kofs = z * Kc;
    const int t = threadIdx.x;
    const int wave = t >> 6, lane = t & 63;
    const int wm = (wave >> 1) * 64, wn = (wave & 1) * 64;
    const int quad = lane >> 4, l16 = lane & 15;

    const int srow = lane >> 3;
    const int schunk = ((lane & 7) ^ srow) * 8;
    const unsigned short* gA = A + (size_t)(tile_m + wave * 32 + srow) * lda + kofs + schunk;
    const unsigned short* gB = Bt + (size_t)(tile_m >> 10) * bt_batch
                                  + (size_t)(tile_n + wave * 32 + srow) * ldb + kofs + schunk;

    f32x4 acc[4][4];
#pragma unroll
    for (int i = 0; i < 4; i++)
#pragma unroll
        for (int j = 0; j < 4; j++) acc[i][j] = (f32x4)0.0f;

    for (int k0 = 0; k0 < Kc; k0 += 64) {
        __syncthreads();
#pragma unroll
        for (int r = 0; r < 4; ++r) {
            __builtin_amdgcn_global_load_lds(GLOBAL_CAST(gA + (size_t)r * 8 * lda),
                                             LDS_CAST(&lA[(wave * 32 + r * 8) * 64]), 16, 0, 0);
            __builtin_amdgcn_global_load_lds(GLOBAL_CAST(gB + (size_t)r * 8 * ldb),
                                             LDS_CAST(&lB[(wave * 32 + r * 8) * 64]), 16, 0, 0);
        }
        gA += 64; gB += 64;
        __builtin_amdgcn_s_waitcnt(0);
        __syncthreads();

#pragma unroll
        for (int kk = 0; kk < 2; ++kk) {
            const int cb = kk * 4 + quad;
            bf16x8 af[4], bf[4];
#pragma unroll
            for (int i = 0; i < 4; i++) {
                const int ra = wm + i * 16 + l16;
                af[i] = *(const bf16x8*)&lA[ra * 64 + ((cb ^ (ra & 7)) * 8)];
                const int rb = wn + i * 16 + l16;
                bf[i] = *(const bf16x8*)&lB[rb * 64 + ((cb ^ (rb & 7)) * 8)];
            }
#pragma unroll
            for (int mi = 0; mi < 4; mi++)
#pragma unroll
                for (int ni = 0; ni < 4; ni++)
                    acc[mi][ni] = __builtin_amdgcn_mfma_f32_16x16x32_bf16(af[mi], bf[ni], acc[mi][ni], 0, 0, 0);
        }
    }

    unsigned short* P = Pbase + (size_t)z * pstride;
#pragma unroll
    for (int mi = 0; mi < 4; mi++) {
#pragma unroll
        for (int ni = 0; ni < 4; ni++) {
            const int col = tile_n + wn + ni * 16 + l16;
            const float bv = (z == 0) ? bias[col] : 0.0f;
#pragma unroll
            for (int r = 0; r < 4; r++) {
                const int row = tile_m + wm + mi * 16 + quad * 4 + r;
                P[(size_t)row * N + col] = f2b(acc[mi][ni][r] + bv);
            }
        }
    }
}

// S_ext = [K(1024) ; relbPad(128)] @ Q^T per batch, split-K=2, bf16 partials.
// grid (72, B, 2): tile_m = (bx>>3)*128 in [0,1152), tile_n = (bx&7)*128.
// Output P[z][b][1152][1024]: rows 0-1023 = S[src,dst], rows 1024.. = T^T[r,dst].
__global__ __launch_bounds__(256, 4)
void gemm_sext(const unsigned short* __restrict__ QKV,
               const unsigned short* __restrict__ relPad,
               unsigned short* __restrict__ Pbase, int Kc) {
    __shared__ unsigned short lA[128 * 64];
    __shared__ unsigned short lB[128 * 64];
    const int bx = blockIdx.x, b = blockIdx.y, z = blockIdx.z;
    const int tile_m = (bx >> 3) * 128;
    const int tile_n = (bx & 7) * 128;
    const int kofs = z * Kc;
    const int t = threadIdx.x;
    const int wave = t >> 6, lane = t & 63;
    const int wm = (wave >> 1) * 64, wn = (wave & 1) * 64;
    const int quad = lane >> 4, l16 = lane & 15;

    const int srow = lane >> 3;
    const int schunk = ((lane & 7) ^ srow) * 8;
    const int arow = tile_m + wave * 32 + srow;
    const unsigned short* gA;
    size_t lda;
    if (tile_m < 1024) {   // K rows
        gA = QKV + (size_t)b * BT_QKV + (size_t)arow * 3072 + 1024 + kofs + schunk;
        lda = 3072;
    } else {               // relPad rows (shared across batches)
        gA = relPad + (size_t)(arow - 1024) * 1024 + kofs + schunk;
        lda = 1024;
    }
    const unsigned short* gB = QKV + (size_t)b * BT_QKV
                                   + (size_t)(tile_n + wave * 32 + srow) * 3072 + kofs + schunk;

    f32x4 acc[4][4];
#pragma unroll
    for (int i = 0; i < 4; i++)
#pragma unroll
        for (int j = 0; j < 4; j++) acc[i][j] = (f32x4)0.0f;

    for (int k0 = 0; k0 < Kc; k0 += 64) {
        __syncthreads();
#pragma unroll
        for (int r = 0; r < 4; ++r) {
            __builtin_amdgcn_global_load_lds(GLOBAL_CAST(gA + (size_t)r * 8 * lda),
                                             LDS_CAST(&lA[(wave * 32 + r * 8) * 64]), 16, 0, 0);
            __builtin_amdgcn_global_load_lds(GLOBAL_CAST(gB + (size_t)r * 8 * 3072),
                                             LDS_CAST(&lB[(wave * 32 + r * 8) * 64]), 16, 0, 0);
        }
        gA += 64; gB += 64;
        __builtin_amdgcn_s_waitcnt(0);
        __syncthreads();

#pragma unroll
        for (int kk = 0; kk < 2; ++kk) {
            const int cb = kk * 4 + quad;
            bf16x8 af[4], bf[4];
#pragma unroll
            for (int i = 0; i < 4; i++) {
                const int ra = wm + i * 16 + l16;
                af[i] = *(const bf16x8*)&lA[ra * 64 + ((cb ^ (ra & 7)) * 8)];
                const int rb = wn + i * 16 + l16;
                bf[i] = *(const bf16x8*)&lB[rb * 64 + ((cb ^ (rb & 7)) * 8)];
            }
#pragma unroll
            for (int mi = 0; mi < 4; mi++)
#pragma unroll
                for (int ni = 0; ni < 4; ni++)
                    acc[mi][ni] = __builtin_amdgcn_mfma_f32_16x16x32_bf16(af[mi], bf[ni], acc[mi][ni], 0, 0, 0);
        }
    }

    unsigned short* P = Pbase + ((size_t)z * B_SZ + b) * (SEXT_M * 1024);
#pragma unroll
    for (int mi = 0; mi < 4; mi++) {
#pragma unroll
        for (int ni = 0; ni < 4; ni++) {
            const int col = tile_n + wn + ni * 16 + l16;
#pragma unroll
            for (int r = 0; r < 4; r++) {
                const int row = tile_m + wm + mi * 16 + quad * 4 + r;
                P[(size_t)row * 1024 + col] = f2b(acc[mi][ni][r]);
            }
        }
    }
}

// ---------------- LayerNorm family ----------------
// partials are bf16 (split-K outputs). MODE 0: LN(X_f32) -> of32+ob16.
// MODE 1: LN(X_f32 + sum NR partials) -> ob16. MODE 2: LN(X_bf16 + sum NR partials);
// fout = hidden + elu(y).
template<int MODE, int NR>
__global__ void ln_kernel(const float* __restrict__ X, const unsigned short* __restrict__ Xb,
                          const unsigned short* __restrict__ Rbase, size_t rstride,
                          const float* __restrict__ g, const float* __restrict__ be,
                          float* __restrict__ of32, unsigned short* __restrict__ ob16,
                          const float* __restrict__ hidden, float* __restrict__ fout) {
    __shared__ float sb1[4], sb2[4];
    const int row = blockIdx.x, t = threadIdx.x;
    const size_t base = (size_t)row * 1024 + t * 4;

    float x0, x1, x2, x3;
    if (MODE == 2) {
        ushort4 xv = *(const ushort4*)(Xb + base);
        x0 = b2f(xv.x); x1 = b2f(xv.y); x2 = b2f(xv.z); x3 = b2f(xv.w);
    } else {
        float4 xv = *(const float4*)(X + base);
        x0 = xv.x; x1 = xv.y; x2 = xv.z; x3 = xv.w;
    }
#pragma unroll
    for (int r = 0; r < NR; r++) {
        ushort4 rv = *(const ushort4*)(Rbase + r * rstride + base);
        x0 += b2f(rv.x); x1 += b2f(rv.y); x2 += b2f(rv.z); x3 += b2f(rv.w);
    }
    float s = x0 + x1 + x2 + x3;
#pragma unroll
    for (int o = 32; o > 0; o >>= 1) s += __shfl_down(s, o);
    if ((t & 63) == 0) sb1[t >> 6] = s;
    __syncthreads();
    const float mu = (sb1[0] + sb1[1] + sb1[2] + sb1[3]) * (1.0f / 1024.0f);

    const float d0 = x0 - mu, d1 = x1 - mu, d2 = x2 - mu, d3 = x3 - mu;
    float s2 = d0 * d0 + d1 * d1 + d2 * d2 + d3 * d3;
#pragma unroll
    for (int o = 32; o > 0; o >>= 1) s2 += __shfl_down(s2, o);
    if ((t & 63) == 0) sb2[t >> 6] = s2;
    __syncthreads();
    const float var = (sb2[0] + sb2[1] + sb2[2] + sb2[3]) * (1.0f / 1024.0f);
    const float rstd = rsqrtf(var + 1e-6f);

    const float4 gv = *(const float4*)(g + t * 4);
    const float4 bv = *(const float4*)(be + t * 4);
    const float y0 = d0 * rstd * gv.x + bv.x;
    const float y1 = d1 * rstd * gv.y + bv.y;
    const float y2 = d2 * rstd * gv.z + bv.z;
    const float y3 = d3 * rstd * gv.w + bv.w;

    if (MODE == 0) {
        float4 o; o.x = y0; o.y = y1; o.z = y2; o.w = y3;
        *(float4*)(of32 + base) = o;
    }
    if (MODE <= 1) {
        ushort4 ob; ob.x = f2b(y0); ob.y = f2b(y1); ob.z = f2b(y2); ob.w = f2b(y3);
        *(ushort4*)(ob16 + base) = ob;
    } else {
        const float4 hv = *(const float4*)(hidden + base);
        const float e0 = y0 > 0.0f ? y0 : expm1f(y0);
        const float e1 = y1 > 0.0f ? y1 : expm1f(y1);
        const float e2 = y2 > 0.0f ? y2 : expm1f(y2);
        const float e3 = y3 > 0.0f ? y3 : expm1f(y3);
        float4 o; o.x = hv.x + e0; o.y = hv.y + e1; o.z = hv.z + e2; o.w = hv.w + e3;
        *(float4*)(fout + base) = o;
    }
}

// ---------------- dense edge phase ----------------
// per edge: sc = exp(clip((S[src,dst] + T^T[r,dst])/32)); A[dst,src]+=sc; G[dst,r]+=sc
// S is the S_ext bf16 split-K pair: partial z at S + z*ZSTR, batch rows b*1152.
__global__ void edge_scatter(const unsigned short* __restrict__ S,
                             const int* __restrict__ src, const int* __restrict__ dst,
                             const int* __restrict__ rel,
                             float* __restrict__ A, float* __restrict__ G) {
    const size_t ZSTR = (size_t)B_SZ * SEXT_M * 1024;
    const int gg = blockIdx.x * 256 + threadIdx.x;   // B*E = 131072
    const int b = gg >> 15;
    const int s = src[gg], d = dst[gg], r = rel[gg];
    const size_t sbase = ((size_t)b * SEXT_M + s) * 1024 + d;
    const size_t tbase = ((size_t)b * SEXT_M + 1024 + r) * 1024 + d;
    const float sval = b2f(S[sbase]) + b2f(S[sbase + ZSTR]);
    const float tval = b2f(S[tbase]) + b2f(S[tbase + ZSTR]);
    float sc = (sval + tval) * (1.0f / 32.0f);
    sc = expf(fminf(fmaxf(sc, -10.0f), 10.0f));
    atomicAdd(&A[((size_t)((b << 10) + d) << 10) + s], sc);
    atomicAdd(&G[((size_t)((b << 10) + d) << 6) + r], sc);
}

// per node: inv = 1/sum_r G[row,r]; Awv[row] = bf16([A*inv | G*inv])  (1088-wide)
__global__ void normalize(const float* __restrict__ A, const float* __restrict__ G,
                          unsigned short* __restrict__ Awv) {
    __shared__ float sInv;
    const int row = blockIdx.x, t = threadIdx.x;
    float v = 0.0f;
    if (t < 64) {
        v = G[(size_t)row * 64 + t];
        float s = v;
#pragma unroll
        for (int o = 1; o < 64; o <<= 1) s += __shfl_xor(s, o);
        if (t == 0) sInv = 1.0f / s;
    }
    __syncthreads();
    const float inv = sInv;
    const size_t obase = (size_t)row * LDB_WV;
    const float4 a = *(const float4*)(A + (size_t)row * 1024 + t * 4);
    ushort4 o;
    o.x = f2b(a.x * inv); o.y = f2b(a.y * inv); o.z = f2b(a.z * inv); o.w = f2b(a.w * inv);
    *(ushort4*)(Awv + obase + t * 4) = o;
    if (t < 16) {
        const float4 gq = *(const float4*)(G + (size_t)row * 64 + t * 4);
        ushort4 og;
        og.x = f2b(gq.x * inv); og.y = f2b(gq.y * inv);
        og.z = f2b(gq.z * inv); og.w = f2b(gq.w * inv);
        *(ushort4*)(Awv + obase + 1024 + t * 4) = og;
    }
}

// ---------------- launch ----------------
extern "C" void kernel_launch(void* const* d_in, const int* in_sizes, int n_in,
                              void* d_out, int out_size, void* d_ws, size_t ws_size,
                              hipStream_t stream) {
    const float* hidden  = (const float*)d_in[0];
    const float* rel_tbl = (const float*)d_in[1];
    const float* Wq = (const float*)d_in[2];
    const float* bq = (const float*)d_in[3];
    const float* Wk = (const float*)d_in[4];
    const float* Wv = (const float*)d_in[5];
    const float* Wo = (const float*)d_in[6];
    const float* bo = (const float*)d_in[7];
    const float* ln0_g = (const float*)d_in[8];
    const float* ln0_b = (const float*)d_in[9];
    const float* ln1_g = (const float*)d_in[10];
    const float* ln1_b = (const float*)d_in[11];
    const float* W1 = (const float*)d_in[12];
    const float* b1 = (const float*)d_in[13];
    const float* W2 = (const float*)d_in[14];
    const float* b2 = (const float*)d_in[15];
    const float* ln2_g = (const float*)d_in[16];
    const float* ln2_b = (const float*)d_in[17];
    const int* esrc = (const int*)d_in[18];
    const int* edst = (const int*)d_in[19];
    const int* erel = (const int*)d_in[20];
    float* out = (float*)d_out;

    // ws lifetime map (peak 121MB), time-ordered overlay:
    //  0-16    Xn_f32 [LN0->LN1]  ; 0-32 H1 [FFN1->W2] (Wo_t 30-32 dead by then)
    // 16-24    Xn_b16 [LN0->QKV]
    // 24-30    Wqkv_t ; 30-32 Wo_t [prep->Wo]
    // 32-40    W1_t ; 40-48 W2_t
    // 48-48.25 relbPad [prep->Sext] ; 48.5 bqkv+zbias
    // 49-73    QKV [QKVg->Vt,Sext] ; then 49-58 Awv [norm->wv] ; 58-66 Obf [wv->Wo]
    //          then 49-81 Qw2H x4 [W2->LN2]
    // 66-82    PwoH x2 [Wo->LN1]  (overlaps SxH tail: SxH dead after scatter)
    // 73-92    SxH (2x4x1152x1024 bf16 = 18.9MB) [Sext->scatter]
    // 92-101   Bwv [prep(rel)+Vt->wv]
    // 101-117  Amat ; 117-118 Gmat [memset->normalize]
    // 113-121  Out_b16 [LN1->FFN1,LN2] (Amat dead by then)
    char* ws = (char*)d_ws;
    const size_t MB = 1024 * 1024;
    float*          Xn_f32  = (float*)(ws + 0);
    unsigned short* Xn_b16  = (unsigned short*)(ws + 16 * MB);
    unsigned short* H1      = (unsigned short*)(ws + 0);
    unsigned short* Wqkv_t  = (unsigned short*)(ws + 24 * MB);
    unsigned short* Wo_t    = (unsigned short*)(ws + 30 * MB);
    unsigned short* W1_t    = (unsigned short*)(ws + 32 * MB);
    unsigned short* W2_t    = (unsigned short*)(ws + 40 * MB);
    unsigned short* relbPad = (unsigned short*)(ws + 48 * MB);
    float*          bqkv    = (float*)(ws + 48 * MB + 512 * 1024);
    const float*    zbias   = bqkv + 1024;  // 2048 zeros
    unsigned short* QKV     = (unsigned short*)(ws + 49 * MB);
    unsigned short* Awv     = (unsigned short*)(ws + 49 * MB);
    unsigned short* Obf     = (unsigned short*)(ws + 58 * MB);
    unsigned short* Qw2H    = (unsigned short*)(ws + 49 * MB);
    unsigned short* PwoH    = (unsigned short*)(ws + 66 * MB);
    unsigned short* SxH     = (unsigned short*)(ws + 73 * MB);
    unsigned short* Bwv     = (unsigned short*)(ws + 92 * MB);
    float*          Amat    = (float*)(ws + 101 * MB);
    float*          Gmat    = (float*)(ws + 117 * MB);
    unsigned short* Out_b16 = (unsigned short*)(ws + 113 * MB);

    const size_t PSTRIDE_H = 4u * 1024 * 1024;   // 8MB bf16 partial, in ushorts
    const dim3 blk(256);

    // ---- fused prep ----
    prep_all<<<13836, blk, 0, stream>>>(Wq, Wk, Wv, Wo, W1, W2, rel_tbl, bq,
                                        Wqkv_t, Wo_t, W1_t, W2_t, relbPad, Bwv, bqkv);
    // ---- LN0 ----
    ln_kernel<0, 0><<<M_ROWS, blk, 0, stream>>>(hidden, nullptr, nullptr, 0, ln0_g, ln0_b,
                                                Xn_f32, Xn_b16, nullptr, nullptr);
    // ---- QKV GEMM ----
    gemm_bf16<true, false><<<dim3(24 * 32), blk, 0, stream>>>(
        Xn_b16, 1024, Wqkv_t, 1024, 0, bqkv, nullptr, QKV, 3072, 1024, 24);
    // ---- V^T into Bwv ----
    transpose_v_bf16<<<dim3(32, 32, 4), blk, 0, stream>>>(QKV, Bwv);
    // ---- S_ext = [K;relPad] Q^T (batched, split-K=2, bf16 partials; rows 1024+ = T^T) ----
    gemm_sext<<<dim3(72, B_SZ, 2), blk, 0, stream>>>(QKV, relbPad, SxH, 512);
    // ---- zero A,G; scatter scores ----
    hipMemsetAsync(ws + 101 * MB, 0, 17 * MB, stream);
    edge_scatter<<<512, blk, 0, stream>>>(SxH, esrc, edst, erel, Amat, Gmat);
    // ---- normalize -> Awv [4096,1088] ----
    normalize<<<M_ROWS, blk, 0, stream>>>(Amat, Gmat, Awv);
    // ---- wv: Obf = Awv @ Bwv^T  (K=1088, batched B) ----
    gemm_bf16<true, false><<<dim3(8 * 32), blk, 0, stream>>>(
        Awv, LDB_WV, Bwv, LDB_WV, BT_WV, zbias, nullptr, Obf, 1024, LDB_WV, 8);
    // ---- o @ Wo + bo (split-K=2, bf16 partials) ----
    gemm_bf16_splitk<<<dim3(8 * 32, 1, 2), blk, 0, stream>>>(
        Obf, 1024, Wo_t, 1024, 0, bo, PwoH, PSTRIDE_H, 1024, 512, 8);
    // ---- LN1 ----
    ln_kernel<1, 2><<<M_ROWS, blk, 0, stream>>>(Xn_f32, nullptr, PwoH, PSTRIDE_H, ln1_g, ln1_b,
                                                nullptr, Out_b16, nullptr, nullptr);
    // ---- FFN1 ----
    gemm_bf16<true, true><<<dim3(32 * 32), blk, 0, stream>>>(
        Out_b16, 1024, W1_t, 1024, 0, b1, nullptr, H1, 4096, 1024, 32);
    // ---- W2 (split-K=4, bf16 partials) ----
    gemm_bf16_splitk<<<dim3(8 * 32, 1, 4), blk, 0, stream>>>(
        H1, 4096, W2_t, 4096, 0, b2, Qw2H, PSTRIDE_H, 1024, 1024, 8);
    // ---- LN2 + elu + residual ----
    ln_kernel<2, 4><<<M_ROWS, blk, 0, stream>>>(nullptr, Out_b16, Qw2H, PSTRIDE_H, ln2_g, ln2_b,
                                                nullptr, nullptr, hidden, out);
    (void)in_sizes; (void)n_in; (void)out_size; (void)ws_size;
}

// Round 9
// 369.239 us; speedup vs baseline: 1.3355x; 1.0197x over previous
//
#include <hip/hip_runtime.h>
#include <hip/hip_bf16.h>

#define B_SZ 4
#define L_SEQ 1024
#define D_MODEL 1024
#define DF_FF 4096
#define E_PER_B 32768
#define R_REL 64
#define M_ROWS (B_SZ * L_SEQ)   // 4096

typedef __attribute__((ext_vector_type(8))) short bf16x8;
typedef __attribute__((ext_vector_type(4))) float f32x4;

__device__ inline float b2f(unsigned short u) {
    union { unsigned int i; float f; } x; x.i = ((unsigned int)u) << 16; return x.f;
}
__device__ inline unsigned short f2b(float f) {
    union { float f; unsigned int u; } x; x.f = f;
    unsigned int r = x.u + 0x7FFFu + ((x.u >> 16) & 1u);
    return (unsigned short)(r >> 16);
}

#define GLOBAL_CAST(p) ((const __attribute__((address_space(1))) void*)(p))
#define LDS_CAST(p)    ((__attribute__((address_space(3))) void*)(p))

#define LDB_WV 1088                      // [V | rel] combined K width (17*64)
#define BT_WV  (1024u * 1088u)           // per-batch Bwv stride (elements)
#define BT_QKV (1024u * 3072u)           // per-batch QKV stride
#define SEXT_M 1152                      // S_ext rows per batch: 1024 src + 128 relPad

// ---------------- fused prep: weights + rel + bias + LN0 + zero(A|G) ----------------
// flat grid 19020 blocks:
//   [0,12288)      weight transposes (Wq,Wk,Wv,Wo,W1,W2)
//   [12288,12800)  relbPad bf16 [128,1024] (rows 64..127 zero)
//   [12800,13824)  Bwv rel columns: Bwv[b][d][1024+r] = rel[r,d]
//   [13824,13836)  bqkv f32 [3072] (cols 1024+ = 0 -> zbias)
//   [13836,17932)  LN0: row = id-13836; Xn_f32 + Xn_b16 = LN(hidden)
//   [17932,19020)  zero 17MB A|G region (16KB per block)
__global__ void prep_all(const float* __restrict__ Wq, const float* __restrict__ Wk,
                         const float* __restrict__ Wv, const float* __restrict__ Wo,
                         const float* __restrict__ W1, const float* __restrict__ W2,
                         const float* __restrict__ rel, const float* __restrict__ bq,
                         const float* __restrict__ hidden,
                         const float* __restrict__ ln0_g, const float* __restrict__ ln0_b,
                         unsigned short* __restrict__ Wqkv_t, unsigned short* __restrict__ Wo_t,
                         unsigned short* __restrict__ W1_t, unsigned short* __restrict__ W2_t,
                         unsigned short* __restrict__ relbPad, unsigned short* __restrict__ Bwv,
                         float* __restrict__ bqkv,
                         float* __restrict__ Xn_f32, unsigned short* __restrict__ Xn_b16,
                         float* __restrict__ zeroReg) {
    __shared__ float tile[32][33];
    __shared__ float sb1[4], sb2[4];
    const int id = blockIdx.x, tid = threadIdx.x;
    if (id < 12288) {
        const float* src; unsigned short* dst; int K, N, x, y;
        if (id < 4096) {
            const int seg = id >> 10, t = id & 1023;
            K = 1024; N = 1024; x = t & 31; y = t >> 5;
            src = (seg == 0) ? Wq : (seg == 1) ? Wk : (seg == 2) ? Wv : Wo;
            dst = (seg == 3) ? Wo_t : (Wqkv_t + (size_t)seg * 1048576);
        } else if (id < 8192) {
            const int t = id - 4096; K = 1024; N = 4096; x = t & 127; y = t >> 7;
            src = W1; dst = W1_t;
        } else {
            const int t = id - 8192; K = 4096; N = 1024; x = t & 31; y = t >> 5;
            src = W2; dst = W2_t;
        }
        const int n0 = x * 32, k0 = y * 32, tx = tid & 31, ty = tid >> 5;
#pragma unroll
        for (int r = 0; r < 32; r += 8)
            tile[ty + r][tx] = src[(size_t)(k0 + ty + r) * N + (n0 + tx)];
        __syncthreads();
#pragma unroll
        for (int r = 0; r < 32; r += 8)
            dst[(size_t)(n0 + ty + r) * K + (k0 + tx)] = f2b(tile[tx][ty + r]);
    } else if (id < 12800) {
        const int i = (id - 12288) * 256 + tid;            // 131072
        relbPad[i] = (i < 65536) ? f2b(rel[i]) : (unsigned short)0;
    } else if (id < 13824) {
        const int i = (id - 12800) * 256 + tid;            // 262144
        const int b = i >> 16, rem = i & 65535, d = rem >> 6, r = rem & 63;
        Bwv[(size_t)b * BT_WV + (size_t)d * LDB_WV + 1024 + r] = f2b(rel[r * 1024 + d]);
    } else if (id < 13836) {
        const int i = (id - 13824) * 256 + tid;            // 3072
        bqkv[i] = (i < 1024) ? bq[i] : 0.0f;
    } else if (id < 17932) {
        // LN0 row
        const int row = id - 13836, t = tid;
        const size_t base = (size_t)row * 1024 + t * 4;
        float4 xv = *(const float4*)(hidden + base);
        float x0 = xv.x, x1 = xv.y, x2 = xv.z, x3 = xv.w;
        float s = x0 + x1 + x2 + x3;
#pragma unroll
        for (int o = 32; o > 0; o >>= 1) s += __shfl_down(s, o);
        if ((t & 63) == 0) sb1[t >> 6] = s;
        __syncthreads();
        const float mu = (sb1[0] + sb1[1] + sb1[2] + sb1[3]) * (1.0f / 1024.0f);
        const float d0 = x0 - mu, d1 = x1 - mu, d2 = x2 - mu, d3 = x3 - mu;
        float s2 = d0 * d0 + d1 * d1 + d2 * d2 + d3 * d3;
#pragma unroll
        for (int o = 32; o > 0; o >>= 1) s2 += __shfl_down(s2, o);
        if ((t & 63) == 0) sb2[t >> 6] = s2;
        __syncthreads();
        const float var = (sb2[0] + sb2[1] + sb2[2] + sb2[3]) * (1.0f / 1024.0f);
        const float rstd = rsqrtf(var + 1e-6f);
        const float4 gv = *(const float4*)(ln0_g + t * 4);
        const float4 bv = *(const float4*)(ln0_b + t * 4);
        const float y0 = d0 * rstd * gv.x + bv.x;
        const float y1 = d1 * rstd * gv.y + bv.y;
        const float y2 = d2 * rstd * gv.z + bv.z;
        const float y3 = d3 * rstd * gv.w + bv.w;
        float4 o; o.x = y0; o.y = y1; o.z = y2; o.w = y3;
        *(float4*)(Xn_f32 + base) = o;
        ushort4 ob; ob.x = f2b(y0); ob.y = f2b(y1); ob.z = f2b(y2); ob.w = f2b(y3);
        *(ushort4*)(Xn_b16 + base) = ob;
    } else {
        // zero A|G: 1088 blocks x 4096 floats
        const size_t base = (size_t)(id - 17932) * 4096 + tid * 4;
        const float4 z4 = make_float4(0.f, 0.f, 0.f, 0.f);
#pragma unroll
        for (int j = 0; j < 4; j++)
            *(float4*)(zeroReg + base + j * 1024) = z4;
    }
}

// XCD-aware tile swizzle: XCD = linear_id % 8. Group all tile_n of a tile_m on one XCD.
__device__ inline void tile_swizzle(int id, int ntn, int& tm, int& tn) {
    tm = ((id & 7) + ((id >> 3) / ntn) * 8) * 128;
    tn = ((id >> 3) % ntn) * 128;
}

// ---------------- GEMM: C[M,N] = A[M,K](bf16, lda) * Bt[N,K](bf16, ldb)^T + bias ----------------
// BK=64 (32KB LDS): 32 MFMA per barrier-pair. XOR swizzle slot = chunk ^ (row&7) -> 0 conflicts.
template<bool OUT_BF16, bool RELU>
__global__ __launch_bounds__(256, 4)
void gemm_bf16(const unsigned short* __restrict__ A, int lda,
               const unsigned short* __restrict__ Bt, int ldb, size_t bt_batch,
               const float* __restrict__ bias,
               float* __restrict__ Cf, unsigned short* __restrict__ Cb,
               int N, int K, int ntn) {
    __shared__ unsigned short lA[128 * 64];
    __shared__ unsigned short lB[128 * 64];
    int tile_m, tile_n;
    tile_swizzle(blockIdx.x, ntn, tile_m, tile_n);
    const int t = threadIdx.x;
    const int wave = t >> 6, lane = t & 63;
    const int wm = (wave >> 1) * 64, wn = (wave & 1) * 64;
    const int quad = lane >> 4, l16 = lane & 15;

    const int srow = lane >> 3;
    const int schunk = ((lane & 7) ^ srow) * 8;
    const unsigned short* gA = A + (size_t)(tile_m + wave * 32 + srow) * lda + schunk;
    const unsigned short* gB = Bt + (size_t)(tile_m >> 10) * bt_batch
                                  + (size_t)(tile_n + wave * 32 + srow) * ldb + schunk;

    f32x4 acc[4][4];
#pragma unroll
    for (int i = 0; i < 4; i++)
#pragma unroll
        for (int j = 0; j < 4; j++) acc[i][j] = (f32x4)0.0f;

    for (int k0 = 0; k0 < K; k0 += 64) {
        __syncthreads();
#pragma unroll
        for (int r = 0; r < 4; ++r) {
            __builtin_amdgcn_global_load_lds(GLOBAL_CAST(gA + (size_t)r * 8 * lda),
                                             LDS_CAST(&lA[(wave * 32 + r * 8) * 64]), 16, 0, 0);
            __builtin_amdgcn_global_load_lds(GLOBAL_CAST(gB + (size_t)r * 8 * ldb),
                                             LDS_CAST(&lB[(wave * 32 + r * 8) * 64]), 16, 0, 0);
        }
        gA += 64; gB += 64;
        __builtin_amdgcn_s_waitcnt(0);
        __syncthreads();

#pragma unroll
        for (int kk = 0; kk < 2; ++kk) {
            const int cb = kk * 4 + quad;
            bf16x8 af[4], bf[4];
#pragma unroll
            for (int i = 0; i < 4; i++) {
                const int ra = wm + i * 16 + l16;
                af[i] = *(const bf16x8*)&lA[ra * 64 + ((cb ^ (ra & 7)) * 8)];
                const int rb = wn + i * 16 + l16;
                bf[i] = *(const bf16x8*)&lB[rb * 64 + ((cb ^ (rb & 7)) * 8)];
            }
#pragma unroll
            for (int mi = 0; mi < 4; mi++)
#pragma unroll
                for (int ni = 0; ni < 4; ni++)
                    acc[mi][ni] = __builtin_amdgcn_mfma_f32_16x16x32_bf16(af[mi], bf[ni], acc[mi][ni], 0, 0, 0);
        }
    }

#pragma unroll
    for (int mi = 0; mi < 4; mi++) {
#pragma unroll
        for (int ni = 0; ni < 4; ni++) {
            const int col = tile_n + wn + ni * 16 + l16;
            const float bv = bias[col];
#pragma unroll
            for (int r = 0; r < 4; r++) {
                const int row = tile_m + wm + mi * 16 + quad * 4 + r;
                float v = acc[mi][ni][r] + bv;
                if (RELU) v = fmaxf(v, 0.0f);
                if (OUT_BF16) Cb[(size_t)row * N + col] = f2b(v);
                else          Cf[(size_t)row * N + col] = v;
            }
        }
    }
}

// split-K: blockIdx.z = z over K-range [z*Kc,(z+1)*Kc); bf16 partial at Pbase + z*pstride.
__global__ __launch_bounds__(256, 4)
void gemm_bf16_splitk(const unsigned short* __restrict__ A, int lda,
                      const unsigned short* __restrict__ Bt, int ldb, size_t bt_batch,
                      const float* __restrict__ bias,
                      unsigned short* __restrict__ Pbase, size_t pstride,
                      int N, int Kc, int ntn) {
    __shared__ unsigned short lA[128 * 64];
    __shared__ unsigned short lB[128 * 64];
    int tile_m, tile_n;
    tile_swizzle(blockIdx.x, ntn, tile_m, tile_n);
    const int z = blockIdx.z;
    const int kofs = z * Kc;
    const int t = threadIdx.x;
    const int wave = t >> 6, lane = t & 63;
    const int wm = (wave >> 1) * 64, wn = (wave & 1) * 64;
    const int quad = lane >> 4, l16 = lane & 15;

    const int srow = lane >> 3;
    const int schunk = ((lane & 7) ^ srow) * 8;
    const unsigned short* gA = A + (size_t)(tile_m + wave * 32 + srow) * lda + kofs + schunk;
    const unsigned short* gB = Bt + (size_t)(tile_m >> 10) * bt_batch
                                  + (size_t)(tile_n + wave * 32 + srow) * ldb + kofs + schunk;

    f32x4 acc[4][4];
#pragma unroll
    for (int i = 0; i < 4; i++)
#pragma unroll
        for (int j = 0; j < 4; j++) acc[i][j] = (f32x4)0.0f;

    for (int k0 = 0; k0 < Kc; k0 += 64) {
        __syncthreads();
#pragma unroll
        for (int r = 0; r < 4; ++r) {
            __builtin_amdgcn_global_load_lds(GLOBAL_CAST(gA + (size_t)r * 8 * lda),
                                             LDS_CAST(&lA[(wave * 32 + r * 8) * 64]), 16, 0, 0);
            __builtin_amdgcn_global_load_lds(GLOBAL_CAST(gB + (size_t)r * 8 * ldb),
                                             LDS_CAST(&lB[(wave * 32 + r * 8) * 64]), 16, 0, 0);
        }
        gA += 64; gB += 64;
        __builtin_amdgcn_s_waitcnt(0);
        __syncthreads();

#pragma unroll
        for (int kk = 0; kk < 2; ++kk) {
            const int cb = kk * 4 + quad;
            bf16x8 af[4], bf[4];
#pragma unroll
            for (int i = 0; i < 4; i++) {
                const int ra = wm + i * 16 + l16;
                af[i] = *(const bf16x8*)&lA[ra * 64 + ((cb ^ (ra & 7)) * 8)];
                const int rb = wn + i * 16 + l16;
                bf[i] = *(const bf16x8*)&lB[rb * 64 + ((cb ^ (rb & 7)) * 8)];
            }
#pragma unroll
            for (int mi = 0; mi < 4; mi++)
#pragma unroll
                for (int ni = 0; ni < 4; ni++)
                    acc[mi][ni] = __builtin_amdgcn_mfma_f32_16x16x32_bf16(af[mi], bf[ni], acc[mi][ni], 0, 0, 0);
        }
    }

    unsigned short* P = Pbase + (size_t)z * pstride;
#pragma unroll
    for (int mi = 0; mi < 4; mi++) {
#pragma unroll
        for (int ni = 0; ni < 4; ni++) {
            const int col = tile_n + wn + ni * 16 + l16;
            const float bv = (z == 0) ? bias[col] : 0.0f;
#pragma unroll
            for (int r = 0; r < 4; r++) {
                const int row = tile_m + wm + mi * 16 + quad * 4 + r;
                P[(size_t)row * N + col] = f2b(acc[mi][ni][r] + bv);
            }
        }
    }
}

// ---------------- S_ext GEMM + V^T transpose, merged (both depend only on QKV) ----------------
// flat grid 4672: [0,576) sext (bx=id%72, b=(id/72)%4, z=id/288); [576,4672) V^T tiles.
// sext: S_ext = [K(1024);relbPad(128)] @ Q^T per batch, split-K=2, bf16 partials.
//       P[z][b][1152][1024]: rows 0-1023 = S[src,dst], rows 1024.. = T^T[r,dst].
// tv:   Bwv[b][d][s] = QKV[(b<<10)+s, 2048+d]
__global__ __launch_bounds__(256, 4)
void sext_tv(const unsigned short* __restrict__ QKV,
             const unsigned short* __restrict__ relPad,
             unsigned short* __restrict__ Pbase,
             unsigned short* __restrict__ Bwv, int Kc) {
    __shared__ unsigned short lA[128 * 64];
    __shared__ unsigned short lB[128 * 64];
    const int id = blockIdx.x, t = threadIdx.x;

    if (id >= 576) {   // ---- V^T tile ----
        unsigned short (*tile)[33] = (unsigned short (*)[33])lA;
        const int t2 = id - 576;
        const int b = t2 >> 10;
        const int d0 = (t2 & 31) * 32, s0 = ((t2 >> 5) & 31) * 32;
        const int tx = t & 31, ty = t >> 5;  // 32 x 8
#pragma unroll
        for (int r = 0; r < 32; r += 8)
            tile[ty + r][tx] = QKV[(size_t)((b << 10) + s0 + ty + r) * 3072 + 2048 + d0 + tx];
        __syncthreads();
#pragma unroll
        for (int r = 0; r < 32; r += 8)
            Bwv[(size_t)b * BT_WV + (size_t)(d0 + ty + r) * LDB_WV + s0 + tx] = tile[tx][ty + r];
        return;
    }

    // ---- sext ----
    const int bx = id % 72, b = (id / 72) & 3, z = id / 288;
    const int tile_m = (bx >> 3) * 128;
    const int tile_n = (bx & 7) * 128;
    const int kofs = z * Kc;
    const int wave = t >> 6, lane = t & 63;
    const int wm = (wave >> 1) * 64, wn = (wave & 1) * 64;
    const int quad = lane >> 4, l16 = lane & 15;

    const int srow = lane >> 3;
    const int schunk = ((lane & 7) ^ srow) * 8;
    const int arow = tile_m + wave * 32 + srow;
    const unsigned short* gA;
    size_t lda;
    if (tile_m < 1024) {   // K rows
        gA = QKV + (size_t)b * BT_QKV + (size_t)arow * 3072 + 1024 + kofs + schunk;
        lda = 3072;
    } else {               // relPad rows (shared across batches)
        gA = relPad + (size_t)(arow - 1024) * 1024 + kofs + schunk;
        lda = 1024;
    }
    const unsigned short* gB = QKV + (size_t)b * BT_QKV
                                   + (size_t)(tile_n + wave * 32 + srow) * 3072 + kofs + schunk;

    f32x4 acc[4][4];
#pragma unroll
    for (int i = 0; i < 4; i++)
#pragma unroll
        for (int j = 0; j < 4; j++) acc[i][j] = (f32x4)0.0f;

    for (int k0 = 0; k0 < Kc; k0 += 64) {
        __syncthreads();
#pragma unroll
        for (int r = 0; r < 4; ++r) {
            __builtin_amdgcn_global_load_lds(GLOBAL_CAST(gA + (size_t)r * 8 * lda),
                                             LDS_CAST(&lA[(wave * 32 + r * 8) * 64]), 16, 0, 0);
            __builtin_amdgcn_global_load_lds(GLOBAL_CAST(gB + (size_t)r * 8 * 3072),
                                             LDS_CAST(&lB[(wave * 32 + r * 8) * 64]), 16, 0, 0);
        }
        gA += 64; gB += 64;
        __builtin_amdgcn_s_waitcnt(0);
        __syncthreads();

#pragma unroll
        for (int kk = 0; kk < 2; ++kk) {
            const int cb = kk * 4 + quad;
            bf16x8 af[4], bf[4];
#pragma unroll
            for (int i = 0; i < 4; i++) {
                const int ra = wm + i * 16 + l16;
                af[i] = *(const bf16x8*)&lA[ra * 64 + ((cb ^ (ra & 7)) * 8)];
                const int rb = wn + i * 16 + l16;
                bf[i] = *(const bf16x8*)&lB[rb * 64 + ((cb ^ (rb & 7)) * 8)];
            }
#pragma unroll
            for (int mi = 0; mi < 4; mi++)
#pragma unroll
                for (int ni = 0; ni < 4; ni++)
                    acc[mi][ni] = __builtin_amdgcn_mfma_f32_16x16x32_bf16(af[mi], bf[ni], acc[mi][ni], 0, 0, 0);
        }
    }

    unsigned short* P = Pbase + ((size_t)z * B_SZ + b) * (SEXT_M * 1024);
#pragma unroll
    for (int mi = 0; mi < 4; mi++) {
#pragma unroll
        for (int ni = 0; ni < 4; ni++) {
            const int col = tile_n + wn + ni * 16 + l16;
#pragma unroll
            for (int r = 0; r < 4; r++) {
                const int row = tile_m + wm + mi * 16 + quad * 4 + r;
                P[(size_t)row * 1024 + col] = f2b(acc[mi][ni][r]);
            }
        }
    }
}

// ---------------- LayerNorm family ----------------
// partials are bf16 (split-K outputs). MODE 1: LN(X_f32 + sum NR partials) -> ob16.
// MODE 2: LN(X_bf16 + sum NR partials); fout = hidden + elu(y).
template<int MODE, int NR>
__global__ void ln_kernel(const float* __restrict__ X, const unsigned short* __restrict__ Xb,
                          const unsigned short* __restrict__ Rbase, size_t rstride,
                          const float* __restrict__ g, const float* __restrict__ be,
                          unsigned short* __restrict__ ob16,
                          const float* __restrict__ hidden, float* __restrict__ fout) {
    __shared__ float sb1[4], sb2[4];
    const int row = blockIdx.x, t = threadIdx.x;
    const size_t base = (size_t)row * 1024 + t * 4;

    float x0, x1, x2, x3;
    if (MODE == 2) {
        ushort4 xv = *(const ushort4*)(Xb + base);
        x0 = b2f(xv.x); x1 = b2f(xv.y); x2 = b2f(xv.z); x3 = b2f(xv.w);
    } else {
        float4 xv = *(const float4*)(X + base);
        x0 = xv.x; x1 = xv.y; x2 = xv.z; x3 = xv.w;
    }
#pragma unroll
    for (int r = 0; r < NR; r++) {
        ushort4 rv = *(const ushort4*)(Rbase + r * rstride + base);
        x0 += b2f(rv.x); x1 += b2f(rv.y); x2 += b2f(rv.z); x3 += b2f(rv.w);
    }
    float s = x0 + x1 + x2 + x3;
#pragma unroll
    for (int o = 32; o > 0; o >>= 1) s += __shfl_down(s, o);
    if ((t & 63) == 0) sb1[t >> 6] = s;
    __syncthreads();
    const float mu = (sb1[0] + sb1[1] + sb1[2] + sb1[3]) * (1.0f / 1024.0f);

    const float d0 = x0 - mu, d1 = x1 - mu, d2 = x2 - mu, d3 = x3 - mu;
    float s2 = d0 * d0 + d1 * d1 + d2 * d2 + d3 * d3;
#pragma unroll
    for (int o = 32; o > 0; o >>= 1) s2 += __shfl_down(s2, o);
    if ((t & 63) == 0) sb2[t >> 6] = s2;
    __syncthreads();
    const float var = (sb2[0] + sb2[1] + sb2[2] + sb2[3]) * (1.0f / 1024.0f);
    const float rstd = rsqrtf(var + 1e-6f);

    const float4 gv = *(const float4*)(g + t * 4);
    const float4 bv = *(const float4*)(be + t * 4);
    const float y0 = d0 * rstd * gv.x + bv.x;
    const float y1 = d1 * rstd * gv.y + bv.y;
    const float y2 = d2 * rstd * gv.z + bv.z;
    const float y3 = d3 * rstd * gv.w + bv.w;

    if (MODE == 1) {
        ushort4 ob; ob.x = f2b(y0); ob.y = f2b(y1); ob.z = f2b(y2); ob.w = f2b(y3);
        *(ushort4*)(ob16 + base) = ob;
    } else {
        const float4 hv = *(const float4*)(hidden + base);
        const float e0 = y0 > 0.0f ? y0 : expm1f(y0);
        const float e1 = y1 > 0.0f ? y1 : expm1f(y1);
        const float e2 = y2 > 0.0f ? y2 : expm1f(y2);
        const float e3 = y3 > 0.0f ? y3 : expm1f(y3);
        float4 o; o.x = hv.x + e0; o.y = hv.y + e1; o.z = hv.z + e2; o.w = hv.w + e3;
        *(float4*)(fout + base) = o;
    }
}

// ---------------- dense edge phase ----------------
// per edge: sc = exp(clip((S[src,dst] + T^T[r,dst])/32)); A[dst,src]+=sc; G[dst,r]+=sc
__global__ void edge_scatter(const unsigned short* __restrict__ S,
                             const int* __restrict__ src, const int* __restrict__ dst,
                             const int* __restrict__ rel,
                             float* __restrict__ A, float* __restrict__ G) {
    const size_t ZSTR = (size_t)B_SZ * SEXT_M * 1024;
    const int gg = blockIdx.x * 256 + threadIdx.x;   // B*E = 131072
    const int b = gg >> 15;
    const int s = src[gg], d = dst[gg], r = rel[gg];
    const size_t sbase = ((size_t)b * SEXT_M + s) * 1024 + d;
    const size_t tbase = ((size_t)b * SEXT_M + 1024 + r) * 1024 + d;
    const float sval = b2f(S[sbase]) + b2f(S[sbase + ZSTR]);
    const float tval = b2f(S[tbase]) + b2f(S[tbase + ZSTR]);
    float sc = (sval + tval) * (1.0f / 32.0f);
    sc = expf(fminf(fmaxf(sc, -10.0f), 10.0f));
    atomicAdd(&A[((size_t)((b << 10) + d) << 10) + s], sc);
    atomicAdd(&G[((size_t)((b << 10) + d) << 6) + r], sc);
}

// per node: inv = 1/sum_r G[row,r]; Awv[row] = bf16([A*inv | G*inv])  (1088-wide)
__global__ void normalize(const float* __restrict__ A, const float* __restrict__ G,
                          unsigned short* __restrict__ Awv) {
    __shared__ float sInv;
    const int row = blockIdx.x, t = threadIdx.x;
    float v = 0.0f;
    if (t < 64) {
        v = G[(size_t)row * 64 + t];
        float s = v;
#pragma unroll
        for (int o = 1; o < 64; o <<= 1) s += __shfl_xor(s, o);
        if (t == 0) sInv = 1.0f / s;
    }
    __syncthreads();
    const float inv = sInv;
    const size_t obase = (size_t)row * LDB_WV;
    const float4 a = *(const float4*)(A + (size_t)row * 1024 + t * 4);
    ushort4 o;
    o.x = f2b(a.x * inv); o.y = f2b(a.y * inv); o.z = f2b(a.z * inv); o.w = f2b(a.w * inv);
    *(ushort4*)(Awv + obase + t * 4) = o;
    if (t < 16) {
        const float4 gq = *(const float4*)(G + (size_t)row * 64 + t * 4);
        ushort4 og;
        og.x = f2b(gq.x * inv); og.y = f2b(gq.y * inv);
        og.z = f2b(gq.z * inv); og.w = f2b(gq.w * inv);
        *(ushort4*)(Awv + obase + 1024 + t * 4) = og;
    }
}

// ---------------- launch ----------------
extern "C" void kernel_launch(void* const* d_in, const int* in_sizes, int n_in,
                              void* d_out, int out_size, void* d_ws, size_t ws_size,
                              hipStream_t stream) {
    const float* hidden  = (const float*)d_in[0];
    const float* rel_tbl = (const float*)d_in[1];
    const float* Wq = (const float*)d_in[2];
    const float* bq = (const float*)d_in[3];
    const float* Wk = (const float*)d_in[4];
    const float* Wv = (const float*)d_in[5];
    const float* Wo = (const float*)d_in[6];
    const float* bo = (const float*)d_in[7];
    const float* ln0_g = (const float*)d_in[8];
    const float* ln0_b = (const float*)d_in[9];
    const float* ln1_g = (const float*)d_in[10];
    const float* ln1_b = (const float*)d_in[11];
    const float* W1 = (const float*)d_in[12];
    const float* b1 = (const float*)d_in[13];
    const float* W2 = (const float*)d_in[14];
    const float* b2 = (const float*)d_in[15];
    const float* ln2_g = (const float*)d_in[16];
    const float* ln2_b = (const float*)d_in[17];
    const int* esrc = (const int*)d_in[18];
    const int* edst = (const int*)d_in[19];
    const int* erel = (const int*)d_in[20];
    float* out = (float*)d_out;

    // ws lifetime map (peak 121MB) — identical overlay to R7.
    char* ws = (char*)d_ws;
    const size_t MB = 1024 * 1024;
    float*          Xn_f32  = (float*)(ws + 0);
    unsigned short* Xn_b16  = (unsigned short*)(ws + 16 * MB);
    unsigned short* H1      = (unsigned short*)(ws + 0);
    unsigned short* Wqkv_t  = (unsigned short*)(ws + 24 * MB);
    unsigned short* Wo_t    = (unsigned short*)(ws + 30 * MB);
    unsigned short* W1_t    = (unsigned short*)(ws + 32 * MB);
    unsigned short* W2_t    = (unsigned short*)(ws + 40 * MB);
    unsigned short* relbPad = (unsigned short*)(ws + 48 * MB);
    float*          bqkv    = (float*)(ws + 48 * MB + 512 * 1024);
    const float*    zbias   = bqkv + 1024;  // 2048 zeros
    unsigned short* QKV     = (unsigned short*)(ws + 49 * MB);
    unsigned short* Awv     = (unsigned short*)(ws + 49 * MB);
    unsigned short* Obf     = (unsigned short*)(ws + 58 * MB);
    unsigned short* Qw2H    = (unsigned short*)(ws + 49 * MB);
    unsigned short* PwoH    = (unsigned short*)(ws + 66 * MB);
    unsigned short* SxH     = (unsigned short*)(ws + 73 * MB);
    unsigned short* Bwv     = (unsigned short*)(ws + 92 * MB);
    float*          Amat    = (float*)(ws + 101 * MB);
    float*          Gmat    = (float*)(ws + 117 * MB);
    unsigned short* Out_b16 = (unsigned short*)(ws + 113 * MB);

    const size_t PSTRIDE_H = 4u * 1024 * 1024;   // 8MB bf16 partial, in ushorts
    const dim3 blk(256);

    // ---- fused prep (weights + rel + bias + LN0 + zero A|G) ----
    prep_all<<<19020, blk, 0, stream>>>(Wq, Wk, Wv, Wo, W1, W2, rel_tbl, bq,
                                        hidden, ln0_g, ln0_b,
                                        Wqkv_t, Wo_t, W1_t, W2_t, relbPad, Bwv, bqkv,
                                        Xn_f32, Xn_b16, Amat);
    // ---- QKV GEMM ----
    gemm_bf16<true, false><<<dim3(24 * 32), blk, 0, stream>>>(
        Xn_b16, 1024, Wqkv_t, 1024, 0, bqkv, nullptr, QKV, 3072, 1024, 24);
    // ---- S_ext GEMM + V^T (merged; both consume QKV only) ----
    sext_tv<<<4672, blk, 0, stream>>>(QKV, relbPad, SxH, Bwv, 512);
    // ---- scatter scores into pre-zeroed A,G ----
    edge_scatter<<<512, blk, 0, stream>>>(SxH, esrc, edst, erel, Amat, Gmat);
    // ---- normalize -> Awv [4096,1088] ----
    normalize<<<M_ROWS, blk, 0, stream>>>(Amat, Gmat, Awv);
    // ---- wv: Obf = Awv @ Bwv^T  (K=1088, batched B) ----
    gemm_bf16<true, false><<<dim3(8 * 32), blk, 0, stream>>>(
        Awv, LDB_WV, Bwv, LDB_WV, BT_WV, zbias, nullptr, Obf, 1024, LDB_WV, 8);
    // ---- o @ Wo + bo (split-K=2, bf16 partials) ----
    gemm_bf16_splitk<<<dim3(8 * 32, 1, 2), blk, 0, stream>>>(
        Obf, 1024, Wo_t, 1024, 0, bo, PwoH, PSTRIDE_H, 1024, 512, 8);
    // ---- LN1 ----
    ln_kernel<1, 2><<<M_ROWS, blk, 0, stream>>>(Xn_f32, nullptr, PwoH, PSTRIDE_H, ln1_g, ln1_b,
                                                Out_b16, nullptr, nullptr);
    // ---- FFN1 ----
    gemm_bf16<true, true><<<dim3(32 * 32), blk, 0, stream>>>(
        Out_b16, 1024, W1_t, 1024, 0, b1, nullptr, H1, 4096, 1024, 32);
    // ---- W2 (split-K=4, bf16 partials) ----
    gemm_bf16_splitk<<<dim3(8 * 32, 1, 4), blk, 0, stream>>>(
        H1, 4096, W2_t, 4096, 0, b2, Qw2H, PSTRIDE_H, 1024, 1024, 8);
    // ---- LN2 + elu + residual ----
    ln_kernel<2, 4><<<M_ROWS, blk, 0, stream>>>(nullptr, Out_b16, Qw2H, PSTRIDE_H, ln2_g, ln2_b,
                                                nullptr, hidden, out);
    (void)in_sizes; (void)n_in; (void)out_size; (void)ws_size;
}

// Round 10
// 368.320 us; speedup vs baseline: 1.3388x; 1.0025x over previous
//
#include <hip/hip_runtime.h>
#include <hip/hip_bf16.h>

#define B_SZ 4
#define L_SEQ 1024
#define D_MODEL 1024
#define DF_FF 4096
#define E_PER_B 32768
#define R_REL 64
#define M_ROWS (B_SZ * L_SEQ)   // 4096

typedef __attribute__((ext_vector_type(8))) short bf16x8;
typedef __attribute__((ext_vector_type(16))) float f32x16;

__device__ inline float b2f(unsigned short u) {
    union { unsigned int i; float f; } x; x.i = ((unsigned int)u) << 16; return x.f;
}
__device__ inline unsigned short f2b(float f) {
    union { float f; unsigned int u; } x; x.f = f;
    unsigned int r = x.u + 0x7FFFu + ((x.u >> 16) & 1u);
    return (unsigned short)(r >> 16);
}

#define GLOBAL_CAST(p) ((const __attribute__((address_space(1))) void*)(p))
#define LDS_CAST(p)    ((__attribute__((address_space(3))) void*)(p))

#define LDB_WV 1088                      // [V | rel] combined K width (17*64)
#define BT_WV  (1024u * 1088u)           // per-batch Bwv stride (elements)
#define BT_QKV (1024u * 3072u)           // per-batch QKV stride
#define SEXT_M 1152                      // S_ext rows per batch: 1024 src + 128 relPad

// ---------------- fused prep: weights + rel + bias + LN0 + zero(A|G) ----------------
__global__ void prep_all(const float* __restrict__ Wq, const float* __restrict__ Wk,
                         const float* __restrict__ Wv, const float* __restrict__ Wo,
                         const float* __restrict__ W1, const float* __restrict__ W2,
                         const float* __restrict__ rel, const float* __restrict__ bq,
                         const float* __restrict__ hidden,
                         const float* __restrict__ ln0_g, const float* __restrict__ ln0_b,
                         unsigned short* __restrict__ Wqkv_t, unsigned short* __restrict__ Wo_t,
                         unsigned short* __restrict__ W1_t, unsigned short* __restrict__ W2_t,
                         unsigned short* __restrict__ relbPad, unsigned short* __restrict__ Bwv,
                         float* __restrict__ bqkv,
                         float* __restrict__ Xn_f32, unsigned short* __restrict__ Xn_b16,
                         float* __restrict__ zeroReg) {
    __shared__ float tile[32][33];
    __shared__ float sb1[4], sb2[4];
    const int id = blockIdx.x, tid = threadIdx.x;
    if (id < 12288) {
        const float* src; unsigned short* dst; int K, N, x, y;
        if (id < 4096) {
            const int seg = id >> 10, t = id & 1023;
            K = 1024; N = 1024; x = t & 31; y = t >> 5;
            src = (seg == 0) ? Wq : (seg == 1) ? Wk : (seg == 2) ? Wv : Wo;
            dst = (seg == 3) ? Wo_t : (Wqkv_t + (size_t)seg * 1048576);
        } else if (id < 8192) {
            const int t = id - 4096; K = 1024; N = 4096; x = t & 127; y = t >> 7;
            src = W1; dst = W1_t;
        } else {
            const int t = id - 8192; K = 4096; N = 1024; x = t & 31; y = t >> 5;
            src = W2; dst = W2_t;
        }
        const int n0 = x * 32, k0 = y * 32, tx = tid & 31, ty = tid >> 5;
#pragma unroll
        for (int r = 0; r < 32; r += 8)
            tile[ty + r][tx] = src[(size_t)(k0 + ty + r) * N + (n0 + tx)];
        __syncthreads();
#pragma unroll
        for (int r = 0; r < 32; r += 8)
            dst[(size_t)(n0 + ty + r) * K + (k0 + tx)] = f2b(tile[tx][ty + r]);
    } else if (id < 12800) {
        const int i = (id - 12288) * 256 + tid;            // 131072
        relbPad[i] = (i < 65536) ? f2b(rel[i]) : (unsigned short)0;
    } else if (id < 13824) {
        const int i = (id - 12800) * 256 + tid;            // 262144
        const int b = i >> 16, rem = i & 65535, d = rem >> 6, r = rem & 63;
        Bwv[(size_t)b * BT_WV + (size_t)d * LDB_WV + 1024 + r] = f2b(rel[r * 1024 + d]);
    } else if (id < 13836) {
        const int i = (id - 13824) * 256 + tid;            // 3072
        bqkv[i] = (i < 1024) ? bq[i] : 0.0f;
    } else if (id < 17932) {
        // LN0 row
        const int row = id - 13836, t = tid;
        const size_t base = (size_t)row * 1024 + t * 4;
        float4 xv = *(const float4*)(hidden + base);
        float x0 = xv.x, x1 = xv.y, x2 = xv.z, x3 = xv.w;
        float s = x0 + x1 + x2 + x3;
#pragma unroll
        for (int o = 32; o > 0; o >>= 1) s += __shfl_down(s, o);
        if ((t & 63) == 0) sb1[t >> 6] = s;
        __syncthreads();
        const float mu = (sb1[0] + sb1[1] + sb1[2] + sb1[3]) * (1.0f / 1024.0f);
        const float d0 = x0 - mu, d1 = x1 - mu, d2 = x2 - mu, d3 = x3 - mu;
        float s2 = d0 * d0 + d1 * d1 + d2 * d2 + d3 * d3;
#pragma unroll
        for (int o = 32; o > 0; o >>= 1) s2 += __shfl_down(s2, o);
        if ((t & 63) == 0) sb2[t >> 6] = s2;
        __syncthreads();
        const float var = (sb2[0] + sb2[1] + sb2[2] + sb2[3]) * (1.0f / 1024.0f);
        const float rstd = rsqrtf(var + 1e-6f);
        const float4 gv = *(const float4*)(ln0_g + t * 4);
        const float4 bv = *(const float4*)(ln0_b + t * 4);
        const float y0 = d0 * rstd * gv.x + bv.x;
        const float y1 = d1 * rstd * gv.y + bv.y;
        const float y2 = d2 * rstd * gv.z + bv.z;
        const float y3 = d3 * rstd * gv.w + bv.w;
        float4 o; o.x = y0; o.y = y1; o.z = y2; o.w = y3;
        *(float4*)(Xn_f32 + base) = o;
        ushort4 ob; ob.x = f2b(y0); ob.y = f2b(y1); ob.z = f2b(y2); ob.w = f2b(y3);
        *(ushort4*)(Xn_b16 + base) = ob;
    } else {
        // zero A|G: 1088 blocks x 4096 floats
        const size_t base = (size_t)(id - 17932) * 4096 + tid * 4;
        const float4 z4 = make_float4(0.f, 0.f, 0.f, 0.f);
#pragma unroll
        for (int j = 0; j < 4; j++)
            *(float4*)(zeroReg + base + j * 1024) = z4;
    }
}

// XCD-aware tile swizzle: XCD = linear_id % 8. Group all tile_n of a tile_m on one XCD.
__device__ inline void tile_swizzle(int id, int ntn, int& tm, int& tn) {
    tm = ((id & 7) + ((id >> 3) / ntn) * 8) * 128;
    tn = ((id >> 3) % ntn) * 128;
}

// ---------------- GEMM core: 32x32x16 MFMA ----------------
// Per wave 64x64 = 2x2 tiles of 32x32; K-step 16; BK=64 -> 16 MFMA + 16 ds_read_b128
// per barrier-pair (was 32+16 with 16x16x32 -> ~18% less MFMA pipe time, half the VALU).
// A/B frag: m(or n)=lane&31, k=(lane>>5)*8+j (K-doubled extension of verified 16x16x32).
// C/D [HW-verified m74/m101]: col=lane&31, row=(reg&3)+8*(reg>>2)+4*(lane>>5).
// LDS XOR swizzle: slot = chunk ^ (row&7); read aliasing is 2-way = free.

// GEMM: C[M,N] = A[M,K](bf16, lda) * Bt[N,K](bf16, ldb)^T + bias
template<bool OUT_BF16, bool RELU>
__global__ __launch_bounds__(256, 4)
void gemm_bf16(const unsigned short* __restrict__ A, int lda,
               const unsigned short* __restrict__ Bt, int ldb, size_t bt_batch,
               const float* __restrict__ bias,
               float* __restrict__ Cf, unsigned short* __restrict__ Cb,
               int N, int K, int ntn) {
    __shared__ unsigned short lA[128 * 64];
    __shared__ unsigned short lB[128 * 64];
    int tile_m, tile_n;
    tile_swizzle(blockIdx.x, ntn, tile_m, tile_n);
    const int t = threadIdx.x;
    const int wave = t >> 6, lane = t & 63;
    const int wm = (wave >> 1) * 64, wn = (wave & 1) * 64;
    const int l31 = lane & 31, half = lane >> 5;

    const int srow = lane >> 3;
    const int schunk = ((lane & 7) ^ srow) * 8;
    const unsigned short* gA = A + (size_t)(tile_m + wave * 32 + srow) * lda + schunk;
    const unsigned short* gB = Bt + (size_t)(tile_m >> 10) * bt_batch
                                  + (size_t)(tile_n + wave * 32 + srow) * ldb + schunk;

    f32x16 acc[2][2];
#pragma unroll
    for (int i = 0; i < 2; i++)
#pragma unroll
        for (int j = 0; j < 2; j++) acc[i][j] = (f32x16)0.0f;

    for (int k0 = 0; k0 < K; k0 += 64) {
        __syncthreads();
#pragma unroll
        for (int r = 0; r < 4; ++r) {
            __builtin_amdgcn_global_load_lds(GLOBAL_CAST(gA + (size_t)r * 8 * lda),
                                             LDS_CAST(&lA[(wave * 32 + r * 8) * 64]), 16, 0, 0);
            __builtin_amdgcn_global_load_lds(GLOBAL_CAST(gB + (size_t)r * 8 * ldb),
                                             LDS_CAST(&lB[(wave * 32 + r * 8) * 64]), 16, 0, 0);
        }
        gA += 64; gB += 64;
        __builtin_amdgcn_s_waitcnt(0);
        __syncthreads();

#pragma unroll
        for (int ks = 0; ks < 4; ++ks) {
            const int cb = ks * 2 + half;
            bf16x8 af[2], bf[2];
#pragma unroll
            for (int i = 0; i < 2; i++) {
                const int ra = wm + i * 32 + l31;
                af[i] = *(const bf16x8*)&lA[ra * 64 + ((cb ^ (ra & 7)) * 8)];
                const int rb = wn + i * 32 + l31;
                bf[i] = *(const bf16x8*)&lB[rb * 64 + ((cb ^ (rb & 7)) * 8)];
            }
#pragma unroll
            for (int mi = 0; mi < 2; mi++)
#pragma unroll
                for (int ni = 0; ni < 2; ni++)
                    acc[mi][ni] = __builtin_amdgcn_mfma_f32_32x32x16_bf16(af[mi], bf[ni], acc[mi][ni], 0, 0, 0);
        }
    }

#pragma unroll
    for (int mi = 0; mi < 2; mi++) {
#pragma unroll
        for (int ni = 0; ni < 2; ni++) {
            const int col = tile_n + wn + ni * 32 + l31;
            const float bv = bias[col];
            const int rowb = tile_m + wm + mi * 32 + 4 * half;
#pragma unroll
            for (int r = 0; r < 16; r++) {
                const int row = rowb + (r & 3) + 8 * (r >> 2);
                float v = acc[mi][ni][r] + bv;
                if (RELU) v = fmaxf(v, 0.0f);
                if (OUT_BF16) Cb[(size_t)row * N + col] = f2b(v);
                else          Cf[(size_t)row * N + col] = v;
            }
        }
    }
}

// split-K: blockIdx.z = z over K-range [z*Kc,(z+1)*Kc); bf16 partial at Pbase + z*pstride.
__global__ __launch_bounds__(256, 4)
void gemm_bf16_splitk(const unsigned short* __restrict__ A, int lda,
                      const unsigned short* __restrict__ Bt, int ldb, size_t bt_batch,
                      const float* __restrict__ bias,
                      unsigned short* __restrict__ Pbase, size_t pstride,
                      int N, int Kc, int ntn) {
    __shared__ unsigned short lA[128 * 64];
    __shared__ unsigned short lB[128 * 64];
    int tile_m, tile_n;
    tile_swizzle(blockIdx.x, ntn, tile_m, tile_n);
    const int z = blockIdx.z;
    const int kofs = z * Kc;
    const int t = threadIdx.x;
    const int wave = t >> 6, lane = t & 63;
    const int wm = (wave >> 1) * 64, wn = (wave & 1) * 64;
    const int l31 = lane & 31, half = lane >> 5;

    const int srow = lane >> 3;
    const int schunk = ((lane & 7) ^ srow) * 8;
    const unsigned short* gA = A + (size_t)(tile_m + wave * 32 + srow) * lda + kofs + schunk;
    const unsigned short* gB = Bt + (size_t)(tile_m >> 10) * bt_batch
                                  + (size_t)(tile_n + wave * 32 + srow) * ldb + kofs + schunk;

    f32x16 acc[2][2];
#pragma unroll
    for (int i = 0; i < 2; i++)
#pragma unroll
        for (int j = 0; j < 2; j++) acc[i][j] = (f32x16)0.0f;

    for (int k0 = 0; k0 < Kc; k0 += 64) {
        __syncthreads();
#pragma unroll
        for (int r = 0; r < 4; ++r) {
            __builtin_amdgcn_global_load_lds(GLOBAL_CAST(gA + (size_t)r * 8 * lda),
                                             LDS_CAST(&lA[(wave * 32 + r * 8) * 64]), 16, 0, 0);
            __builtin_amdgcn_global_load_lds(GLOBAL_CAST(gB + (size_t)r * 8 * ldb),
                                             LDS_CAST(&lB[(wave * 32 + r * 8) * 64]), 16, 0, 0);
        }
        gA += 64; gB += 64;
        __builtin_amdgcn_s_waitcnt(0);
        __syncthreads();

#pragma unroll
        for (int ks = 0; ks < 4; ++ks) {
            const int cb = ks * 2 + half;
            bf16x8 af[2], bf[2];
#pragma unroll
            for (int i = 0; i < 2; i++) {
                const int ra = wm + i * 32 + l31;
                af[i] = *(const bf16x8*)&lA[ra * 64 + ((cb ^ (ra & 7)) * 8)];
                const int rb = wn + i * 32 + l31;
                bf[i] = *(const bf16x8*)&lB[rb * 64 + ((cb ^ (rb & 7)) * 8)];
            }
#pragma unroll
            for (int mi = 0; mi < 2; mi++)
#pragma unroll
                for (int ni = 0; ni < 2; ni++)
                    acc[mi][ni] = __builtin_amdgcn_mfma_f32_32x32x16_bf16(af[mi], bf[ni], acc[mi][ni], 0, 0, 0);
        }
    }

    unsigned short* P = Pbase + (size_t)z * pstride;
#pragma unroll
    for (int mi = 0; mi < 2; mi++) {
#pragma unroll
        for (int ni = 0; ni < 2; ni++) {
            const int col = tile_n + wn + ni * 32 + l31;
            const float bv = (z == 0) ? bias[col] : 0.0f;
            const int rowb = tile_m + wm + mi * 32 + 4 * half;
#pragma unroll
            for (int r = 0; r < 16; r++) {
                const int row = rowb + (r & 3) + 8 * (r >> 2);
                P[(size_t)row * N + col] = f2b(acc[mi][ni][r] + bv);
            }
        }
    }
}

// ---------------- S_ext GEMM + V^T transpose, merged ----------------
// flat grid 4672: [0,576) sext; [576,4672) V^T tiles.
__global__ __launch_bounds__(256, 4)
void sext_tv(const unsigned short* __restrict__ QKV,
             const unsigned short* __restrict__ relPad,
             unsigned short* __restrict__ Pbase,
             unsigned short* __restrict__ Bwv, int Kc) {
    __shared__ unsigned short lA[128 * 64];
    __shared__ unsigned short lB[128 * 64];
    const int id = blockIdx.x, t = threadIdx.x;

    if (id >= 576) {   // ---- V^T tile ----
        unsigned short (*tile)[33] = (unsigned short (*)[33])lA;
        const int t2 = id - 576;
        const int b = t2 >> 10;
        const int d0 = (t2 & 31) * 32, s0 = ((t2 >> 5) & 31) * 32;
        const int tx = t & 31, ty = t >> 5;  // 32 x 8
#pragma unroll
        for (int r = 0; r < 32; r += 8)
            tile[ty + r][tx] = QKV[(size_t)((b << 10) + s0 + ty + r) * 3072 + 2048 + d0 + tx];
        __syncthreads();
#pragma unroll
        for (int r = 0; r < 32; r += 8)
            Bwv[(size_t)b * BT_WV + (size_t)(d0 + ty + r) * LDB_WV + s0 + tx] = tile[tx][ty + r];
        return;
    }

    // ---- sext: [K(1024);relbPad(128)] @ Q^T per batch, split-K=2, bf16 partials ----
    const int bx = id % 72, b = (id / 72) & 3, z = id / 288;
    const int tile_m = (bx >> 3) * 128;
    const int tile_n = (bx & 7) * 128;
    const int kofs = z * Kc;
    const int wave = t >> 6, lane = t & 63;
    const int wm = (wave >> 1) * 64, wn = (wave & 1) * 64;
    const int l31 = lane & 31, half = lane >> 5;

    const int srow = lane >> 3;
    const int schunk = ((lane & 7) ^ srow) * 8;
    const int arow = tile_m + wave * 32 + srow;
    const unsigned short* gA;
    size_t lda;
    if (tile_m < 1024) {   // K rows
        gA = QKV + (size_t)b * BT_QKV + (size_t)arow * 3072 + 1024 + kofs + schunk;
        lda = 3072;
    } else {               // relPad rows (shared across batches)
        gA = relPad + (size_t)(arow - 1024) * 1024 + kofs + schunk;
        lda = 1024;
    }
    const unsigned short* gB = QKV + (size_t)b * BT_QKV
                                   + (size_t)(tile_n + wave * 32 + srow) * 3072 + kofs + schunk;

    f32x16 acc[2][2];
#pragma unroll
    for (int i = 0; i < 2; i++)
#pragma unroll
        for (int j = 0; j < 2; j++) acc[i][j] = (f32x16)0.0f;

    for (int k0 = 0; k0 < Kc; k0 += 64) {
        __syncthreads();
#pragma unroll
        for (int r = 0; r < 4; ++r) {
            __builtin_amdgcn_global_load_lds(GLOBAL_CAST(gA + (size_t)r * 8 * lda),
                                             LDS_CAST(&lA[(wave * 32 + r * 8) * 64]), 16, 0, 0);
            __builtin_amdgcn_global_load_lds(GLOBAL_CAST(gB + (size_t)r * 8 * 3072),
                                             LDS_CAST(&lB[(wave * 32 + r * 8) * 64]), 16, 0, 0);
        }
        gA += 64; gB += 64;
        __builtin_amdgcn_s_waitcnt(0);
        __syncthreads();

#pragma unroll
        for (int ks = 0; ks < 4; ++ks) {
            const int cb = ks * 2 + half;
            bf16x8 af[2], bf[2];
#pragma unroll
            for (int i = 0; i < 2; i++) {
                const int ra = wm + i * 32 + l31;
                af[i] = *(const bf16x8*)&lA[ra * 64 + ((cb ^ (ra & 7)) * 8)];
                const int rb = wn + i * 32 + l31;
                bf[i] = *(const bf16x8*)&lB[rb * 64 + ((cb ^ (rb & 7)) * 8)];
            }
#pragma unroll
            for (int mi = 0; mi < 2; mi++)
#pragma unroll
                for (int ni = 0; ni < 2; ni++)
                    acc[mi][ni] = __builtin_amdgcn_mfma_f32_32x32x16_bf16(af[mi], bf[ni], acc[mi][ni], 0, 0, 0);
        }
    }

    unsigned short* P = Pbase + ((size_t)z * B_SZ + b) * (SEXT_M * 1024);
#pragma unroll
    for (int mi = 0; mi < 2; mi++) {
#pragma unroll
        for (int ni = 0; ni < 2; ni++) {
            const int col = tile_n + wn + ni * 32 + l31;
            const int rowb = tile_m + wm + mi * 32 + 4 * half;
#pragma unroll
            for (int r = 0; r < 16; r++) {
                const int row = rowb + (r & 3) + 8 * (r >> 2);
                P[(size_t)row * 1024 + col] = f2b(acc[mi][ni][r]);
            }
        }
    }
}

// ---------------- LayerNorm family ----------------
template<int MODE, int NR>
__global__ void ln_kernel(const float* __restrict__ X, const unsigned short* __restrict__ Xb,
                          const unsigned short* __restrict__ Rbase, size_t rstride,
                          const float* __restrict__ g, const float* __restrict__ be,
                          unsigned short* __restrict__ ob16,
                          const float* __restrict__ hidden, float* __restrict__ fout) {
    __shared__ float sb1[4], sb2[4];
    const int row = blockIdx.x, t = threadIdx.x;
    const size_t base = (size_t)row * 1024 + t * 4;

    float x0, x1, x2, x3;
    if (MODE == 2) {
        ushort4 xv = *(const ushort4*)(Xb + base);
        x0 = b2f(xv.x); x1 = b2f(xv.y); x2 = b2f(xv.z); x3 = b2f(xv.w);
    } else {
        float4 xv = *(const float4*)(X + base);
        x0 = xv.x; x1 = xv.y; x2 = xv.z; x3 = xv.w;
    }
#pragma unroll
    for (int r = 0; r < NR; r++) {
        ushort4 rv = *(const ushort4*)(Rbase + r * rstride + base);
        x0 += b2f(rv.x); x1 += b2f(rv.y); x2 += b2f(rv.z); x3 += b2f(rv.w);
    }
    float s = x0 + x1 + x2 + x3;
#pragma unroll
    for (int o = 32; o > 0; o >>= 1) s += __shfl_down(s, o);
    if ((t & 63) == 0) sb1[t >> 6] = s;
    __syncthreads();
    const float mu = (sb1[0] + sb1[1] + sb1[2] + sb1[3]) * (1.0f / 1024.0f);

    const float d0 = x0 - mu, d1 = x1 - mu, d2 = x2 - mu, d3 = x3 - mu;
    float s2 = d0 * d0 + d1 * d1 + d2 * d2 + d3 * d3;
#pragma unroll
    for (int o = 32; o > 0; o >>= 1) s2 += __shfl_down(s2, o);
    if ((t & 63) == 0) sb2[t >> 6] = s2;
    __syncthreads();
    const float var = (sb2[0] + sb2[1] + sb2[2] + sb2[3]) * (1.0f / 1024.0f);
    const float rstd = rsqrtf(var + 1e-6f);

    const float4 gv = *(const float4*)(g + t * 4);
    const float4 bv = *(const float4*)(be + t * 4);
    const float y0 = d0 * rstd * gv.x + bv.x;
    const float y1 = d1 * rstd * gv.y + bv.y;
    const float y2 = d2 * rstd * gv.z + bv.z;
    const float y3 = d3 * rstd * gv.w + bv.w;

    if (MODE == 1) {
        ushort4 ob; ob.x = f2b(y0); ob.y = f2b(y1); ob.z = f2b(y2); ob.w = f2b(y3);
        *(ushort4*)(ob16 + base) = ob;
    } else {
        const float4 hv = *(const float4*)(hidden + base);
        const float e0 = y0 > 0.0f ? y0 : expm1f(y0);
        const float e1 = y1 > 0.0f ? y1 : expm1f(y1);
        const float e2 = y2 > 0.0f ? y2 : expm1f(y2);
        const float e3 = y3 > 0.0f ? y3 : expm1f(y3);
        float4 o; o.x = hv.x + e0; o.y = hv.y + e1; o.z = hv.z + e2; o.w = hv.w + e3;
        *(float4*)(fout + base) = o;
    }
}

// ---------------- dense edge phase ----------------
__global__ void edge_scatter(const unsigned short* __restrict__ S,
                             const int* __restrict__ src, const int* __restrict__ dst,
                             const int* __restrict__ rel,
                             float* __restrict__ A, float* __restrict__ G) {
    const size_t ZSTR = (size_t)B_SZ * SEXT_M * 1024;
    const int gg = blockIdx.x * 256 + threadIdx.x;   // B*E = 131072
    const int b = gg >> 15;
    const int s = src[gg], d = dst[gg], r = rel[gg];
    const size_t sbase = ((size_t)b * SEXT_M + s) * 1024 + d;
    const size_t tbase = ((size_t)b * SEXT_M + 1024 + r) * 1024 + d;
    const float sval = b2f(S[sbase]) + b2f(S[sbase + ZSTR]);
    const float tval = b2f(S[tbase]) + b2f(S[tbase + ZSTR]);
    float sc = (sval + tval) * (1.0f / 32.0f);
    sc = expf(fminf(fmaxf(sc, -10.0f), 10.0f));
    atomicAdd(&A[((size_t)((b << 10) + d) << 10) + s], sc);
    atomicAdd(&G[((size_t)((b << 10) + d) << 6) + r], sc);
}

// per node: inv = 1/sum_r G[row,r]; Awv[row] = bf16([A*inv | G*inv])  (1088-wide)
__global__ void normalize(const float* __restrict__ A, const float* __restrict__ G,
                          unsigned short* __restrict__ Awv) {
    __shared__ float sInv;
    const int row = blockIdx.x, t = threadIdx.x;
    float v = 0.0f;
    if (t < 64) {
        v = G[(size_t)row * 64 + t];
        float s = v;
#pragma unroll
        for (int o = 1; o < 64; o <<= 1) s += __shfl_xor(s, o);
        if (t == 0) sInv = 1.0f / s;
    }
    __syncthreads();
    const float inv = sInv;
    const size_t obase = (size_t)row * LDB_WV;
    const float4 a = *(const float4*)(A + (size_t)row * 1024 + t * 4);
    ushort4 o;
    o.x = f2b(a.x * inv); o.y = f2b(a.y * inv); o.z = f2b(a.z * inv); o.w = f2b(a.w * inv);
    *(ushort4*)(Awv + obase + t * 4) = o;
    if (t < 16) {
        const float4 gq = *(const float4*)(G + (size_t)row * 64 + t * 4);
        ushort4 og;
        og.x = f2b(gq.x * inv); og.y = f2b(gq.y * inv);
        og.z = f2b(gq.z * inv); og.w = f2b(gq.w * inv);
        *(ushort4*)(Awv + obase + 1024 + t * 4) = og;
    }
}

// ---------------- launch ----------------
extern "C" void kernel_launch(void* const* d_in, const int* in_sizes, int n_in,
                              void* d_out, int out_size, void* d_ws, size_t ws_size,
                              hipStream_t stream) {
    const float* hidden  = (const float*)d_in[0];
    const float* rel_tbl = (const float*)d_in[1];
    const float* Wq = (const float*)d_in[2];
    const float* bq = (const float*)d_in[3];
    const float* Wk = (const float*)d_in[4];
    const float* Wv = (const float*)d_in[5];
    const float* Wo = (const float*)d_in[6];
    const float* bo = (const float*)d_in[7];
    const float* ln0_g = (const float*)d_in[8];
    const float* ln0_b = (const float*)d_in[9];
    const float* ln1_g = (const float*)d_in[10];
    const float* ln1_b = (const float*)d_in[11];
    const float* W1 = (const float*)d_in[12];
    const float* b1 = (const float*)d_in[13];
    const float* W2 = (const float*)d_in[14];
    const float* b2 = (const float*)d_in[15];
    const float* ln2_g = (const float*)d_in[16];
    const float* ln2_b = (const float*)d_in[17];
    const int* esrc = (const int*)d_in[18];
    const int* edst = (const int*)d_in[19];
    const int* erel = (const int*)d_in[20];
    float* out = (float*)d_out;

    // ws lifetime map (peak 121MB) — identical overlay to R7/R9.
    char* ws = (char*)d_ws;
    const size_t MB = 1024 * 1024;
    float*          Xn_f32  = (float*)(ws + 0);
    unsigned short* Xn_b16  = (unsigned short*)(ws + 16 * MB);
    unsigned short* H1      = (unsigned short*)(ws + 0);
    unsigned short* Wqkv_t  = (unsigned short*)(ws + 24 * MB);
    unsigned short* Wo_t    = (unsigned short*)(ws + 30 * MB);
    unsigned short* W1_t    = (unsigned short*)(ws + 32 * MB);
    unsigned short* W2_t    = (unsigned short*)(ws + 40 * MB);
    unsigned short* relbPad = (unsigned short*)(ws + 48 * MB);
    float*          bqkv    = (float*)(ws + 48 * MB + 512 * 1024);
    const float*    zbias   = bqkv + 1024;  // 2048 zeros
    unsigned short* QKV     = (unsigned short*)(ws + 49 * MB);
    unsigned short* Awv     = (unsigned short*)(ws + 49 * MB);
    unsigned short* Obf     = (unsigned short*)(ws + 58 * MB);
    unsigned short* Qw2H    = (unsigned short*)(ws + 49 * MB);
    unsigned short* PwoH    = (unsigned short*)(ws + 66 * MB);
    unsigned short* SxH     = (unsigned short*)(ws + 73 * MB);
    unsigned short* Bwv     = (unsigned short*)(ws + 92 * MB);
    float*          Amat    = (float*)(ws + 101 * MB);
    float*          Gmat    = (float*)(ws + 117 * MB);
    unsigned short* Out_b16 = (unsigned short*)(ws + 113 * MB);

    const size_t PSTRIDE_H = 4u * 1024 * 1024;   // 8MB bf16 partial, in ushorts
    const dim3 blk(256);

    // ---- fused prep (weights + rel + bias + LN0 + zero A|G) ----
    prep_all<<<19020, blk, 0, stream>>>(Wq, Wk, Wv, Wo, W1, W2, rel_tbl, bq,
                                        hidden, ln0_g, ln0_b,
                                        Wqkv_t, Wo_t, W1_t, W2_t, relbPad, Bwv, bqkv,
                                        Xn_f32, Xn_b16, Amat);
    // ---- QKV GEMM ----
    gemm_bf16<true, false><<<dim3(24 * 32), blk, 0, stream>>>(
        Xn_b16, 1024, Wqkv_t, 1024, 0, bqkv, nullptr, QKV, 3072, 1024, 24);
    // ---- S_ext GEMM + V^T (merged) ----
    sext_tv<<<4672, blk, 0, stream>>>(QKV, relbPad, SxH, Bwv, 512);
    // ---- scatter scores into pre-zeroed A,G ----
    edge_scatter<<<512, blk, 0, stream>>>(SxH, esrc, edst, erel, Amat, Gmat);
    // ---- normalize -> Awv [4096,1088] ----
    normalize<<<M_ROWS, blk, 0, stream>>>(Amat, Gmat, Awv);
    // ---- wv: Obf = Awv @ Bwv^T  (K=1088, batched B) ----
    gemm_bf16<true, false><<<dim3(8 * 32), blk, 0, stream>>>(
        Awv, LDB_WV, Bwv, LDB_WV, BT_WV, zbias, nullptr, Obf, 1024, LDB_WV, 8);
    // ---- o @ Wo + bo (split-K=2, bf16 partials) ----
    gemm_bf16_splitk<<<dim3(8 * 32, 1, 2), blk, 0, stream>>>(
        Obf, 1024, Wo_t, 1024, 0, bo, PwoH, PSTRIDE_H, 1024, 512, 8);
    // ---- LN1 ----
    ln_kernel<1, 2><<<M_ROWS, blk, 0, stream>>>(Xn_f32, nullptr, PwoH, PSTRIDE_H, ln1_g, ln1_b,
                                                Out_b16, nullptr, nullptr);
    // ---- FFN1 ----
    gemm_bf16<true, true><<<dim3(32 * 32), blk, 0, stream>>>(
        Out_b16, 1024, W1_t, 1024, 0, b1, nullptr, H1, 4096, 1024, 32);
    // ---- W2 (split-K=4, bf16 partials) ----
    gemm_bf16_splitk<<<dim3(8 * 32, 1, 4), blk, 0, stream>>>(
        H1, 4096, W2_t, 4096, 0, b2, Qw2H, PSTRIDE_H, 1024, 1024, 8);
    // ---- LN2 + elu + residual ----
    ln_kernel<2, 4><<<M_ROWS, blk, 0, stream>>>(nullptr, Out_b16, Qw2H, PSTRIDE_H, ln2_g, ln2_b,
                                                nullptr, hidden, out);
    (void)in_sizes; (void)n_in; (void)out_size; (void)ws_size;
}

// Round 11
// 363.311 us; speedup vs baseline: 1.3573x; 1.0138x over previous
//
#include <hip/hip_runtime.h>
#include <hip/hip_bf16.h>

#define B_SZ 4
#define L_SEQ 1024
#define D_MODEL 1024
#define DF_FF 4096
#define E_PER_B 32768
#define R_REL 64
#define M_ROWS (B_SZ * L_SEQ)   // 4096

typedef __attribute__((ext_vector_type(8))) short bf16x8;
typedef __attribute__((ext_vector_type(4))) float f32x4;

__device__ inline float b2f(unsigned short u) {
    union { unsigned int i; float f; } x; x.i = ((unsigned int)u) << 16; return x.f;
}
__device__ inline unsigned short f2b(float f) {
    union { float f; unsigned int u; } x; x.f = f;
    unsigned int r = x.u + 0x7FFFu + ((x.u >> 16) & 1u);
    return (unsigned short)(r >> 16);
}

#define GLOBAL_CAST(p) ((const __attribute__((address_space(1))) void*)(p))
#define LDS_CAST(p)    ((__attribute__((address_space(3))) void*)(p))

#define LDB_WV 1088                      // [V | rel] combined K width (17*64)
#define BT_WV  (1024u * 1088u)           // per-batch Bwv stride (elements)
#define BT_QKV (1024u * 3072u)           // per-batch QKV stride
#define SEXT_M 1152                      // S_ext rows per batch: 1024 src + 128 relPad

// ---------------- fused prep: weights + rel + bias + LN0(bf16 out) + zero(A|G) ----------------
__global__ void prep_all(const float* __restrict__ Wq, const float* __restrict__ Wk,
                         const float* __restrict__ Wv, const float* __restrict__ Wo,
                         const float* __restrict__ W1, const float* __restrict__ W2,
                         const float* __restrict__ rel, const float* __restrict__ bq,
                         const float* __restrict__ hidden,
                         const float* __restrict__ ln0_g, const float* __restrict__ ln0_b,
                         unsigned short* __restrict__ Wqkv_t, unsigned short* __restrict__ Wo_t,
                         unsigned short* __restrict__ W1_t, unsigned short* __restrict__ W2_t,
                         unsigned short* __restrict__ relbPad, unsigned short* __restrict__ Bwv,
                         float* __restrict__ bqkv,
                         unsigned short* __restrict__ Xn_b16,
                         float* __restrict__ zeroReg) {
    __shared__ float tile[32][33];
    __shared__ float sb1[4], sb2[4];
    const int id = blockIdx.x, tid = threadIdx.x;
    if (id < 12288) {
        const float* src; unsigned short* dst; int K, N, x, y;
        if (id < 4096) {
            const int seg = id >> 10, t = id & 1023;
            K = 1024; N = 1024; x = t & 31; y = t >> 5;
            src = (seg == 0) ? Wq : (seg == 1) ? Wk : (seg == 2) ? Wv : Wo;
            dst = (seg == 3) ? Wo_t : (Wqkv_t + (size_t)seg * 1048576);
        } else if (id < 8192) {
            const int t = id - 4096; K = 1024; N = 4096; x = t & 127; y = t >> 7;
            src = W1; dst = W1_t;
        } else {
            const int t = id - 8192; K = 4096; N = 1024; x = t & 31; y = t >> 5;
            src = W2; dst = W2_t;
        }
        const int n0 = x * 32, k0 = y * 32, tx = tid & 31, ty = tid >> 5;
#pragma unroll
        for (int r = 0; r < 32; r += 8)
            tile[ty + r][tx] = src[(size_t)(k0 + ty + r) * N + (n0 + tx)];
        __syncthreads();
#pragma unroll
        for (int r = 0; r < 32; r += 8)
            dst[(size_t)(n0 + ty + r) * K + (k0 + tx)] = f2b(tile[tx][ty + r]);
    } else if (id < 12800) {
        const int i = (id - 12288) * 256 + tid;            // 131072
        relbPad[i] = (i < 65536) ? f2b(rel[i]) : (unsigned short)0;
    } else if (id < 13824) {
        const int i = (id - 12800) * 256 + tid;            // 262144
        const int b = i >> 16, rem = i & 65535, d = rem >> 6, r = rem & 63;
        Bwv[(size_t)b * BT_WV + (size_t)d * LDB_WV + 1024 + r] = f2b(rel[r * 1024 + d]);
    } else if (id < 13836) {
        const int i = (id - 13824) * 256 + tid;            // 3072
        bqkv[i] = (i < 1024) ? bq[i] : 0.0f;
    } else if (id < 17932) {
        // LN0 row -> bf16 only
        const int row = id - 13836, t = tid;
        const size_t base = (size_t)row * 1024 + t * 4;
        float4 xv = *(const float4*)(hidden + base);
        float x0 = xv.x, x1 = xv.y, x2 = xv.z, x3 = xv.w;
        float s = x0 + x1 + x2 + x3;
#pragma unroll
        for (int o = 32; o > 0; o >>= 1) s += __shfl_down(s, o);
        if ((t & 63) == 0) sb1[t >> 6] = s;
        __syncthreads();
        const float mu = (sb1[0] + sb1[1] + sb1[2] + sb1[3]) * (1.0f / 1024.0f);
        const float d0 = x0 - mu, d1 = x1 - mu, d2 = x2 - mu, d3 = x3 - mu;
        float s2 = d0 * d0 + d1 * d1 + d2 * d2 + d3 * d3;
#pragma unroll
        for (int o = 32; o > 0; o >>= 1) s2 += __shfl_down(s2, o);
        if ((t & 63) == 0) sb2[t >> 6] = s2;
        __syncthreads();
        const float var = (sb2[0] + sb2[1] + sb2[2] + sb2[3]) * (1.0f / 1024.0f);
        const float rstd = rsqrtf(var + 1e-6f);
        const float4 gv = *(const float4*)(ln0_g + t * 4);
        const float4 bv = *(const float4*)(ln0_b + t * 4);
        ushort4 ob;
        ob.x = f2b(d0 * rstd * gv.x + bv.x);
        ob.y = f2b(d1 * rstd * gv.y + bv.y);
        ob.z = f2b(d2 * rstd * gv.z + bv.z);
        ob.w = f2b(d3 * rstd * gv.w + bv.w);
        *(ushort4*)(Xn_b16 + base) = ob;
    } else {
        // zero A|G: 1088 blocks x 4096 floats
        const size_t base = (size_t)(id - 17932) * 4096 + tid * 4;
        const float4 z4 = make_float4(0.f, 0.f, 0.f, 0.f);
#pragma unroll
        for (int j = 0; j < 4; j++)
            *(float4*)(zeroReg + base + j * 1024) = z4;
    }
}

// XCD-aware tile swizzle: XCD = linear_id % 8. Group all tile_n of a tile_m on one XCD.
__device__ inline void tile_swizzle(int id, int ntn, int& tm, int& tn) {
    tm = ((id & 7) + ((id >> 3) / ntn) * 8) * 128;
    tn = ((id >> 3) % ntn) * 128;
}

// ---------------- GEMM: 16x16x32 MFMA core (R9 known-good: 0 LDS conflicts) ----------------
// BK=64 (32KB LDS): 32 MFMA per barrier-pair. XOR swizzle slot = chunk ^ (row&7).
template<bool OUT_BF16, bool RELU>
__global__ __launch_bounds__(256, 4)
void gemm_bf16(const unsigned short* __restrict__ A, int lda,
               const unsigned short* __restrict__ Bt, int ldb, size_t bt_batch,
               const float* __restrict__ bias,
               float* __restrict__ Cf, unsigned short* __restrict__ Cb,
               int N, int K, int ntn) {
    __shared__ unsigned short lA[128 * 64];
    __shared__ unsigned short lB[128 * 64];
    int tile_m, tile_n;
    tile_swizzle(blockIdx.x, ntn, tile_m, tile_n);
    const int t = threadIdx.x;
    const int wave = t >> 6, lane = t & 63;
    const int wm = (wave >> 1) * 64, wn = (wave & 1) * 64;
    const int quad = lane >> 4, l16 = lane & 15;

    const int srow = lane >> 3;
    const int schunk = ((lane & 7) ^ srow) * 8;
    const unsigned short* gA = A + (size_t)(tile_m + wave * 32 + srow) * lda + schunk;
    const unsigned short* gB = Bt + (size_t)(tile_m >> 10) * bt_batch
                                  + (size_t)(tile_n + wave * 32 + srow) * ldb + schunk;

    f32x4 acc[4][4];
#pragma unroll
    for (int i = 0; i < 4; i++)
#pragma unroll
        for (int j = 0; j < 4; j++) acc[i][j] = (f32x4)0.0f;

    for (int k0 = 0; k0 < K; k0 += 64) {
        __syncthreads();
#pragma unroll
        for (int r = 0; r < 4; ++r) {
            __builtin_amdgcn_global_load_lds(GLOBAL_CAST(gA + (size_t)r * 8 * lda),
                                             LDS_CAST(&lA[(wave * 32 + r * 8) * 64]), 16, 0, 0);
            __builtin_amdgcn_global_load_lds(GLOBAL_CAST(gB + (size_t)r * 8 * ldb),
                                             LDS_CAST(&lB[(wave * 32 + r * 8) * 64]), 16, 0, 0);
        }
        gA += 64; gB += 64;
        __builtin_amdgcn_s_waitcnt(0);
        __syncthreads();

#pragma unroll
        for (int kk = 0; kk < 2; ++kk) {
            const int cb = kk * 4 + quad;
            bf16x8 af[4], bf[4];
#pragma unroll
            for (int i = 0; i < 4; i++) {
                const int ra = wm + i * 16 + l16;
                af[i] = *(const bf16x8*)&lA[ra * 64 + ((cb ^ (ra & 7)) * 8)];
                const int rb = wn + i * 16 + l16;
                bf[i] = *(const bf16x8*)&lB[rb * 64 + ((cb ^ (rb & 7)) * 8)];
            }
#pragma unroll
            for (int mi = 0; mi < 4; mi++)
#pragma unroll
                for (int ni = 0; ni < 4; ni++)
                    acc[mi][ni] = __builtin_amdgcn_mfma_f32_16x16x32_bf16(af[mi], bf[ni], acc[mi][ni], 0, 0, 0);
        }
    }

#pragma unroll
    for (int mi = 0; mi < 4; mi++) {
#pragma unroll
        for (int ni = 0; ni < 4; ni++) {
            const int col = tile_n + wn + ni * 16 + l16;
            const float bv = bias[col];
#pragma unroll
            for (int r = 0; r < 4; r++) {
                const int row = tile_m + wm + mi * 16 + quad * 4 + r;
                float v = acc[mi][ni][r] + bv;
                if (RELU) v = fmaxf(v, 0.0f);
                if (OUT_BF16) Cb[(size_t)row * N + col] = f2b(v);
                else          Cf[(size_t)row * N + col] = v;
            }
        }
    }
}

// split-K: blockIdx.z = z over K-range [z*Kc,(z+1)*Kc); bf16 partial at Pbase + z*pstride.
__global__ __launch_bounds__(256, 4)
void gemm_bf16_splitk(const unsigned short* __restrict__ A, int lda,
                      const unsigned short* __restrict__ Bt, int ldb, size_t bt_batch,
                      const float* __restrict__ bias,
                      unsigned short* __restrict__ Pbase, size_t pstride,
                      int N, int Kc, int ntn) {
    __shared__ unsigned short lA[128 * 64];
    __shared__ unsigned short lB[128 * 64];
    int tile_m, tile_n;
    tile_swizzle(blockIdx.x, ntn, tile_m, tile_n);
    const int z = blockIdx.z;
    const int kofs = z * Kc;
    const int t = threadIdx.x;
    const int wave = t >> 6, lane = t & 63;
    const int wm = (wave >> 1) * 64, wn = (wave & 1) * 64;
    const int quad = lane >> 4, l16 = lane & 15;

    const int srow = lane >> 3;
    const int schunk = ((lane & 7) ^ srow) * 8;
    const unsigned short* gA = A + (size_t)(tile_m + wave * 32 + srow) * lda + kofs + schunk;
    const unsigned short* gB = Bt + (size_t)(tile_m >> 10) * bt_batch
                                  + (size_t)(tile_n + wave * 32 + srow) * ldb + kofs + schunk;

    f32x4 acc[4][4];
#pragma unroll
    for (int i = 0; i < 4; i++)
#pragma unroll
        for (int j = 0; j < 4; j++) acc[i][j] = (f32x4)0.0f;

    for (int k0 = 0; k0 < Kc; k0 += 64) {
        __syncthreads();
#pragma unroll
        for (int r = 0; r < 4; ++r) {
            __builtin_amdgcn_global_load_lds(GLOBAL_CAST(gA + (size_t)r * 8 * lda),
                                             LDS_CAST(&lA[(wave * 32 + r * 8) * 64]), 16, 0, 0);
            __builtin_amdgcn_global_load_lds(GLOBAL_CAST(gB + (size_t)r * 8 * ldb),
                                             LDS_CAST(&lB[(wave * 32 + r * 8) * 64]), 16, 0, 0);
        }
        gA += 64; gB += 64;
        __builtin_amdgcn_s_waitcnt(0);
        __syncthreads();

#pragma unroll
        for (int kk = 0; kk < 2; ++kk) {
            const int cb = kk * 4 + quad;
            bf16x8 af[4], bf[4];
#pragma unroll
            for (int i = 0; i < 4; i++) {
                const int ra = wm + i * 16 + l16;
                af[i] = *(const bf16x8*)&lA[ra * 64 + ((cb ^ (ra & 7)) * 8)];
                const int rb = wn + i * 16 + l16;
                bf[i] = *(const bf16x8*)&lB[rb * 64 + ((cb ^ (rb & 7)) * 8)];
            }
#pragma unroll
            for (int mi = 0; mi < 4; mi++)
#pragma unroll
                for (int ni = 0; ni < 4; ni++)
                    acc[mi][ni] = __builtin_amdgcn_mfma_f32_16x16x32_bf16(af[mi], bf[ni], acc[mi][ni], 0, 0, 0);
        }
    }

    unsigned short* P = Pbase + (size_t)z * pstride;
#pragma unroll
    for (int mi = 0; mi < 4; mi++) {
#pragma unroll
        for (int ni = 0; ni < 4; ni++) {
            const int col = tile_n + wn + ni * 16 + l16;
            const float bv = (z == 0) ? bias[col] : 0.0f;
#pragma unroll
            for (int r = 0; r < 4; r++) {
                const int row = tile_m + wm + mi * 16 + quad * 4 + r;
                P[(size_t)row * N + col] = f2b(acc[mi][ni][r] + bv);
            }
        }
    }
}

// ---------------- S_ext GEMM + V^T transpose, merged ----------------
// flat grid 4672: [0,576) sext (bx=id%72, b=(id/72)%4, z=id/288); [576,4672) V^T tiles.
__global__ __launch_bounds__(256, 4)
void sext_tv(const unsigned short* __restrict__ QKV,
             const unsigned short* __restrict__ relPad,
             unsigned short* __restrict__ Pbase,
             unsigned short* __restrict__ Bwv, int Kc) {
    __shared__ unsigned short lA[128 * 64];
    __shared__ unsigned short lB[128 * 64];
    const int id = blockIdx.x, t = threadIdx.x;

    if (id >= 576) {   // ---- V^T tile ----
        unsigned short (*tile)[33] = (unsigned short (*)[33])lA;
        const int t2 = id - 576;
        const int b = t2 >> 10;
        const int d0 = (t2 & 31) * 32, s0 = ((t2 >> 5) & 31) * 32;
        const int tx = t & 31, ty = t >> 5;  // 32 x 8
#pragma unroll
        for (int r = 0; r < 32; r += 8)
            tile[ty + r][tx] = QKV[(size_t)((b << 10) + s0 + ty + r) * 3072 + 2048 + d0 + tx];
        __syncthreads();
#pragma unroll
        for (int r = 0; r < 32; r += 8)
            Bwv[(size_t)b * BT_WV + (size_t)(d0 + ty + r) * LDB_WV + s0 + tx] = tile[tx][ty + r];
        return;
    }

    // ---- sext: [K(1024);relbPad(128)] @ Q^T per batch, split-K=2, bf16 partials ----
    const int bx = id % 72, b = (id / 72) & 3, z = id / 288;
    const int tile_m = (bx >> 3) * 128;
    const int tile_n = (bx & 7) * 128;
    const int kofs = z * Kc;
    const int wave = t >> 6, lane = t & 63;
    const int wm = (wave >> 1) * 64, wn = (wave & 1) * 64;
    const int quad = lane >> 4, l16 = lane & 15;

    const int srow = lane >> 3;
    const int schunk = ((lane & 7) ^ srow) * 8;
    const int arow = tile_m + wave * 32 + srow;
    const unsigned short* gA;
    size_t lda;
    if (tile_m < 1024) {   // K rows
        gA = QKV + (size_t)b * BT_QKV + (size_t)arow * 3072 + 1024 + kofs + schunk;
        lda = 3072;
    } else {               // relPad rows (shared across batches)
        gA = relPad + (size_t)(arow - 1024) * 1024 + kofs + schunk;
        lda = 1024;
    }
    const unsigned short* gB = QKV + (size_t)b * BT_QKV
                                   + (size_t)(tile_n + wave * 32 + srow) * 3072 + kofs + schunk;

    f32x4 acc[4][4];
#pragma unroll
    for (int i = 0; i < 4; i++)
#pragma unroll
        for (int j = 0; j < 4; j++) acc[i][j] = (f32x4)0.0f;

    for (int k0 = 0; k0 < Kc; k0 += 64) {
        __syncthreads();
#pragma unroll
        for (int r = 0; r < 4; ++r) {
            __builtin_amdgcn_global_load_lds(GLOBAL_CAST(gA + (size_t)r * 8 * lda),
                                             LDS_CAST(&lA[(wave * 32 + r * 8) * 64]), 16, 0, 0);
            __builtin_amdgcn_global_load_lds(GLOBAL_CAST(gB + (size_t)r * 8 * 3072),
                                             LDS_CAST(&lB[(wave * 32 + r * 8) * 64]), 16, 0, 0);
        }
        gA += 64; gB += 64;
        __builtin_amdgcn_s_waitcnt(0);
        __syncthreads();

#pragma unroll
        for (int kk = 0; kk < 2; ++kk) {
            const int cb = kk * 4 + quad;
            bf16x8 af[4], bf[4];
#pragma unroll
            for (int i = 0; i < 4; i++) {
                const int ra = wm + i * 16 + l16;
                af[i] = *(const bf16x8*)&lA[ra * 64 + ((cb ^ (ra & 7)) * 8)];
                const int rb = wn + i * 16 + l16;
                bf[i] = *(const bf16x8*)&lB[rb * 64 + ((cb ^ (rb & 7)) * 8)];
            }
#pragma unroll
            for (int mi = 0; mi < 4; mi++)
#pragma unroll
                for (int ni = 0; ni < 4; ni++)
                    acc[mi][ni] = __builtin_amdgcn_mfma_f32_16x16x32_bf16(af[mi], bf[ni], acc[mi][ni], 0, 0, 0);
        }
    }

    unsigned short* P = Pbase + ((size_t)z * B_SZ + b) * (SEXT_M * 1024);
#pragma unroll
    for (int mi = 0; mi < 4; mi++) {
#pragma unroll
        for (int ni = 0; ni < 4; ni++) {
            const int col = tile_n + wn + ni * 16 + l16;
#pragma unroll
            for (int r = 0; r < 4; r++) {
                const int row = tile_m + wm + mi * 16 + quad * 4 + r;
                P[(size_t)row * 1024 + col] = f2b(acc[mi][ni][r]);
            }
        }
    }
}

// ---------------- LayerNorm family (bf16 X + bf16 partials) ----------------
// FINAL=false: y -> ob16.  FINAL=true: fout = hidden + elu(y).
template<bool FINAL, int NR>
__global__ void ln_kernel(const unsigned short* __restrict__ Xb,
                          const unsigned short* __restrict__ Rbase, size_t rstride,
                          const float* __restrict__ g, const float* __restrict__ be,
                          unsigned short* __restrict__ ob16,
                          const float* __restrict__ hidden, float* __restrict__ fout) {
    __shared__ float sb1[4], sb2[4];
    const int row = blockIdx.x, t = threadIdx.x;
    const size_t base = (size_t)row * 1024 + t * 4;

    ushort4 xv = *(const ushort4*)(Xb + base);
    float x0 = b2f(xv.x), x1 = b2f(xv.y), x2 = b2f(xv.z), x3 = b2f(xv.w);
#pragma unroll
    for (int r = 0; r < NR; r++) {
        ushort4 rv = *(const ushort4*)(Rbase + r * rstride + base);
        x0 += b2f(rv.x); x1 += b2f(rv.y); x2 += b2f(rv.z); x3 += b2f(rv.w);
    }
    float s = x0 + x1 + x2 + x3;
#pragma unroll
    for (int o = 32; o > 0; o >>= 1) s += __shfl_down(s, o);
    if ((t & 63) == 0) sb1[t >> 6] = s;
    __syncthreads();
    const float mu = (sb1[0] + sb1[1] + sb1[2] + sb1[3]) * (1.0f / 1024.0f);

    const float d0 = x0 - mu, d1 = x1 - mu, d2 = x2 - mu, d3 = x3 - mu;
    float s2 = d0 * d0 + d1 * d1 + d2 * d2 + d3 * d3;
#pragma unroll
    for (int o = 32; o > 0; o >>= 1) s2 += __shfl_down(s2, o);
    if ((t & 63) == 0) sb2[t >> 6] = s2;
    __syncthreads();
    const float var = (sb2[0] + sb2[1] + sb2[2] + sb2[3]) * (1.0f / 1024.0f);
    const float rstd = rsqrtf(var + 1e-6f);

    const float4 gv = *(const float4*)(g + t * 4);
    const float4 bv = *(const float4*)(be + t * 4);
    const float y0 = d0 * rstd * gv.x + bv.x;
    const float y1 = d1 * rstd * gv.y + bv.y;
    const float y2 = d2 * rstd * gv.z + bv.z;
    const float y3 = d3 * rstd * gv.w + bv.w;

    if (!FINAL) {
        ushort4 ob; ob.x = f2b(y0); ob.y = f2b(y1); ob.z = f2b(y2); ob.w = f2b(y3);
        *(ushort4*)(ob16 + base) = ob;
    } else {
        const float4 hv = *(const float4*)(hidden + base);
        const float e0 = y0 > 0.0f ? y0 : expm1f(y0);
        const float e1 = y1 > 0.0f ? y1 : expm1f(y1);
        const float e2 = y2 > 0.0f ? y2 : expm1f(y2);
        const float e3 = y3 > 0.0f ? y3 : expm1f(y3);
        float4 o; o.x = hv.x + e0; o.y = hv.y + e1; o.z = hv.z + e2; o.w = hv.w + e3;
        *(float4*)(fout + base) = o;
    }
}

// ---------------- dense edge phase ----------------
__global__ void edge_scatter(const unsigned short* __restrict__ S,
                             const int* __restrict__ src, const int* __restrict__ dst,
                             const int* __restrict__ rel,
                             float* __restrict__ A, float* __restrict__ G) {
    const size_t ZSTR = (size_t)B_SZ * SEXT_M * 1024;
    const int gg = blockIdx.x * 256 + threadIdx.x;   // B*E = 131072
    const int b = gg >> 15;
    const int s = src[gg], d = dst[gg], r = rel[gg];
    const size_t sbase = ((size_t)b * SEXT_M + s) * 1024 + d;
    const size_t tbase = ((size_t)b * SEXT_M + 1024 + r) * 1024 + d;
    const float sval = b2f(S[sbase]) + b2f(S[sbase + ZSTR]);
    const float tval = b2f(S[tbase]) + b2f(S[tbase + ZSTR]);
    float sc = (sval + tval) * (1.0f / 32.0f);
    sc = expf(fminf(fmaxf(sc, -10.0f), 10.0f));
    atomicAdd(&A[((size_t)((b << 10) + d) << 10) + s], sc);
    atomicAdd(&G[((size_t)((b << 10) + d) << 6) + r], sc);
}

// per node: inv = 1/sum_r G[row,r]; Awv[row] = bf16([A*inv | G*inv])  (1088-wide)
__global__ void normalize(const float* __restrict__ A, const float* __restrict__ G,
                          unsigned short* __restrict__ Awv) {
    __shared__ float sInv;
    const int row = blockIdx.x, t = threadIdx.x;
    float v = 0.0f;
    if (t < 64) {
        v = G[(size_t)row * 64 + t];
        float s = v;
#pragma unroll
        for (int o = 1; o < 64; o <<= 1) s += __shfl_xor(s, o);
        if (t == 0) sInv = 1.0f / s;
    }
    __syncthreads();
    const float inv = sInv;
    const size_t obase = (size_t)row * LDB_WV;
    const float4 a = *(const float4*)(A + (size_t)row * 1024 + t * 4);
    ushort4 o;
    o.x = f2b(a.x * inv); o.y = f2b(a.y * inv); o.z = f2b(a.z * inv); o.w = f2b(a.w * inv);
    *(ushort4*)(Awv + obase + t * 4) = o;
    if (t < 16) {
        const float4 gq = *(const float4*)(G + (size_t)row * 64 + t * 4);
        ushort4 og;
        og.x = f2b(gq.x * inv); og.y = f2b(gq.y * inv);
        og.z = f2b(gq.z * inv); og.w = f2b(gq.w * inv);
        *(ushort4*)(Awv + obase + 1024 + t * 4) = og;
    }
}

// ---------------- launch ----------------
extern "C" void kernel_launch(void* const* d_in, const int* in_sizes, int n_in,
                              void* d_out, int out_size, void* d_ws, size_t ws_size,
                              hipStream_t stream) {
    const float* hidden  = (const float*)d_in[0];
    const float* rel_tbl = (const float*)d_in[1];
    const float* Wq = (const float*)d_in[2];
    const float* bq = (const float*)d_in[3];
    const float* Wk = (const float*)d_in[4];
    const float* Wv = (const float*)d_in[5];
    const float* Wo = (const float*)d_in[6];
    const float* bo = (const float*)d_in[7];
    const float* ln0_g = (const float*)d_in[8];
    const float* ln0_b = (const float*)d_in[9];
    const float* ln1_g = (const float*)d_in[10];
    const float* ln1_b = (const float*)d_in[11];
    const float* W1 = (const float*)d_in[12];
    const float* b1 = (const float*)d_in[13];
    const float* W2 = (const float*)d_in[14];
    const float* b2 = (const float*)d_in[15];
    const float* ln2_g = (const float*)d_in[16];
    const float* ln2_b = (const float*)d_in[17];
    const int* esrc = (const int*)d_in[18];
    const int* edst = (const int*)d_in[19];
    const int* erel = (const int*)d_in[20];
    float* out = (float*)d_out;

    // ws lifetime map (peak 121MB) — R7/R9 overlay (Xn_f32 slot now unused).
    char* ws = (char*)d_ws;
    const size_t MB = 1024 * 1024;
    unsigned short* Xn_b16  = (unsigned short*)(ws + 16 * MB);
    unsigned short* H1      = (unsigned short*)(ws + 0);
    unsigned short* Wqkv_t  = (unsigned short*)(ws + 24 * MB);
    unsigned short* Wo_t    = (unsigned short*)(ws + 30 * MB);
    unsigned short* W1_t    = (unsigned short*)(ws + 32 * MB);
    unsigned short* W2_t    = (unsigned short*)(ws + 40 * MB);
    unsigned short* relbPad = (unsigned short*)(ws + 48 * MB);
    float*          bqkv    = (float*)(ws + 48 * MB + 512 * 1024);
    const float*    zbias   = bqkv + 1024;  // 2048 zeros
    unsigned short* QKV     = (unsigned short*)(ws + 49 * MB);
    unsigned short* Awv     = (unsigned short*)(ws + 49 * MB);
    unsigned short* Obf     = (unsigned short*)(ws + 58 * MB);
    unsigned short* Qw2H    = (unsigned short*)(ws + 49 * MB);
    unsigned short* PwoH    = (unsigned short*)(ws + 66 * MB);
    unsigned short* SxH     = (unsigned short*)(ws + 73 * MB);
    unsigned short* Bwv     = (unsigned short*)(ws + 92 * MB);
    float*          Amat    = (float*)(ws + 101 * MB);
    float*          Gmat    = (float*)(ws + 117 * MB);
    unsigned short* Out_b16 = (unsigned short*)(ws + 113 * MB);

    const size_t PSTRIDE_H = 4u * 1024 * 1024;   // 8MB bf16 partial, in ushorts
    const dim3 blk(256);

    // ---- fused prep (weights + rel + bias + LN0 + zero A|G) ----
    prep_all<<<19020, blk, 0, stream>>>(Wq, Wk, Wv, Wo, W1, W2, rel_tbl, bq,
                                        hidden, ln0_g, ln0_b,
                                        Wqkv_t, Wo_t, W1_t, W2_t, relbPad, Bwv, bqkv,
                                        Xn_b16, Amat);
    // ---- QKV GEMM ----
    gemm_bf16<true, false><<<dim3(24 * 32), blk, 0, stream>>>(
        Xn_b16, 1024, Wqkv_t, 1024, 0, bqkv, nullptr, QKV, 3072, 1024, 24);
    // ---- S_ext GEMM + V^T (merged) ----
    sext_tv<<<4672, blk, 0, stream>>>(QKV, relbPad, SxH, Bwv, 512);
    // ---- scatter scores into pre-zeroed A,G ----
    edge_scatter<<<512, blk, 0, stream>>>(SxH, esrc, edst, erel, Amat, Gmat);
    // ---- normalize -> Awv [4096,1088] ----
    normalize<<<M_ROWS, blk, 0, stream>>>(Amat, Gmat, Awv);
    // ---- wv: Obf = Awv @ Bwv^T  (K=1088, batched B) ----
    gemm_bf16<true, false><<<dim3(8 * 32), blk, 0, stream>>>(
        Awv, LDB_WV, Bwv, LDB_WV, BT_WV, zbias, nullptr, Obf, 1024, LDB_WV, 8);
    // ---- o @ Wo + bo (split-K=2, bf16 partials) ----
    gemm_bf16_splitk<<<dim3(8 * 32, 1, 2), blk, 0, stream>>>(
        Obf, 1024, Wo_t, 1024, 0, bo, PwoH, PSTRIDE_H, 1024, 512, 8);
    // ---- LN1: LN(Xn + Pwo) -> Out_b16 ----
    ln_kernel<false, 2><<<M_ROWS, blk, 0, stream>>>(Xn_b16, PwoH, PSTRIDE_H, ln1_g, ln1_b,
                                                    Out_b16, nullptr, nullptr);
    // ---- FFN1 ----
    gemm_bf16<true, true><<<dim3(32 * 32), blk, 0, stream>>>(
        Out_b16, 1024, W1_t, 1024, 0, b1, nullptr, H1, 4096, 1024, 32);
    // ---- W2 (split-K=4, bf16 partials) ----
    gemm_bf16_splitk<<<dim3(8 * 32, 1, 4), blk, 0, stream>>>(
        H1, 4096, W2_t, 4096, 0, b2, Qw2H, PSTRIDE_H, 1024, 1024, 8);
    // ---- LN2(out + sum Qw2) + elu + residual ----
    ln_kernel<true, 4><<<M_ROWS, blk, 0, stream>>>(Out_b16, Qw2H, PSTRIDE_H, ln2_g, ln2_b,
                                                   nullptr, hidden, out);
    (void)in_sizes; (void)n_in; (void)out_size; (void)ws_size;
}

// Round 12
// 352.114 us; speedup vs baseline: 1.4004x; 1.0318x over previous
//
#include <hip/hip_runtime.h>
#include <hip/hip_bf16.h>

#define B_SZ 4
#define L_SEQ 1024
#define D_MODEL 1024
#define DF_FF 4096
#define E_PER_B 32768
#define R_REL 64
#define M_ROWS (B_SZ * L_SEQ)   // 4096

typedef __attribute__((ext_vector_type(8))) short bf16x8;
typedef __attribute__((ext_vector_type(4))) float f32x4;

__device__ inline float b2f(unsigned short u) {
    union { unsigned int i; float f; } x; x.i = ((unsigned int)u) << 16; return x.f;
}
__device__ inline unsigned short f2b(float f) {
    union { float f; unsigned int u; } x; x.f = f;
    unsigned int r = x.u + 0x7FFFu + ((x.u >> 16) & 1u);
    return (unsigned short)(r >> 16);
}

#define GLOBAL_CAST(p) ((const __attribute__((address_space(1))) void*)(p))
#define LDS_CAST(p)    ((__attribute__((address_space(3))) void*)(p))

#define BT_QKV (1024u * 3072u)           // per-batch QKV stride
#define SEXT_M 1152                      // S_ext rows per batch: 1024 src + 128 relPad
#define LDA_WV 1088                      // Awv K width: 1024 (A) + 64 (G)
#define LDB_WVP 1152                     // Bwv' row stride (K padded to 18*64)
#define BT_WVP (1024u * 1152u)           // per-batch Bwv' stride

// ---------------- fused prep: weights + relPad + bias + LN0(bf16) + zero(A|G) ----------------
// flat grid 17996:
//   [0,12288)      weight transposes (Wq,Wk,Wv,Wo,W1,W2)
//   [12288,12800)  relbPad bf16 [128,1024] (rows 64..127 zero)
//   [12800,12812)  bqkv f32 [3072] (cols 1024+ = 0)
//   [12812,16908)  LN0 -> Xn_b16
//   [16908,17996)  zero 17MB A|G region
__global__ void prep_all(const float* __restrict__ Wq, const float* __restrict__ Wk,
                         const float* __restrict__ Wv, const float* __restrict__ Wo,
                         const float* __restrict__ W1, const float* __restrict__ W2,
                         const float* __restrict__ rel, const float* __restrict__ bq,
                         const float* __restrict__ hidden,
                         const float* __restrict__ ln0_g, const float* __restrict__ ln0_b,
                         unsigned short* __restrict__ Wqkv_t, unsigned short* __restrict__ Wo_t,
                         unsigned short* __restrict__ W1_t, unsigned short* __restrict__ W2_t,
                         unsigned short* __restrict__ relbPad,
                         float* __restrict__ bqkv,
                         unsigned short* __restrict__ Xn_b16,
                         float* __restrict__ zeroReg) {
    __shared__ float tile[32][33];
    __shared__ float sb1[4], sb2[4];
    const int id = blockIdx.x, tid = threadIdx.x;
    if (id < 12288) {
        const float* src; unsigned short* dst; int K, N, x, y;
        if (id < 4096) {
            const int seg = id >> 10, t = id & 1023;
            K = 1024; N = 1024; x = t & 31; y = t >> 5;
            src = (seg == 0) ? Wq : (seg == 1) ? Wk : (seg == 2) ? Wv : Wo;
            dst = (seg == 3) ? Wo_t : (Wqkv_t + (size_t)seg * 1048576);
        } else if (id < 8192) {
            const int t = id - 4096; K = 1024; N = 4096; x = t & 127; y = t >> 7;
            src = W1; dst = W1_t;
        } else {
            const int t = id - 8192; K = 4096; N = 1024; x = t & 31; y = t >> 5;
            src = W2; dst = W2_t;
        }
        const int n0 = x * 32, k0 = y * 32, tx = tid & 31, ty = tid >> 5;
#pragma unroll
        for (int r = 0; r < 32; r += 8)
            tile[ty + r][tx] = src[(size_t)(k0 + ty + r) * N + (n0 + tx)];
        __syncthreads();
#pragma unroll
        for (int r = 0; r < 32; r += 8)
            dst[(size_t)(n0 + ty + r) * K + (k0 + tx)] = f2b(tile[tx][ty + r]);
    } else if (id < 12800) {
        const int i = (id - 12288) * 256 + tid;            // 131072
        relbPad[i] = (i < 65536) ? f2b(rel[i]) : (unsigned short)0;
    } else if (id < 12812) {
        const int i = (id - 12800) * 256 + tid;            // 3072
        bqkv[i] = (i < 1024) ? bq[i] : 0.0f;
    } else if (id < 16908) {
        // LN0 row -> bf16
        const int row = id - 12812, t = tid;
        const size_t base = (size_t)row * 1024 + t * 4;
        float4 xv = *(const float4*)(hidden + base);
        float x0 = xv.x, x1 = xv.y, x2 = xv.z, x3 = xv.w;
        float s = x0 + x1 + x2 + x3;
#pragma unroll
        for (int o = 32; o > 0; o >>= 1) s += __shfl_down(s, o);
        if ((t & 63) == 0) sb1[t >> 6] = s;
        __syncthreads();
        const float mu = (sb1[0] + sb1[1] + sb1[2] + sb1[3]) * (1.0f / 1024.0f);
        const float d0 = x0 - mu, d1 = x1 - mu, d2 = x2 - mu, d3 = x3 - mu;
        float s2 = d0 * d0 + d1 * d1 + d2 * d2 + d3 * d3;
#pragma unroll
        for (int o = 32; o > 0; o >>= 1) s2 += __shfl_down(s2, o);
        if ((t & 63) == 0) sb2[t >> 6] = s2;
        __syncthreads();
        const float var = (sb2[0] + sb2[1] + sb2[2] + sb2[3]) * (1.0f / 1024.0f);
        const float rstd = rsqrtf(var + 1e-6f);
        const float4 gv = *(const float4*)(ln0_g + t * 4);
        const float4 bv = *(const float4*)(ln0_b + t * 4);
        ushort4 ob;
        ob.x = f2b(d0 * rstd * gv.x + bv.x);
        ob.y = f2b(d1 * rstd * gv.y + bv.y);
        ob.z = f2b(d2 * rstd * gv.z + bv.z);
        ob.w = f2b(d3 * rstd * gv.w + bv.w);
        *(ushort4*)(Xn_b16 + base) = ob;
    } else {
        const size_t base = (size_t)(id - 16908) * 4096 + tid * 4;
        const float4 z4 = make_float4(0.f, 0.f, 0.f, 0.f);
#pragma unroll
        for (int j = 0; j < 4; j++)
            *(float4*)(zeroReg + base + j * 1024) = z4;
    }
}

// XCD-aware tile swizzle: XCD = linear_id % 8. Group all tile_n of a tile_m on one XCD.
__device__ inline void tile_swizzle(int id, int ntn, int& tm, int& tn) {
    tm = ((id & 7) + ((id >> 3) / ntn) * 8) * 128;
    tn = ((id >> 3) % ntn) * 128;
}

// ---------------- GEMM: 16x16x32 MFMA core (known-good: 0 LDS conflicts) ----------------
// BK=64 (32KB LDS): 32 MFMA per barrier-pair. XOR swizzle slot = chunk ^ (row&7).
#define GEMM_BODY(GA, LDA_, GB, LDB_, KLEN)                                                 \
    f32x4 acc[4][4];                                                                        \
    _Pragma("unroll") for (int i = 0; i < 4; i++)                                           \
        _Pragma("unroll") for (int j = 0; j < 4; j++) acc[i][j] = (f32x4)0.0f;              \
    for (int k0 = 0; k0 < (KLEN); k0 += 64) {                                               \
        __syncthreads();                                                                    \
        _Pragma("unroll") for (int r = 0; r < 4; ++r) {                                     \
            __builtin_amdgcn_global_load_lds(GLOBAL_CAST((GA) + (size_t)r * 8 * (LDA_)),    \
                LDS_CAST(&lA[(wave * 32 + r * 8) * 64]), 16, 0, 0);                         \
            __builtin_amdgcn_global_load_lds(GLOBAL_CAST((GB) + (size_t)r * 8 * (LDB_)),    \
                LDS_CAST(&lB[(wave * 32 + r * 8) * 64]), 16, 0, 0);                         \
        }                                                                                   \
        (GA) += 64; (GB) += 64;                                                             \
        __builtin_amdgcn_s_waitcnt(0);                                                      \
        __syncthreads();                                                                    \
        _Pragma("unroll") for (int kk = 0; kk < 2; ++kk) {                                  \
            const int cb = kk * 4 + quad;                                                   \
            bf16x8 af[4], bf[4];                                                            \
            _Pragma("unroll") for (int i = 0; i < 4; i++) {                                 \
                const int ra = wm + i * 16 + l16;                                           \
                af[i] = *(const bf16x8*)&lA[ra * 64 + ((cb ^ (ra & 7)) * 8)];               \
                const int rb = wn + i * 16 + l16;                                           \
                bf[i] = *(const bf16x8*)&lB[rb * 64 + ((cb ^ (rb & 7)) * 8)];               \
            }                                                                               \
            _Pragma("unroll") for (int mi = 0; mi < 4; mi++)                                \
                _Pragma("unroll") for (int ni = 0; ni < 4; ni++)                            \
                    acc[mi][ni] = __builtin_amdgcn_mfma_f32_16x16x32_bf16(                  \
                        af[mi], bf[ni], acc[mi][ni], 0, 0, 0);                              \
        }                                                                                   \
    }

template<bool OUT_BF16, bool RELU>
__global__ __launch_bounds__(256, 4)
void gemm_bf16(const unsigned short* __restrict__ A, int lda,
               const unsigned short* __restrict__ Bt, int ldb, size_t bt_batch,
               const float* __restrict__ bias,
               float* __restrict__ Cf, unsigned short* __restrict__ Cb,
               int N, int K, int ntn) {
    __shared__ unsigned short lA[128 * 64];
    __shared__ unsigned short lB[128 * 64];
    int tile_m, tile_n;
    tile_swizzle(blockIdx.x, ntn, tile_m, tile_n);
    const int t = threadIdx.x;
    const int wave = t >> 6, lane = t & 63;
    const int wm = (wave >> 1) * 64, wn = (wave & 1) * 64;
    const int quad = lane >> 4, l16 = lane & 15;
    const int srow = lane >> 3;
    const int schunk = ((lane & 7) ^ srow) * 8;
    const unsigned short* gA = A + (size_t)(tile_m + wave * 32 + srow) * lda + schunk;
    const unsigned short* gB = Bt + (size_t)(tile_m >> 10) * bt_batch
                                  + (size_t)(tile_n + wave * 32 + srow) * ldb + schunk;
    GEMM_BODY(gA, lda, gB, ldb, K)
#pragma unroll
    for (int mi = 0; mi < 4; mi++) {
#pragma unroll
        for (int ni = 0; ni < 4; ni++) {
            const int col = tile_n + wn + ni * 16 + l16;
            const float bv = bias[col];
#pragma unroll
            for (int r = 0; r < 4; r++) {
                const int row = tile_m + wm + mi * 16 + quad * 4 + r;
                float v = acc[mi][ni][r] + bv;
                if (RELU) v = fmaxf(v, 0.0f);
                if (OUT_BF16) Cb[(size_t)row * N + col] = f2b(v);
                else          Cf[(size_t)row * N + col] = v;
            }
        }
    }
}

// split-K (symmetric): bf16 partial at Pbase + z*pstride.
__global__ __launch_bounds__(256, 4)
void gemm_bf16_splitk(const unsigned short* __restrict__ A, int lda,
                      const unsigned short* __restrict__ Bt, int ldb, size_t bt_batch,
                      const float* __restrict__ bias,
                      unsigned short* __restrict__ Pbase, size_t pstride,
                      int N, int Kc, int ntn) {
    __shared__ unsigned short lA[128 * 64];
    __shared__ unsigned short lB[128 * 64];
    int tile_m, tile_n;
    tile_swizzle(blockIdx.x, ntn, tile_m, tile_n);
    const int z = blockIdx.z;
    const int kofs = z * Kc;
    const int t = threadIdx.x;
    const int wave = t >> 6, lane = t & 63;
    const int wm = (wave >> 1) * 64, wn = (wave & 1) * 64;
    const int quad = lane >> 4, l16 = lane & 15;
    const int srow = lane >> 3;
    const int schunk = ((lane & 7) ^ srow) * 8;
    const unsigned short* gA = A + (size_t)(tile_m + wave * 32 + srow) * lda + kofs + schunk;
    const unsigned short* gB = Bt + (size_t)(tile_m >> 10) * bt_batch
                                  + (size_t)(tile_n + wave * 32 + srow) * ldb + kofs + schunk;
    GEMM_BODY(gA, lda, gB, ldb, Kc)
    unsigned short* P = Pbase + (size_t)z * pstride;
#pragma unroll
    for (int mi = 0; mi < 4; mi++) {
#pragma unroll
        for (int ni = 0; ni < 4; ni++) {
            const int col = tile_n + wn + ni * 16 + l16;
            const float bv = (z == 0) ? bias[col] : 0.0f;
#pragma unroll
            for (int r = 0; r < 4; r++) {
                const int row = tile_m + wm + mi * 16 + quad * 4 + r;
                P[(size_t)row * N + col] = f2b(acc[mi][ni][r] + bv);
            }
        }
    }
}

// ---------------- S_ext GEMM + W' GEMM, merged (both depend on QKV + weights only) ----------------
// flat grid 864:
//  [0,576)   sext: S_ext = [K(1024);relbPad(128)] @ Q^T per batch, split-K=2, bf16 partials.
//            P[z][b][1152][1024]: rows 0-1023 = S[src,dst], rows 1024.. = T^T[r,dst].
//  [576,864) W': Bwv'[b][e][n] = Wo_t[e,:] . ([V_b ; relbPad][n,:])   (K=1024, N=1152)
//            cols 0-1023 from V (natural layout in QKV), 1024-1151 from relbPad (1088+ = 0).
__global__ __launch_bounds__(256, 4)
void sext_w(const unsigned short* __restrict__ QKV,
            const unsigned short* __restrict__ relPad,
            const unsigned short* __restrict__ Wo_t,
            unsigned short* __restrict__ Pbase,
            unsigned short* __restrict__ Bwvp, int Kc) {
    __shared__ unsigned short lA[128 * 64];
    __shared__ unsigned short lB[128 * 64];
    const int id = blockIdx.x, t = threadIdx.x;
    const int wave = t >> 6, lane = t & 63;
    const int wm = (wave >> 1) * 64, wn = (wave & 1) * 64;
    const int quad = lane >> 4, l16 = lane & 15;
    const int srow = lane >> 3;
    const int schunk = ((lane & 7) ^ srow) * 8;

    if (id >= 576) {   // ---- W' segment ----
        const int t2 = id - 576;
        const int b = t2 / 72, rem = t2 % 72;
        const int tile_m = (rem / 9) * 128;          // e
        const int tile_n = (rem % 9) * 128;          // s | 1024+r
        const unsigned short* gA = Wo_t + (size_t)(tile_m + wave * 32 + srow) * 1024 + schunk;
        const int brow = tile_n + wave * 32 + srow;
        const unsigned short* gB;
        size_t ldb;
        if (tile_n < 1024) {                          // V rows, natural layout
            gB = QKV + (size_t)b * BT_QKV + (size_t)brow * 3072 + 2048 + schunk;
            ldb = 3072;
        } else {                                      // relPad rows
            gB = relPad + (size_t)(brow - 1024) * 1024 + schunk;
            ldb = 1024;
        }
        GEMM_BODY(gA, 1024, gB, ldb, 1024)
        unsigned short* P = Bwvp + (size_t)b * BT_WVP;
#pragma unroll
        for (int mi = 0; mi < 4; mi++) {
#pragma unroll
            for (int ni = 0; ni < 4; ni++) {
                const int col = tile_n + wn + ni * 16 + l16;
#pragma unroll
                for (int r = 0; r < 4; r++) {
                    const int row = tile_m + wm + mi * 16 + quad * 4 + r;
                    P[(size_t)row * LDB_WVP + col] = f2b(acc[mi][ni][r]);
                }
            }
        }
        return;
    }

    // ---- sext segment ----
    const int bx = id % 72, b = (id / 72) & 3, z = id / 288;
    const int tile_m = (bx >> 3) * 128;
    const int tile_n = (bx & 7) * 128;
    const int kofs = z * Kc;
    const int arow = tile_m + wave * 32 + srow;
    const unsigned short* gA;
    size_t lda;
    if (tile_m < 1024) {   // K rows
        gA = QKV + (size_t)b * BT_QKV + (size_t)arow * 3072 + 1024 + kofs + schunk;
        lda = 3072;
    } else {               // relPad rows
        gA = relPad + (size_t)(arow - 1024) * 1024 + kofs + schunk;
        lda = 1024;
    }
    const unsigned short* gB = QKV + (size_t)b * BT_QKV
                                   + (size_t)(tile_n + wave * 32 + srow) * 3072 + kofs + schunk;
    GEMM_BODY(gA, lda, gB, 3072, Kc)
    unsigned short* P = Pbase + ((size_t)z * B_SZ + b) * (SEXT_M * 1024);
#pragma unroll
    for (int mi = 0; mi < 4; mi++) {
#pragma unroll
        for (int ni = 0; ni < 4; ni++) {
            const int col = tile_n + wn + ni * 16 + l16;
#pragma unroll
            for (int r = 0; r < 4; r++) {
                const int row = tile_m + wm + mi * 16 + quad * 4 + r;
                P[(size_t)row * 1024 + col] = f2b(acc[mi][ni][r]);
            }
        }
    }
}

// ---------------- wv' GEMM: attention-out = Awv @ Bwv'^T + bo, asymmetric split-K=2 ----------------
// z=0: K [0,576); z=1: K [576,1088). bf16 partials -> PwoH + z*pstride. grid (256,1,2).
__global__ __launch_bounds__(256, 4)
void gemm_wv_splitk(const unsigned short* __restrict__ A,
                    const unsigned short* __restrict__ Bt,
                    const float* __restrict__ bias,
                    unsigned short* __restrict__ Pbase, size_t pstride) {
    __shared__ unsigned short lA[128 * 64];
    __shared__ unsigned short lB[128 * 64];
    int tile_m, tile_n;
    tile_swizzle(blockIdx.x, 8, tile_m, tile_n);
    const int z = blockIdx.z;
    const int kofs = z * 576;
    const int Kc = z ? 512 : 576;
    const int t = threadIdx.x;
    const int wave = t >> 6, lane = t & 63;
    const int wm = (wave >> 1) * 64, wn = (wave & 1) * 64;
    const int quad = lane >> 4, l16 = lane & 15;
    const int srow = lane >> 3;
    const int schunk = ((lane & 7) ^ srow) * 8;
    const unsigned short* gA = A + (size_t)(tile_m + wave * 32 + srow) * LDA_WV + kofs + schunk;
    const unsigned short* gB = Bt + (size_t)(tile_m >> 10) * BT_WVP
                                  + (size_t)(tile_n + wave * 32 + srow) * LDB_WVP + kofs + schunk;
    GEMM_BODY(gA, LDA_WV, gB, LDB_WVP, Kc)
    unsigned short* P = Pbase + (size_t)z * pstride;
#pragma unroll
    for (int mi = 0; mi < 4; mi++) {
#pragma unroll
        for (int ni = 0; ni < 4; ni++) {
            const int col = tile_n + wn + ni * 16 + l16;
            const float bv = (z == 0) ? bias[col] : 0.0f;
#pragma unroll
            for (int r = 0; r < 4; r++) {
                const int row = tile_m + wm + mi * 16 + quad * 4 + r;
                P[(size_t)row * 1024 + col] = f2b(acc[mi][ni][r] + bv);
            }
        }
    }
}

// ---------------- LayerNorm family (bf16 X + bf16 partials) ----------------
template<bool FINAL, int NR>
__global__ void ln_kernel(const unsigned short* __restrict__ Xb,
                          const unsigned short* __restrict__ Rbase, size_t rstride,
                          const float* __restrict__ g, const float* __restrict__ be,
                          unsigned short* __restrict__ ob16,
                          const float* __restrict__ hidden, float* __restrict__ fout) {
    __shared__ float sb1[4], sb2[4];
    const int row = blockIdx.x, t = threadIdx.x;
    const size_t base = (size_t)row * 1024 + t * 4;

    ushort4 xv = *(const ushort4*)(Xb + base);
    float x0 = b2f(xv.x), x1 = b2f(xv.y), x2 = b2f(xv.z), x3 = b2f(xv.w);
#pragma unroll
    for (int r = 0; r < NR; r++) {
        ushort4 rv = *(const ushort4*)(Rbase + r * rstride + base);
        x0 += b2f(rv.x); x1 += b2f(rv.y); x2 += b2f(rv.z); x3 += b2f(rv.w);
    }
    float s = x0 + x1 + x2 + x3;
#pragma unroll
    for (int o = 32; o > 0; o >>= 1) s += __shfl_down(s, o);
    if ((t & 63) == 0) sb1[t >> 6] = s;
    __syncthreads();
    const float mu = (sb1[0] + sb1[1] + sb1[2] + sb1[3]) * (1.0f / 1024.0f);

    const float d0 = x0 - mu, d1 = x1 - mu, d2 = x2 - mu, d3 = x3 - mu;
    float s2 = d0 * d0 + d1 * d1 + d2 * d2 + d3 * d3;
#pragma unroll
    for (int o = 32; o > 0; o >>= 1) s2 += __shfl_down(s2, o);
    if ((t & 63) == 0) sb2[t >> 6] = s2;
    __syncthreads();
    const float var = (sb2[0] + sb2[1] + sb2[2] + sb2[3]) * (1.0f / 1024.0f);
    const float rstd = rsqrtf(var + 1e-6f);

    const float4 gv = *(const float4*)(g + t * 4);
    const float4 bv = *(const float4*)(be + t * 4);
    const float y0 = d0 * rstd * gv.x + bv.x;
    const float y1 = d1 * rstd * gv.y + bv.y;
    const float y2 = d2 * rstd * gv.z + bv.z;
    const float y3 = d3 * rstd * gv.w + bv.w;

    if (!FINAL) {
        ushort4 ob; ob.x = f2b(y0); ob.y = f2b(y1); ob.z = f2b(y2); ob.w = f2b(y3);
        *(ushort4*)(ob16 + base) = ob;
    } else {
        const float4 hv = *(const float4*)(hidden + base);
        const float e0 = y0 > 0.0f ? y0 : expm1f(y0);
        const float e1 = y1 > 0.0f ? y1 : expm1f(y1);
        const float e2 = y2 > 0.0f ? y2 : expm1f(y2);
        const float e3 = y3 > 0.0f ? y3 : expm1f(y3);
        float4 o; o.x = hv.x + e0; o.y = hv.y + e1; o.z = hv.z + e2; o.w = hv.w + e3;
        *(float4*)(fout + base) = o;
    }
}

// ---------------- dense edge phase ----------------
__global__ void edge_scatter(const unsigned short* __restrict__ S,
                             const int* __restrict__ src, const int* __restrict__ dst,
                             const int* __restrict__ rel,
                             float* __restrict__ A, float* __restrict__ G) {
    const size_t ZSTR = (size_t)B_SZ * SEXT_M * 1024;
    const int gg = blockIdx.x * 256 + threadIdx.x;   // B*E = 131072
    const int b = gg >> 15;
    const int s = src[gg], d = dst[gg], r = rel[gg];
    const size_t sbase = ((size_t)b * SEXT_M + s) * 1024 + d;
    const size_t tbase = ((size_t)b * SEXT_M + 1024 + r) * 1024 + d;
    const float sval = b2f(S[sbase]) + b2f(S[sbase + ZSTR]);
    const float tval = b2f(S[tbase]) + b2f(S[tbase + ZSTR]);
    float sc = (sval + tval) * (1.0f / 32.0f);
    sc = expf(fminf(fmaxf(sc, -10.0f), 10.0f));
    atomicAdd(&A[((size_t)((b << 10) + d) << 10) + s], sc);
    atomicAdd(&G[((size_t)((b << 10) + d) << 6) + r], sc);
}

// per node: inv = 1/sum_r G[row,r]; Awv[row] = bf16([A*inv | G*inv])  (1088-wide)
__global__ void normalize(const float* __restrict__ A, const float* __restrict__ G,
                          unsigned short* __restrict__ Awv) {
    __shared__ float sInv;
    const int row = blockIdx.x, t = threadIdx.x;
    float v = 0.0f;
    if (t < 64) {
        v = G[(size_t)row * 64 + t];
        float s = v;
#pragma unroll
        for (int o = 1; o < 64; o <<= 1) s += __shfl_xor(s, o);
        if (t == 0) sInv = 1.0f / s;
    }
    __syncthreads();
    const float inv = sInv;
    const size_t obase = (size_t)row * LDA_WV;
    const float4 a = *(const float4*)(A + (size_t)row * 1024 + t * 4);
    ushort4 o;
    o.x = f2b(a.x * inv); o.y = f2b(a.y * inv); o.z = f2b(a.z * inv); o.w = f2b(a.w * inv);
    *(ushort4*)(Awv + obase + t * 4) = o;
    if (t < 16) {
        const float4 gq = *(const float4*)(G + (size_t)row * 64 + t * 4);
        ushort4 og;
        og.x = f2b(gq.x * inv); og.y = f2b(gq.y * inv);
        og.z = f2b(gq.z * inv); og.w = f2b(gq.w * inv);
        *(ushort4*)(Awv + obase + 1024 + t * 4) = og;
    }
}

// ---------------- launch ----------------
extern "C" void kernel_launch(void* const* d_in, const int* in_sizes, int n_in,
                              void* d_out, int out_size, void* d_ws, size_t ws_size,
                              hipStream_t stream) {
    const float* hidden  = (const float*)d_in[0];
    const float* rel_tbl = (const float*)d_in[1];
    const float* Wq = (const float*)d_in[2];
    const float* bq = (const float*)d_in[3];
    const float* Wk = (const float*)d_in[4];
    const float* Wv = (const float*)d_in[5];
    const float* Wo = (const float*)d_in[6];
    const float* bo = (const float*)d_in[7];
    const float* ln0_g = (const float*)d_in[8];
    const float* ln0_b = (const float*)d_in[9];
    const float* ln1_g = (const float*)d_in[10];
    const float* ln1_b = (const float*)d_in[11];
    const float* W1 = (const float*)d_in[12];
    const float* b1 = (const float*)d_in[13];
    const float* W2 = (const float*)d_in[14];
    const float* b2 = (const float*)d_in[15];
    const float* ln2_g = (const float*)d_in[16];
    const float* ln2_b = (const float*)d_in[17];
    const int* esrc = (const int*)d_in[18];
    const int* edst = (const int*)d_in[19];
    const int* erel = (const int*)d_in[20];
    float* out = (float*)d_out;

    // ws lifetime map (peak 121MB):
    //  0-32    H1 [FFN1->W2]
    // 16-24    Xn_b16 [LN0->QKV,LN1]
    // 24-30    Wqkv_t ; 30-32 Wo_t [prep->sext_w]
    // 32-40    W1_t ; 40-48 W2_t
    // 48-48.25 relbPad ; 48.5 bqkv
    // 49-73    QKV [QKVg->sext_w] ; then 49-58 Awv [norm->wv'] ; then 49-81 Qw2H x4 [W2->LN2]
    // 66-82    PwoH x2 [wv'->LN1] (SxH dead after scatter)
    // 73-92    SxH [sext_w->scatter]
    // 92-101   Bwv' 4x2.25MB [sext_w->wv']
    // 101-117  Amat ; 117-118 Gmat [prep-zero->normalize]
    // 113-121  Out_b16 [LN1->FFN1,LN2] (Amat dead by then)
    char* ws = (char*)d_ws;
    const size_t MB = 1024 * 1024;
    unsigned short* Xn_b16  = (unsigned short*)(ws + 16 * MB);
    unsigned short* H1      = (unsigned short*)(ws + 0);
    unsigned short* Wqkv_t  = (unsigned short*)(ws + 24 * MB);
    unsigned short* Wo_t    = (unsigned short*)(ws + 30 * MB);
    unsigned short* W1_t    = (unsigned short*)(ws + 32 * MB);
    unsigned short* W2_t    = (unsigned short*)(ws + 40 * MB);
    unsigned short* relbPad = (unsigned short*)(ws + 48 * MB);
    float*          bqkv    = (float*)(ws + 48 * MB + 512 * 1024);
    unsigned short* QKV     = (unsigned short*)(ws + 49 * MB);
    unsigned short* Awv     = (unsigned short*)(ws + 49 * MB);
    unsigned short* Qw2H    = (unsigned short*)(ws + 49 * MB);
    unsigned short* PwoH    = (unsigned short*)(ws + 66 * MB);
    unsigned short* SxH     = (unsigned short*)(ws + 73 * MB);
    unsigned short* Bwvp    = (unsigned short*)(ws + 92 * MB);
    float*          Amat    = (float*)(ws + 101 * MB);
    float*          Gmat    = (float*)(ws + 117 * MB);
    unsigned short* Out_b16 = (unsigned short*)(ws + 113 * MB);

    const size_t PSTRIDE_H = 4u * 1024 * 1024;   // 8MB bf16 partial, in ushorts
    const dim3 blk(256);

    // ---- fused prep ----
    prep_all<<<17996, blk, 0, stream>>>(Wq, Wk, Wv, Wo, W1, W2, rel_tbl, bq,
                                        hidden, ln0_g, ln0_b,
                                        Wqkv_t, Wo_t, W1_t, W2_t, relbPad, bqkv,
                                        Xn_b16, Amat);
    // ---- QKV GEMM ----
    gemm_bf16<true, false><<<dim3(24 * 32), blk, 0, stream>>>(
        Xn_b16, 1024, Wqkv_t, 1024, 0, bqkv, nullptr, QKV, 3072, 1024, 24);
    // ---- S_ext GEMM + W' GEMM (merged) ----
    sext_w<<<864, blk, 0, stream>>>(QKV, relbPad, Wo_t, SxH, Bwvp, 512);
    // ---- scatter scores into pre-zeroed A,G ----
    edge_scatter<<<512, blk, 0, stream>>>(SxH, esrc, edst, erel, Amat, Gmat);
    // ---- normalize -> Awv [4096,1088] ----
    normalize<<<M_ROWS, blk, 0, stream>>>(Amat, Gmat, Awv);
    // ---- wv': attention out = Awv @ Bwv'^T + bo (asym split-K=2 -> PwoH) ----
    gemm_wv_splitk<<<dim3(256, 1, 2), blk, 0, stream>>>(Awv, Bwvp, bo, PwoH, PSTRIDE_H);
    // ---- LN1: LN(Xn + Pwo) -> Out_b16 ----
    ln_kernel<false, 2><<<M_ROWS, blk, 0, stream>>>(Xn_b16, PwoH, PSTRIDE_H, ln1_g, ln1_b,
                                                    Out_b16, nullptr, nullptr);
    // ---- FFN1 ----
    gemm_bf16<true, true><<<dim3(32 * 32), blk, 0, stream>>>(
        Out_b16, 1024, W1_t, 1024, 0, b1, nullptr, H1, 4096, 1024, 32);
    // ---- W2 (split-K=4, bf16 partials) ----
    gemm_bf16_splitk<<<dim3(8 * 32, 1, 4), blk, 0, stream>>>(
        H1, 4096, W2_t, 4096, 0, b2, Qw2H, PSTRIDE_H, 1024, 1024, 8);
    // ---- LN2(out + sum Qw2) + elu + residual ----
    ln_kernel<true, 4><<<M_ROWS, blk, 0, stream>>>(Out_b16, Qw2H, PSTRIDE_H, ln2_g, ln2_b,
                                                   nullptr, hidden, out);
    (void)in_sizes; (void)n_in; (void)out_size; (void)ws_size;
}

// Round 13
// 346.346 us; speedup vs baseline: 1.4238x; 1.0167x over previous
//
#include <hip/hip_runtime.h>
#include <hip/hip_bf16.h>

#define B_SZ 4
#define L_SEQ 1024
#define D_MODEL 1024
#define DF_FF 4096
#define E_PER_B 32768
#define R_REL 64
#define M_ROWS (B_SZ * L_SEQ)   // 4096

typedef __attribute__((ext_vector_type(8))) short bf16x8;
typedef __attribute__((ext_vector_type(4))) float f32x4;

__device__ inline float b2f(unsigned short u) {
    union { unsigned int i; float f; } x; x.i = ((unsigned int)u) << 16; return x.f;
}
__device__ inline unsigned short f2b(float f) {
    union { float f; unsigned int u; } x; x.f = f;
    unsigned int r = x.u + 0x7FFFu + ((x.u >> 16) & 1u);
    return (unsigned short)(r >> 16);
}

#define GLOBAL_CAST(p) ((const __attribute__((address_space(1))) void*)(p))
#define LDS_CAST(p)    ((__attribute__((address_space(3))) void*)(p))

#define BT_QKV (1024u * 3072u)           // per-batch QKV stride
#define SEXT_M 1152                      // S_ext rows per batch: 1024 src + 128 relPad
#define LDA_WV 1088                      // Awv K width: 1024 (A) + 64 (G)
#define LDB_WVP 1152                     // Bwv' row stride (K padded to 18*64)
#define BT_WVP (1024u * 1152u)           // per-batch Bwv' stride

// ---------------- fused prep: weights + relPad + bias + LN0(bf16) + zero(A|G) ----------------
// flat grid 17996:
//   [0,12288)      weight transposes (Wq,Wk,Wv,Wo,W1,W2)
//   [12288,12800)  relbPad bf16 [128,1024] (rows 64..127 zero)
//   [12800,12812)  bqkv f32 [3072] (cols 1024+ = 0)
//   [12812,16908)  LN0 -> Xn_b16
//   [16908,17996)  zero 17MB A|G region
__global__ void prep_all(const float* __restrict__ Wq, const float* __restrict__ Wk,
                         const float* __restrict__ Wv, const float* __restrict__ Wo,
                         const float* __restrict__ W1, const float* __restrict__ W2,
                         const float* __restrict__ rel, const float* __restrict__ bq,
                         const float* __restrict__ hidden,
                         const float* __restrict__ ln0_g, const float* __restrict__ ln0_b,
                         unsigned short* __restrict__ Wqkv_t, unsigned short* __restrict__ Wo_t,
                         unsigned short* __restrict__ W1_t, unsigned short* __restrict__ W2_t,
                         unsigned short* __restrict__ relbPad,
                         float* __restrict__ bqkv,
                         unsigned short* __restrict__ Xn_b16,
                         float* __restrict__ zeroReg) {
    __shared__ float tile[32][33];
    __shared__ float sb1[4], sb2[4];
    const int id = blockIdx.x, tid = threadIdx.x;
    if (id < 12288) {
        const float* src; unsigned short* dst; int K, N, x, y;
        if (id < 4096) {
            const int seg = id >> 10, t = id & 1023;
            K = 1024; N = 1024; x = t & 31; y = t >> 5;
            src = (seg == 0) ? Wq : (seg == 1) ? Wk : (seg == 2) ? Wv : Wo;
            dst = (seg == 3) ? Wo_t : (Wqkv_t + (size_t)seg * 1048576);
        } else if (id < 8192) {
            const int t = id - 4096; K = 1024; N = 4096; x = t & 127; y = t >> 7;
            src = W1; dst = W1_t;
        } else {
            const int t = id - 8192; K = 4096; N = 1024; x = t & 31; y = t >> 5;
            src = W2; dst = W2_t;
        }
        const int n0 = x * 32, k0 = y * 32, tx = tid & 31, ty = tid >> 5;
#pragma unroll
        for (int r = 0; r < 32; r += 8)
            tile[ty + r][tx] = src[(size_t)(k0 + ty + r) * N + (n0 + tx)];
        __syncthreads();
#pragma unroll
        for (int r = 0; r < 32; r += 8)
            dst[(size_t)(n0 + ty + r) * K + (k0 + tx)] = f2b(tile[tx][ty + r]);
    } else if (id < 12800) {
        const int i = (id - 12288) * 256 + tid;            // 131072
        relbPad[i] = (i < 65536) ? f2b(rel[i]) : (unsigned short)0;
    } else if (id < 12812) {
        const int i = (id - 12800) * 256 + tid;            // 3072
        bqkv[i] = (i < 1024) ? bq[i] : 0.0f;
    } else if (id < 16908) {
        // LN0 row -> bf16
        const int row = id - 12812, t = tid;
        const size_t base = (size_t)row * 1024 + t * 4;
        float4 xv = *(const float4*)(hidden + base);
        float x0 = xv.x, x1 = xv.y, x2 = xv.z, x3 = xv.w;
        float s = x0 + x1 + x2 + x3;
#pragma unroll
        for (int o = 32; o > 0; o >>= 1) s += __shfl_down(s, o);
        if ((t & 63) == 0) sb1[t >> 6] = s;
        __syncthreads();
        const float mu = (sb1[0] + sb1[1] + sb1[2] + sb1[3]) * (1.0f / 1024.0f);
        const float d0 = x0 - mu, d1 = x1 - mu, d2 = x2 - mu, d3 = x3 - mu;
        float s2 = d0 * d0 + d1 * d1 + d2 * d2 + d3 * d3;
#pragma unroll
        for (int o = 32; o > 0; o >>= 1) s2 += __shfl_down(s2, o);
        if ((t & 63) == 0) sb2[t >> 6] = s2;
        __syncthreads();
        const float var = (sb2[0] + sb2[1] + sb2[2] + sb2[3]) * (1.0f / 1024.0f);
        const float rstd = rsqrtf(var + 1e-6f);
        const float4 gv = *(const float4*)(ln0_g + t * 4);
        const float4 bv = *(const float4*)(ln0_b + t * 4);
        ushort4 ob;
        ob.x = f2b(d0 * rstd * gv.x + bv.x);
        ob.y = f2b(d1 * rstd * gv.y + bv.y);
        ob.z = f2b(d2 * rstd * gv.z + bv.z);
        ob.w = f2b(d3 * rstd * gv.w + bv.w);
        *(ushort4*)(Xn_b16 + base) = ob;
    } else {
        const size_t base = (size_t)(id - 16908) * 4096 + tid * 4;
        const float4 z4 = make_float4(0.f, 0.f, 0.f, 0.f);
#pragma unroll
        for (int j = 0; j < 4; j++)
            *(float4*)(zeroReg + base + j * 1024) = z4;
    }
}

// 1D XCD swizzle: XCD = linear_id % 8; group all tile_n of a tile_m on one XCD.
__device__ inline void tile_swizzle(int id, int ntn, int& tm, int& tn) {
    tm = ((id & 7) + ((id >> 3) / ntn) * 8) * 128;
    tn = ((id >> 3) % ntn) * 128;
}

// 2D supertile XCD swizzle (requires ntm==32, ntn%4==0): XCDs form a 2(m) x 4(n)
// supergrid; each XCD covers a 16 x (ntn/4) tile region -> per-XCD L2 fetch
// (16+ntn/4)*0.25MB instead of (4+ntn)*0.25MB.
__device__ inline void tile_swizzle2(int id, int ntn, int& tm, int& tn) {
    const int xcd = id & 7;
    const int local = id >> 3;
    const int nh = ntn >> 2;
    tm = ((xcd >> 2) * 16 + (local & 15)) * 128;
    tn = ((xcd & 3) * nh + (local >> 4)) * 128;
}

// ---------------- GEMM: 16x16x32 MFMA core (known-good: 0 LDS conflicts) ----------------
// BK=64 (32KB LDS): 32 MFMA per barrier-pair. XOR swizzle slot = chunk ^ (row&7).
#define GEMM_BODY(GA, LDA_, GB, LDB_, KLEN)                                                 \
    f32x4 acc[4][4];                                                                        \
    _Pragma("unroll") for (int i = 0; i < 4; i++)                                           \
        _Pragma("unroll") for (int j = 0; j < 4; j++) acc[i][j] = (f32x4)0.0f;              \
    for (int k0 = 0; k0 < (KLEN); k0 += 64) {                                               \
        __syncthreads();                                                                    \
        _Pragma("unroll") for (int r = 0; r < 4; ++r) {                                     \
            __builtin_amdgcn_global_load_lds(GLOBAL_CAST((GA) + (size_t)r * 8 * (LDA_)),    \
                LDS_CAST(&lA[(wave * 32 + r * 8) * 64]), 16, 0, 0);                         \
            __builtin_amdgcn_global_load_lds(GLOBAL_CAST((GB) + (size_t)r * 8 * (LDB_)),    \
                LDS_CAST(&lB[(wave * 32 + r * 8) * 64]), 16, 0, 0);                         \
        }                                                                                   \
        (GA) += 64; (GB) += 64;                                                             \
        __builtin_amdgcn_s_waitcnt(0);                                                      \
        __syncthreads();                                                                    \
        _Pragma("unroll") for (int kk = 0; kk < 2; ++kk) {                                  \
            const int cb = kk * 4 + quad;                                                   \
            bf16x8 af[4], bf[4];                                                            \
            _Pragma("unroll") for (int i = 0; i < 4; i++) {                                 \
                const int ra = wm + i * 16 + l16;                                           \
                af[i] = *(const bf16x8*)&lA[ra * 64 + ((cb ^ (ra & 7)) * 8)];               \
                const int rb = wn + i * 16 + l16;                                           \
                bf[i] = *(const bf16x8*)&lB[rb * 64 + ((cb ^ (rb & 7)) * 8)];               \
            }                                                                               \
            _Pragma("unroll") for (int mi = 0; mi < 4; mi++)                                \
                _Pragma("unroll") for (int ni = 0; ni < 4; ni++)                            \
                    acc[mi][ni] = __builtin_amdgcn_mfma_f32_16x16x32_bf16(                  \
                        af[mi], bf[ni], acc[mi][ni], 0, 0, 0);                              \
        }                                                                                   \
    }

template<bool OUT_BF16, bool RELU, bool SW2>
__global__ __launch_bounds__(256, 4)
void gemm_bf16(const unsigned short* __restrict__ A, int lda,
               const unsigned short* __restrict__ Bt, int ldb, size_t bt_batch,
               const float* __restrict__ bias,
               float* __restrict__ Cf, unsigned short* __restrict__ Cb,
               int N, int K, int ntn) {
    __shared__ unsigned short lA[128 * 64];
    __shared__ unsigned short lB[128 * 64];
    int tile_m, tile_n;
    if (SW2) tile_swizzle2(blockIdx.x, ntn, tile_m, tile_n);
    else     tile_swizzle(blockIdx.x, ntn, tile_m, tile_n);
    const int t = threadIdx.x;
    const int wave = t >> 6, lane = t & 63;
    const int wm = (wave >> 1) * 64, wn = (wave & 1) * 64;
    const int quad = lane >> 4, l16 = lane & 15;
    const int srow = lane >> 3;
    const int schunk = ((lane & 7) ^ srow) * 8;
    const unsigned short* gA = A + (size_t)(tile_m + wave * 32 + srow) * lda + schunk;
    const unsigned short* gB = Bt + (size_t)(tile_m >> 10) * bt_batch
                                  + (size_t)(tile_n + wave * 32 + srow) * ldb + schunk;
    GEMM_BODY(gA, lda, gB, ldb, K)
#pragma unroll
    for (int mi = 0; mi < 4; mi++) {
#pragma unroll
        for (int ni = 0; ni < 4; ni++) {
            const int col = tile_n + wn + ni * 16 + l16;
            const float bv = bias[col];
#pragma unroll
            for (int r = 0; r < 4; r++) {
                const int row = tile_m + wm + mi * 16 + quad * 4 + r;
                float v = acc[mi][ni][r] + bv;
                if (RELU) v = fmaxf(v, 0.0f);
                if (OUT_BF16) Cb[(size_t)row * N + col] = f2b(v);
                else          Cf[(size_t)row * N + col] = v;
            }
        }
    }
}

// split-K (symmetric): bf16 partial at Pbase + z*pstride.
__global__ __launch_bounds__(256, 4)
void gemm_bf16_splitk(const unsigned short* __restrict__ A, int lda,
                      const unsigned short* __restrict__ Bt, int ldb, size_t bt_batch,
                      const float* __restrict__ bias,
                      unsigned short* __restrict__ Pbase, size_t pstride,
                      int N, int Kc, int ntn) {
    __shared__ unsigned short lA[128 * 64];
    __shared__ unsigned short lB[128 * 64];
    int tile_m, tile_n;
    tile_swizzle(blockIdx.x, ntn, tile_m, tile_n);
    const int z = blockIdx.z;
    const int kofs = z * Kc;
    const int t = threadIdx.x;
    const int wave = t >> 6, lane = t & 63;
    const int wm = (wave >> 1) * 64, wn = (wave & 1) * 64;
    const int quad = lane >> 4, l16 = lane & 15;
    const int srow = lane >> 3;
    const int schunk = ((lane & 7) ^ srow) * 8;
    const unsigned short* gA = A + (size_t)(tile_m + wave * 32 + srow) * lda + kofs + schunk;
    const unsigned short* gB = Bt + (size_t)(tile_m >> 10) * bt_batch
                                  + (size_t)(tile_n + wave * 32 + srow) * ldb + kofs + schunk;
    GEMM_BODY(gA, lda, gB, ldb, Kc)
    unsigned short* P = Pbase + (size_t)z * pstride;
#pragma unroll
    for (int mi = 0; mi < 4; mi++) {
#pragma unroll
        for (int ni = 0; ni < 4; ni++) {
            const int col = tile_n + wn + ni * 16 + l16;
            const float bv = (z == 0) ? bias[col] : 0.0f;
#pragma unroll
            for (int r = 0; r < 4; r++) {
                const int row = tile_m + wm + mi * 16 + quad * 4 + r;
                P[(size_t)row * N + col] = f2b(acc[mi][ni][r] + bv);
            }
        }
    }
}

// ---------------- S_ext GEMM + W' GEMM, merged (both depend on QKV + weights only) ----------------
// flat grid 864:
//  [0,576)   sext: S_ext = [K(1024);relbPad(128)] @ Q^T per batch, split-K=2, bf16 partials.
//            P[z][b][1152][1024]: rows 0-1023 = S[src,dst], rows 1024.. = T^T[r,dst].
//  [576,864) W': Bwv'[b][e][n] = Wo_t[e,:] . ([V_b ; relbPad][n,:])   (K=1024, N=1152)
__global__ __launch_bounds__(256, 4)
void sext_w(const unsigned short* __restrict__ QKV,
            const unsigned short* __restrict__ relPad,
            const unsigned short* __restrict__ Wo_t,
            unsigned short* __restrict__ Pbase,
            unsigned short* __restrict__ Bwvp, int Kc) {
    __shared__ unsigned short lA[128 * 64];
    __shared__ unsigned short lB[128 * 64];
    const int id = blockIdx.x, t = threadIdx.x;
    const int wave = t >> 6, lane = t & 63;
    const int wm = (wave >> 1) * 64, wn = (wave & 1) * 64;
    const int quad = lane >> 4, l16 = lane & 15;
    const int srow = lane >> 3;
    const int schunk = ((lane & 7) ^ srow) * 8;

    if (id >= 576) {   // ---- W' segment ----
        const int t2 = id - 576;
        const int b = t2 / 72, rem = t2 % 72;
        const int tile_m = (rem / 9) * 128;          // e
        const int tile_n = (rem % 9) * 128;          // s | 1024+r
        const unsigned short* gA = Wo_t + (size_t)(tile_m + wave * 32 + srow) * 1024 + schunk;
        const int brow = tile_n + wave * 32 + srow;
        const unsigned short* gB;
        size_t ldb;
        if (tile_n < 1024) {                          // V rows, natural layout
            gB = QKV + (size_t)b * BT_QKV + (size_t)brow * 3072 + 2048 + schunk;
            ldb = 3072;
        } else {                                      // relPad rows
            gB = relPad + (size_t)(brow - 1024) * 1024 + schunk;
            ldb = 1024;
        }
        GEMM_BODY(gA, 1024, gB, ldb, 1024)
        unsigned short* P = Bwvp + (size_t)b * BT_WVP;
#pragma unroll
        for (int mi = 0; mi < 4; mi++) {
#pragma unroll
            for (int ni = 0; ni < 4; ni++) {
                const int col = tile_n + wn + ni * 16 + l16;
#pragma unroll
                for (int r = 0; r < 4; r++) {
                    const int row = tile_m + wm + mi * 16 + quad * 4 + r;
                    P[(size_t)row * LDB_WVP + col] = f2b(acc[mi][ni][r]);
                }
            }
        }
        return;
    }

    // ---- sext segment ----
    const int bx = id % 72, b = (id / 72) & 3, z = id / 288;
    const int tile_m = (bx >> 3) * 128;
    const int tile_n = (bx & 7) * 128;
    const int kofs = z * Kc;
    const int arow = tile_m + wave * 32 + srow;
    const unsigned short* gA;
    size_t lda;
    if (tile_m < 1024) {   // K rows
        gA = QKV + (size_t)b * BT_QKV + (size_t)arow * 3072 + 1024 + kofs + schunk;
        lda = 3072;
    } else {               // relPad rows
        gA = relPad + (size_t)(arow - 1024) * 1024 + kofs + schunk;
        lda = 1024;
    }
    const unsigned short* gB = QKV + (size_t)b * BT_QKV
                                   + (size_t)(tile_n + wave * 32 + srow) * 3072 + kofs + schunk;
    GEMM_BODY(gA, lda, gB, 3072, Kc)
    unsigned short* P = Pbase + ((size_t)z * B_SZ + b) * (SEXT_M * 1024);
#pragma unroll
    for (int mi = 0; mi < 4; mi++) {
#pragma unroll
        for (int ni = 0; ni < 4; ni++) {
            const int col = tile_n + wn + ni * 16 + l16;
#pragma unroll
            for (int r = 0; r < 4; r++) {
                const int row = tile_m + wm + mi * 16 + quad * 4 + r;
                P[(size_t)row * 1024 + col] = f2b(acc[mi][ni][r]);
            }
        }
    }
}

// ---------------- wv' GEMM: attention-out = Awv @ Bwv'^T + bo, asymmetric split-K=2 ----------------
// z=0: K [0,576); z=1: K [576,1088). bf16 partials -> PwoH + z*pstride. grid (256,1,2).
__global__ __launch_bounds__(256, 4)
void gemm_wv_splitk(const unsigned short* __restrict__ A,
                    const unsigned short* __restrict__ Bt,
                    const float* __restrict__ bias,
                    unsigned short* __restrict__ Pbase, size_t pstride) {
    __shared__ unsigned short lA[128 * 64];
    __shared__ unsigned short lB[128 * 64];
    int tile_m, tile_n;
    tile_swizzle(blockIdx.x, 8, tile_m, tile_n);
    const int z = blockIdx.z;
    const int kofs = z * 576;
    const int Kc = z ? 512 : 576;
    const int t = threadIdx.x;
    const int wave = t >> 6, lane = t & 63;
    const int wm = (wave >> 1) * 64, wn = (wave & 1) * 64;
    const int quad = lane >> 4, l16 = lane & 15;
    const int srow = lane >> 3;
    const int schunk = ((lane & 7) ^ srow) * 8;
    const unsigned short* gA = A + (size_t)(tile_m + wave * 32 + srow) * LDA_WV + kofs + schunk;
    const unsigned short* gB = Bt + (size_t)(tile_m >> 10) * BT_WVP
                                  + (size_t)(tile_n + wave * 32 + srow) * LDB_WVP + kofs + schunk;
    GEMM_BODY(gA, LDA_WV, gB, LDB_WVP, Kc)
    unsigned short* P = Pbase + (size_t)z * pstride;
#pragma unroll
    for (int mi = 0; mi < 4; mi++) {
#pragma unroll
        for (int ni = 0; ni < 4; ni++) {
            const int col = tile_n + wn + ni * 16 + l16;
            const float bv = (z == 0) ? bias[col] : 0.0f;
#pragma unroll
            for (int r = 0; r < 4; r++) {
                const int row = tile_m + wm + mi * 16 + quad * 4 + r;
                P[(size_t)row * 1024 + col] = f2b(acc[mi][ni][r] + bv);
            }
        }
    }
}

// ---------------- LayerNorm family (bf16 X + bf16 partials) ----------------
template<bool FINAL, int NR>
__global__ void ln_kernel(const unsigned short* __restrict__ Xb,
                          const unsigned short* __restrict__ Rbase, size_t rstride,
                          const float* __restrict__ g, const float* __restrict__ be,
                          unsigned short* __restrict__ ob16,
                          const float* __restrict__ hidden, float* __restrict__ fout) {
    __shared__ float sb1[4], sb2[4];
    const int row = blockIdx.x, t = threadIdx.x;
    const size_t base = (size_t)row * 1024 + t * 4;

    ushort4 xv = *(const ushort4*)(Xb + base);
    float x0 = b2f(xv.x), x1 = b2f(xv.y), x2 = b2f(xv.z), x3 = b2f(xv.w);
#pragma unroll
    for (int r = 0; r < NR; r++) {
        ushort4 rv = *(const ushort4*)(Rbase + r * rstride + base);
        x0 += b2f(rv.x); x1 += b2f(rv.y); x2 += b2f(rv.z); x3 += b2f(rv.w);
    }
    float s = x0 + x1 + x2 + x3;
#pragma unroll
    for (int o = 32; o > 0; o >>= 1) s += __shfl_down(s, o);
    if ((t & 63) == 0) sb1[t >> 6] = s;
    __syncthreads();
    const float mu = (sb1[0] + sb1[1] + sb1[2] + sb1[3]) * (1.0f / 1024.0f);

    const float d0 = x0 - mu, d1 = x1 - mu, d2 = x2 - mu, d3 = x3 - mu;
    float s2 = d0 * d0 + d1 * d1 + d2 * d2 + d3 * d3;
#pragma unroll
    for (int o = 32; o > 0; o >>= 1) s2 += __shfl_down(s2, o);
    if ((t & 63) == 0) sb2[t >> 6] = s2;
    __syncthreads();
    const float var = (sb2[0] + sb2[1] + sb2[2] + sb2[3]) * (1.0f / 1024.0f);
    const float rstd = rsqrtf(var + 1e-6f);

    const float4 gv = *(const float4*)(g + t * 4);
    const float4 bv = *(const float4*)(be + t * 4);
    const float y0 = d0 * rstd * gv.x + bv.x;
    const float y1 = d1 * rstd * gv.y + bv.y;
    const float y2 = d2 * rstd * gv.z + bv.z;
    const float y3 = d3 * rstd * gv.w + bv.w;

    if (!FINAL) {
        ushort4 ob; ob.x = f2b(y0); ob.y = f2b(y1); ob.z = f2b(y2); ob.w = f2b(y3);
        *(ushort4*)(ob16 + base) = ob;
    } else {
        const float4 hv = *(const float4*)(hidden + base);
        const float e0 = y0 > 0.0f ? y0 : expm1f(y0);
        const float e1 = y1 > 0.0f ? y1 : expm1f(y1);
        const float e2 = y2 > 0.0f ? y2 : expm1f(y2);
        const float e3 = y3 > 0.0f ? y3 : expm1f(y3);
        float4 o; o.x = hv.x + e0; o.y = hv.y + e1; o.z = hv.z + e2; o.w = hv.w + e3;
        *(float4*)(fout + base) = o;
    }
}

// ---------------- dense edge phase ----------------
__global__ void edge_scatter(const unsigned short* __restrict__ S,
                             const int* __restrict__ src, const int* __restrict__ dst,
                             const int* __restrict__ rel,
                             float* __restrict__ A, float* __restrict__ G) {
    const size_t ZSTR = (size_t)B_SZ * SEXT_M * 1024;
    const int gg = blockIdx.x * 256 + threadIdx.x;   // B*E = 131072
    const int b = gg >> 15;
    const int s = src[gg], d = dst[gg], r = rel[gg];
    const size_t sbase = ((size_t)b * SEXT_M + s) * 1024 + d;
    const size_t tbase = ((size_t)b * SEXT_M + 1024 + r) * 1024 + d;
    const float sval = b2f(S[sbase]) + b2f(S[sbase + ZSTR]);
    const float tval = b2f(S[tbase]) + b2f(S[tbase + ZSTR]);
    float sc = (sval + tval) * (1.0f / 32.0f);
    sc = expf(fminf(fmaxf(sc, -10.0f), 10.0f));
    atomicAdd(&A[((size_t)((b << 10) + d) << 10) + s], sc);
    atomicAdd(&G[((size_t)((b << 10) + d) << 6) + r], sc);
}

// per node: inv = 1/sum_r G[row,r]; Awv[row] = bf16([A*inv | G*inv])  (1088-wide)
__global__ void normalize(const float* __restrict__ A, const float* __restrict__ G,
                          unsigned short* __restrict__ Awv) {
    __shared__ float sInv;
    const int row = blockIdx.x, t = threadIdx.x;
    float v = 0.0f;
    if (t < 64) {
        v = G[(size_t)row * 64 + t];
        float s = v;
#pragma unroll
        for (int o = 1; o < 64; o <<= 1) s += __shfl_xor(s, o);
        if (t == 0) sInv = 1.0f / s;
    }
    __syncthreads();
    const float inv = sInv;
    const size_t obase = (size_t)row * LDA_WV;
    const float4 a = *(const float4*)(A + (size_t)row * 1024 + t * 4);
    ushort4 o;
    o.x = f2b(a.x * inv); o.y = f2b(a.y * inv); o.z = f2b(a.z * inv); o.w = f2b(a.w * inv);
    *(ushort4*)(Awv + obase + t * 4) = o;
    if (t < 16) {
        const float4 gq = *(const float4*)(G + (size_t)row * 64 + t * 4);
        ushort4 og;
        og.x = f2b(gq.x * inv); og.y = f2b(gq.y * inv);
        og.z = f2b(gq.z * inv); og.w = f2b(gq.w * inv);
        *(ushort4*)(Awv + obase + 1024 + t * 4) = og;
    }
}

// ---------------- launch ----------------
extern "C" void kernel_launch(void* const* d_in, const int* in_sizes, int n_in,
                              void* d_out, int out_size, void* d_ws, size_t ws_size,
                              hipStream_t stream) {
    const float* hidden  = (const float*)d_in[0];
    const float* rel_tbl = (const float*)d_in[1];
    const float* Wq = (const float*)d_in[2];
    const float* bq = (const float*)d_in[3];
    const float* Wk = (const float*)d_in[4];
    const float* Wv = (const float*)d_in[5];
    const float* Wo = (const float*)d_in[6];
    const float* bo = (const float*)d_in[7];
    const float* ln0_g = (const float*)d_in[8];
    const float* ln0_b = (const float*)d_in[9];
    const float* ln1_g = (const float*)d_in[10];
    const float* ln1_b = (const float*)d_in[11];
    const float* W1 = (const float*)d_in[12];
    const float* b1 = (const float*)d_in[13];
    const float* W2 = (const float*)d_in[14];
    const float* b2 = (const float*)d_in[15];
    const float* ln2_g = (const float*)d_in[16];
    const float* ln2_b = (const float*)d_in[17];
    const int* esrc = (const int*)d_in[18];
    const int* edst = (const int*)d_in[19];
    const int* erel = (const int*)d_in[20];
    float* out = (float*)d_out;

    // ws lifetime map (peak 121MB) — identical overlay to R12.
    char* ws = (char*)d_ws;
    const size_t MB = 1024 * 1024;
    unsigned short* Xn_b16  = (unsigned short*)(ws + 16 * MB);
    unsigned short* H1      = (unsigned short*)(ws + 0);
    unsigned short* Wqkv_t  = (unsigned short*)(ws + 24 * MB);
    unsigned short* Wo_t    = (unsigned short*)(ws + 30 * MB);
    unsigned short* W1_t    = (unsigned short*)(ws + 32 * MB);
    unsigned short* W2_t    = (unsigned short*)(ws + 40 * MB);
    unsigned short* relbPad = (unsigned short*)(ws + 48 * MB);
    float*          bqkv    = (float*)(ws + 48 * MB + 512 * 1024);
    unsigned short* QKV     = (unsigned short*)(ws + 49 * MB);
    unsigned short* Awv     = (unsigned short*)(ws + 49 * MB);
    unsigned short* Qw2H    = (unsigned short*)(ws + 49 * MB);
    unsigned short* PwoH    = (unsigned short*)(ws + 66 * MB);
    unsigned short* SxH     = (unsigned short*)(ws + 73 * MB);
    unsigned short* Bwvp    = (unsigned short*)(ws + 92 * MB);
    float*          Amat    = (float*)(ws + 101 * MB);
    float*          Gmat    = (float*)(ws + 117 * MB);
    unsigned short* Out_b16 = (unsigned short*)(ws + 113 * MB);

    const size_t PSTRIDE_H = 4u * 1024 * 1024;   // 8MB bf16 partial, in ushorts
    const dim3 blk(256);

    // ---- fused prep ----
    prep_all<<<17996, blk, 0, stream>>>(Wq, Wk, Wv, Wo, W1, W2, rel_tbl, bq,
                                        hidden, ln0_g, ln0_b,
                                        Wqkv_t, Wo_t, W1_t, W2_t, relbPad, bqkv,
                                        Xn_b16, Amat);
    // ---- QKV GEMM (2D supertile swizzle) ----
    gemm_bf16<true, false, true><<<dim3(24 * 32), blk, 0, stream>>>(
        Xn_b16, 1024, Wqkv_t, 1024, 0, bqkv, nullptr, QKV, 3072, 1024, 24);
    // ---- S_ext GEMM + W' GEMM (merged) ----
    sext_w<<<864, blk, 0, stream>>>(QKV, relbPad, Wo_t, SxH, Bwvp, 512);
    // ---- scatter scores into pre-zeroed A,G ----
    edge_scatter<<<512, blk, 0, stream>>>(SxH, esrc, edst, erel, Amat, Gmat);
    // ---- normalize -> Awv [4096,1088] ----
    normalize<<<M_ROWS, blk, 0, stream>>>(Amat, Gmat, Awv);
    // ---- wv': attention out = Awv @ Bwv'^T + bo (asym split-K=2 -> PwoH) ----
    gemm_wv_splitk<<<dim3(256, 1, 2), blk, 0, stream>>>(Awv, Bwvp, bo, PwoH, PSTRIDE_H);
    // ---- LN1: LN(Xn + Pwo) -> Out_b16 ----
    ln_kernel<false, 2><<<M_ROWS, blk, 0, stream>>>(Xn_b16, PwoH, PSTRIDE_H, ln1_g, ln1_b,
                                                    Out_b16, nullptr, nullptr);
    // ---- FFN1 (2D supertile swizzle) ----
    gemm_bf16<true, true, true><<<dim3(32 * 32), blk, 0, stream>>>(
        Out_b16, 1024, W1_t, 1024, 0, b1, nullptr, H1, 4096, 1024, 32);
    // ---- W2 (split-K=4, bf16 partials) ----
    gemm_bf16_splitk<<<dim3(8 * 32, 1, 4), blk, 0, stream>>>(
        H1, 4096, W2_t, 4096, 0, b2, Qw2H, PSTRIDE_H, 1024, 1024, 8);
    // ---- LN2(out + sum Qw2) + elu + residual ----
    ln_kernel<true, 4><<<M_ROWS, blk, 0, stream>>>(Out_b16, Qw2H, PSTRIDE_H, ln2_g, ln2_b,
                                                   nullptr, hidden, out);
    (void)in_sizes; (void)n_in; (void)out_size; (void)ws_size;
}